// Round 3
// baseline (337.815 us; speedup 1.0000x reference)
//
#include <hip/hip_runtime.h>

#define S 1024
#define D 512
#define HID 64
#define CD 32768
#define DT 0.1f

typedef __attribute__((ext_vector_type(4))) float floatx4;
typedef __attribute__((ext_vector_type(8))) short shortx8;
// may_alias variants for type-punned LDS/global access (TBAA-safe)
typedef short shortx8_a __attribute__((ext_vector_type(8), may_alias));
typedef short shortx4_a __attribute__((ext_vector_type(4), may_alias));
typedef unsigned int uint_a __attribute__((may_alias));
typedef unsigned int uint2_a __attribute__((ext_vector_type(2), may_alias));
typedef unsigned int uint4_a __attribute__((ext_vector_type(4), may_alias));
typedef float float4_a __attribute__((ext_vector_type(4), may_alias));
typedef float float_a __attribute__((may_alias));

__device__ __forceinline__ unsigned short f2bf(float f) {
  union { float f; unsigned int u; } v;
  v.f = f;
  unsigned int r = v.u + 0x7FFFu + ((v.u >> 16) & 1u);
  return (unsigned short)(r >> 16);
}
__device__ __forceinline__ float bf2f(unsigned short h) {
  union { unsigned int u; float f; } v;
  v.u = ((unsigned int)h) << 16;
  return v.f;
}
// hi/lo split: v ~= bf2f(h) + bf2f(lo), ~16-bit mantissa accuracy
__device__ __forceinline__ void cvt_hilo(float v, unsigned short& h, unsigned short& lo) {
  h = f2bf(v);
  lo = f2bf(v - bf2f(h));
}

// =====================  L1: fused QKV-GEMM + cbkd  ==========================
// blocks [0,384): {Q,Kraw,V}T[n][m] = sum_k x[m][k]*W[n][k] via bf16 hi/lo MFMA
// blocks [384,2432): per-16-channel cb2 + kd build (inline dA-power table)
__global__ __launch_bounds__(256) void fused_qkv_cbkd(
    const float* __restrict__ x, const float* __restrict__ WQ,
    const float* __restrict__ WK, const float* __restrict__ WV,
    const float* __restrict__ Are, const float* __restrict__ Aim,
    const float* __restrict__ Cre, const float* __restrict__ Cim,
    float* __restrict__ QT, float* __restrict__ KrawT, float* __restrict__ VT,
    unsigned short* __restrict__ cb2pack, unsigned short* __restrict__ kdpack) {
  __shared__ __align__(16) char LB[21760];
  const int tid = threadIdx.x;
  const int bid = blockIdx.x;
  const int l = tid & 63, w = tid >> 6;
  const int l15 = l & 15, q = l >> 4;

  if (bid < 384) {
    // ---------------- QKV GEMM: 64x64 tile, K=512, BK=32 ----------------
    unsigned short* Wh = (unsigned short*)LB;     // [64][40]
    unsigned short* Wl = Wh + 2560;
    unsigned short* Xh = Wl + 2560;
    unsigned short* Xl = Xh + 2560;
    float_a* Ct = (float_a*)LB;                   // [64][68], aliased after loop
    const int mat = bid >> 7;                     // /128
    const int rem = bid & 127;
    const int n0 = (rem & 7) * 64, m0 = (rem >> 3) * 64;
    const float* Wsel = (mat == 0) ? WQ : (mat == 1) ? WK : WV;
    float* CT = (mat == 0) ? QT : (mat == 1) ? KrawT : VT;

    floatx4 acc[4];
#pragma unroll
    for (int nt = 0; nt < 4; ++nt) acc[nt] = (floatx4){0.f, 0.f, 0.f, 0.f};

    for (int k0 = 0; k0 < D; k0 += 32) {
      if (k0) __syncthreads();
#pragma unroll
      for (int p = 0; p < 2; ++p) {
        const int idx = tid + 256 * p;
        const int row = idx >> 3, c4 = (idx & 7) * 4;
        const float4 wv = *(const float4*)&Wsel[(n0 + row) * D + k0 + c4];
        const float4 xv = *(const float4*)&x[(m0 + row) * D + k0 + c4];
        unsigned short h0, h1, h2, h3, g0, g1, g2, g3;
        cvt_hilo(wv.x, h0, g0); cvt_hilo(wv.y, h1, g1);
        cvt_hilo(wv.z, h2, g2); cvt_hilo(wv.w, h3, g3);
        uint2_a hv = {(unsigned int)h0 | ((unsigned int)h1 << 16),
                      (unsigned int)h2 | ((unsigned int)h3 << 16)};
        uint2_a lv = {(unsigned int)g0 | ((unsigned int)g1 << 16),
                      (unsigned int)g2 | ((unsigned int)g3 << 16)};
        *(uint2_a*)&Wh[row * 40 + c4] = hv;
        *(uint2_a*)&Wl[row * 40 + c4] = lv;
        cvt_hilo(xv.x, h0, g0); cvt_hilo(xv.y, h1, g1);
        cvt_hilo(xv.z, h2, g2); cvt_hilo(xv.w, h3, g3);
        uint2_a hv2 = {(unsigned int)h0 | ((unsigned int)h1 << 16),
                       (unsigned int)h2 | ((unsigned int)h3 << 16)};
        uint2_a lv2 = {(unsigned int)g0 | ((unsigned int)g1 << 16),
                       (unsigned int)g2 | ((unsigned int)g3 << 16)};
        *(uint2_a*)&Xh[row * 40 + c4] = hv2;
        *(uint2_a*)&Xl[row * 40 + c4] = lv2;
      }
      __syncthreads();
      const shortx8 xh = *(const shortx8_a*)&Xh[(16 * w + l15) * 40 + 8 * q];
      const shortx8 xl = *(const shortx8_a*)&Xl[(16 * w + l15) * 40 + 8 * q];
#pragma unroll
      for (int nt = 0; nt < 4; ++nt) {
        const shortx8 wh = *(const shortx8_a*)&Wh[(16 * nt + l15) * 40 + 8 * q];
        const shortx8 wl = *(const shortx8_a*)&Wl[(16 * nt + l15) * 40 + 8 * q];
        acc[nt] = __builtin_amdgcn_mfma_f32_16x16x32_bf16(wh, xh, acc[nt], 0, 0, 0);
        acc[nt] = __builtin_amdgcn_mfma_f32_16x16x32_bf16(wh, xl, acc[nt], 0, 0, 0);
        acc[nt] = __builtin_amdgcn_mfma_f32_16x16x32_bf16(wl, xh, acc[nt], 0, 0, 0);
      }
    }
    __syncthreads();
    // lane holds D[n = 16nt+4q+v][m = 16w+l15] -> Ct[n][m]
#pragma unroll
    for (int nt = 0; nt < 4; ++nt)
#pragma unroll
      for (int v = 0; v < 4; ++v)
        Ct[(16 * nt + 4 * q + v) * 68 + 16 * w + l15] = acc[nt][v];
    __syncthreads();
#pragma unroll
    for (int p = 0; p < 4; ++p) {
      const int row = (tid >> 4) + 16 * p;
      const int col4 = (tid & 15) * 4;
      *(float4_a*)&CT[(n0 + row) * S + m0 + col4] = *(const float4_a*)&Ct[row * 68 + col4];
    }
  } else {
    // ---------------- cbkd: c0 = (bid-384)*16 ----------------
    unsigned short* cbs = (unsigned short*)LB;          // [16][136]
    unsigned short* PCc2s = (unsigned short*)(LB + 4352);  // [64][136]
    const int c0 = (bid - 384) << 4;
    // inline PCc2 table build: thread (n=l, seg=w)
    {
      const int n = l, seg = w;
      const float ar = Are[n], ai = Aim[n];
      const float den_re = 1.0f - 0.05f * ar;
      const float den_im = -0.05f * ai;
      const float num_re = 1.0f + 0.05f * ar;
      const float num_im = 0.05f * ai;
      const float inv_d2 = 1.0f / (den_re * den_re + den_im * den_im);
      const float dAr = (num_re * den_re + num_im * den_im) * inv_d2;
      const float dAi = (num_im * den_re - num_re * den_im) * inv_d2;
      float e2r = dAr * dAr - dAi * dAi, e2i = 2.0f * dAr * dAi;
      float e4r = e2r * e2r - e2i * e2i, e4i = 2.0f * e2r * e2i;
      float e8r = e4r * e4r - e4i * e4i, e8i = 2.0f * e4r * e4i;
      float e16r = e8r * e8r - e8i * e8i, e16i = 2.0f * e8r * e8i;
      float br = 1.0f, bi = 0.0f;
      for (int sgo = 0; sgo < seg; ++sgo) {
        const float nr = br * e16r - bi * e16i;
        bi = br * e16i + bi * e16r;
        br = nr;
      }
      float pr = br, pi = bi;
      for (int k = 16 * seg + 1; k <= 16 * seg + 16; ++k) {
        const float nr = pr * dAr - pi * dAi;
        pi = pr * dAi + pi * dAr;
        pr = nr;
        if (k <= 63) {
          PCc2s[k * 136 + n] = f2bf(pr);
          PCc2s[k * 136 + 64 + n] = f2bf(-pi);
        }
      }
      if (seg == 0) {
        PCc2s[n] = f2bf(1.0f);
        PCc2s[64 + n] = 0;
      }
    }
    // cb2 build
#pragma unroll
    for (int ii = 0; ii < 4; ++ii) {
      const int idx = tid + 256 * ii;
      const int ci = idx >> 6, n = idx & 63;
      const int c = c0 + ci;
      const float ar = Are[n], ai = Aim[n];
      const float den_re = 1.0f - 0.05f * ar;
      const float den_im = -0.05f * ai;
      const float inv_d2 = 1.0f / (den_re * den_re + den_im * den_im);
      const float dBr = DT * den_re * inv_d2;
      const float dBi = -DT * den_im * inv_d2;
      const float cr = Cre[c * HID + n], cim = Cim[c * HID + n];
      const unsigned short re = f2bf(2.0f * (cr * dBr - cim * dBi));
      const unsigned short im = f2bf(2.0f * (cr * dBi + cim * dBr));
      cbs[ci * 136 + n] = re;
      cbs[ci * 136 + 64 + n] = im;
      cb2pack[c * 128 + n] = re;
      cb2pack[c * 128 + 64 + n] = im;
    }
    __syncthreads();
    // kd GEMM -> kdpack (kdR layout)
    floatx4 acc = {0.f, 0.f, 0.f, 0.f};
#pragma unroll
    for (int k = 0; k < 4; ++k) {
      const shortx8 a = *(const shortx8_a*)&cbs[l15 * 136 + 8 * q + 32 * k];
      const shortx8 b = *(const shortx8_a*)&PCc2s[(16 * w + l15) * 136 + 8 * q + 32 * k];
      acc = __builtin_amdgcn_mfma_f32_16x16x32_bf16(a, b, acc, 0, 0, 0);
    }
    const int dlt = 16 * w + l15;
#pragma unroll
    for (int v = 0; v < 4; ++v)
      kdpack[(c0 + 4 * q + v) * 128 + 64 - dlt] = f2bf(acc[v]);
    const int row = tid >> 4, p = tid & 15;
#pragma unroll
    for (int k2 = 0; k2 < 4; ++k2) {
      const int idx = p + 16 * k2;
      const int m = (idx == 0) ? 0 : 64 + idx;
      kdpack[(c0 + row) * 128 + m] = 0;
    }
  }
}

// ======= L2: shift SSM, [d][t] domain, taps via scalar loads ================
__global__ __launch_bounds__(256) void shift_ssmT(const float* __restrict__ KrawT,
                                                  const float* __restrict__ Cs,
                                                  const float* __restrict__ Ds,
                                                  float* __restrict__ KnT) {
  __shared__ float kpad[64 + S];
  const int d = blockIdx.x, tid = threadIdx.x;
  if (tid < 64) kpad[tid] = 0.0f;
  *(float4_a*)&kpad[64 + 4 * tid] = *(const float4_a*)&KrawT[d * S + 4 * tid];
  const float dskip = Ds[d];
  const float* taps = Cs + d * HID;  // block-uniform -> scalar loads
  __syncthreads();
  float acc[4];
#pragma unroll
  for (int s = 0; s < 4; ++s) acc[s] = dskip * kpad[64 + tid + 256 * s];
  for (int j = 0; j < 64; ++j) {
    const float tj = taps[j];
#pragma unroll
    for (int s = 0; s < 4; ++s) acc[s] += tj * kpad[64 + tid + 256 * s - j];
  }
#pragma unroll
  for (int s = 0; s < 4; ++s) KnT[d * S + tid + 256 * s] = acc[s];
}

// =============== L3: s4d_fused (channel-split, 2x occupancy) ================
// Round-3 changes vs round 2:
//  * Grid 512 -> 1024: each block handles HALF the channels (8 of 16 iters).
//    Round-2 was grid-capped at 2 blocks/CU (19% occupancy) while LDS/VGPR
//    allow 4; the serial LDS round-trip chain was latency-exposed.
//    Iterations are independent (scan state resets per channel), so the
//    split only needs partial-sum buffers: half 0 -> OT, half 1 -> OT1
//    (reuses the dead KrawT buffer); gemm_outT sums the two on load.
//  * __launch_bounds__(256,4) pins VGPR<=128 so 4 blocks/CU materialize.
__global__ __launch_bounds__(256, 4) void s4d_fused(
    const float* __restrict__ KnT, const float* __restrict__ VT,
    const float* __restrict__ QT,
    const float* __restrict__ Are, const float* __restrict__ Aim,
    const unsigned short* __restrict__ cb2pack,
    const unsigned short* __restrict__ kdpack,
    const float* __restrict__ Dd, float* __restrict__ OT,
    float* __restrict__ OT1) {
  __shared__ __align__(16) unsigned short SHu[18176];  // 36352 B
  const int tid = threadIdx.x;
  const int l = tid & 63, w = tid >> 6;
  const int l15 = l & 15, q = l >> 4;
  const int half = blockIdx.x & 1;
  const int dv = blockIdx.x >> 1;            // 0..511 (halves adjacent: L2 share)
  const int h = dv >> 6, j = dv & 63;
  float* __restrict__ OTout = half ? OT1 : OT;

  // ---- inline table build: PAre/PAim [n][72], PCc [64][136] interleaved, dA64 ----
  {
    const int n = l, seg = w;
    unsigned short* PAreW = SHu;
    unsigned short* PAimW = SHu + 4608;
    unsigned short* PCcW = SHu + 9216;
    float_a* dA64W = (float_a*)(SHu + 17920);
    const float ar = Are[n], ai = Aim[n];
    const float den_re = 1.0f - 0.05f * ar;
    const float den_im = -0.05f * ai;
    const float num_re = 1.0f + 0.05f * ar;
    const float num_im = 0.05f * ai;
    const float inv_d2 = 1.0f / (den_re * den_re + den_im * den_im);
    const float dAr = (num_re * den_re + num_im * den_im) * inv_d2;
    const float dAi = (num_im * den_re - num_re * den_im) * inv_d2;
    float e2r = dAr * dAr - dAi * dAi, e2i = 2.0f * dAr * dAi;
    float e4r = e2r * e2r - e2i * e2i, e4i = 2.0f * e2r * e2i;
    float e8r = e4r * e4r - e4i * e4i, e8i = 2.0f * e4r * e4i;
    float e16r = e8r * e8r - e8i * e8i, e16i = 2.0f * e8r * e8i;
    float br = 1.0f, bi = 0.0f;
    for (int sgo = 0; sgo < seg; ++sgo) {
      const float nr = br * e16r - bi * e16i;
      bi = br * e16i + bi * e16r;
      br = nr;
    }
    float pr = br, pi = bi;
    for (int k = 16 * seg + 1; k <= 16 * seg + 16; ++k) {
      const float nr = pr * dAr - pi * dAi;
      pi = pr * dAi + pi * dAr;
      pr = nr;
      if (k <= 63) {
        PAreW[n * 72 + 63 - k] = f2bf(pr);
        PAimW[n * 72 + 63 - k] = f2bf(pi);
      }
      // interleaved (re, -im) pairs at columns 2n, 2n+1
      PCcW[(k - 1) * 136 + 2 * n] = f2bf(pr);
      PCcW[(k - 1) * 136 + 2 * n + 1] = f2bf(-pi);
      if (k == 64) {
        dA64W[2 * n] = pr;
        dA64W[2 * n + 1] = pi;
      }
    }
    if (seg == 0) {
      PAreW[n * 72 + 63] = f2bf(1.0f);
      PAimW[n * 72 + 63] = 0;
    }
  }
  // ---- V row slice in registers ----
  float4 vvr[4];
#pragma unroll
  for (int s = 0; s < 4; ++s)
    vvr[s] = *(const float4*)&VT[dv * S + 4 * l + 256 * s];

  // ---- initial per-channel scalar prefetch (channel i = half*32 + w) ----
  float c2r, c2i, dd;
  unsigned int kdv;
  {
    const int c = (h << 12) + ((half * 32 + w) << 6) + j;
    c2r = bf2f(cb2pack[c * 128 + l]);
    c2i = bf2f(cb2pack[c * 128 + 64 + l]);
    kdv = *(const uint_a*)&kdpack[c * 128 + 2 * l];
    dd = Dd[c];
  }
  __syncthreads();

  // ---- hoist table fragments into registers (once per block) ----
  const unsigned short* PAre = SHu;
  const unsigned short* PAim = SHu + 4608;
  const unsigned short* PCc = SHu + 9216;
  const float_a* dA64v = (const float_a*)(SHu + 17920);
  const float er = dA64v[2 * l], ei = dA64v[2 * l + 1];
  shortx8 paR[4][2], paI[4][2];
#pragma unroll
  for (int tt = 0; tt < 4; ++tt) {
    const int rowb = (tt * 16 + l15) * 72 + 8 * q;
    paR[tt][0] = *(const shortx8_a*)&PAre[rowb];
    paR[tt][1] = *(const shortx8_a*)&PAre[rowb + 32];
    paI[tt][0] = *(const shortx8_a*)&PAim[rowb];
    paI[tt][1] = *(const shortx8_a*)&PAim[rowb + 32];
  }
  shortx8 pcb[4][4];
#pragma unroll
  for (int k = 0; k < 4; ++k)
#pragma unroll
    for (int tt = 0; tt < 4; ++tt)
      pcb[k][tt] = *(const shortx8_a*)&PCc[(tt * 16 + l15) * 136 + 8 * q + 32 * k];
  __syncthreads();  // all table reads done before workspace aliases tables

  // ---- per-wave workspace, aliased over the table region ----
  unsigned short* WB = SHu + w * 4048;
  unsigned short* Ub = WB;                    // [16][72] bf16
  unsigned short* SXY = WB + 1152;            // [16][136]: Sc -> Xcb interleaved
  uint_a* kdR32 = (uint_a*)(WB + 3328);       // 68 uints (+pad)
  unsigned short* kdSH = WB + 3472;           // [4][136]

  floatx4 OaccD[4];
  float4 Odd[4];
#pragma unroll
  for (int tt = 0; tt < 4; ++tt) OaccD[tt] = (floatx4){0.f, 0.f, 0.f, 0.f};
#pragma unroll
  for (int s = 0; s < 4; ++s) Odd[s] = make_float4(0.f, 0.f, 0.f, 0.f);

#pragma unroll 1
  for (int itl = 0; itl < 8; ++itl) {
    // ---- prefetch next channel's HBM-cold scalars ----
    float nc2r = 0.f, nc2i = 0.f, ndd = 0.f;
    unsigned int nkdv = 0;
    if (itl < 7) {
      const int c = (h << 12) + ((half * 32 + (itl + 1) * 4 + w) << 6) + j;
      nc2r = bf2f(cb2pack[c * 128 + l]);
      nc2i = bf2f(cb2pack[c * 128 + 64 + l]);
      nkdv = *(const uint_a*)&kdpack[c * 128 + 2 * l];
      ndd = Dd[c];
    }
    // ---- current-channel row loads (L2-warm: shared across 64 j-blocks) ----
    const int dk = (h << 6) + half * 32 + itl * 4 + w;
    const int kb = dk * S + 4 * l;
    float4 kx[4], qtv[4];
#pragma unroll
    for (int s = 0; s < 4; ++s) {
      kx[s] = *(const float4*)&KnT[kb + 256 * s];
      qtv[s] = *(const float4*)&QT[kb + 256 * s];
    }

    // ---- kdR + 4 shifted copies (uses prefetched kdv; covers row loads) ----
    kdR32[l] = kdv;
    if (l < 4) kdR32[64 + l] = 0;
    asm volatile("" ::: "memory");
#pragma unroll
    for (int s2 = 0; s2 < 4; ++s2) {
      unsigned int v;
      if (s2 == 0) {
        v = kdR32[l];
      } else if (s2 == 1) {
        v = (kdR32[l] >> 16) | (kdR32[l + 1] << 16);
      } else if (s2 == 2) {
        v = kdR32[l + 1];
      } else {
        v = (kdR32[l + 1] >> 16) | (kdR32[l + 2] << 16);
      }
      *(uint_a*)&kdSH[s2 * 136 + 2 * l] = v;
    }
    asm volatile("" ::: "memory");

    // ---- u fill + dd-skip accumulation (kx/qtv die here) ----
#pragma unroll
    for (int s = 0; s < 4; ++s) {
      const int t = 4 * l + 256 * s;
      const int g = t >> 6, r = t & 63;
      const float ux = kx[s].x * vvr[s].x;
      const float uy = kx[s].y * vvr[s].y;
      const float uz = kx[s].z * vvr[s].z;
      const float uw = kx[s].w * vvr[s].w;
      uint2_a pp;
      pp.x = (unsigned int)f2bf(ux) | ((unsigned int)f2bf(uy) << 16);
      pp.y = (unsigned int)f2bf(uz) | ((unsigned int)f2bf(uw) << 16);
      *(uint2_a*)&Ub[g * 72 + r] = pp;
      Odd[s].x += dd * qtv[s].x * ux;
      Odd[s].y += dd * qtv[s].y * uy;
      Odd[s].z += dd * qtv[s].z * uz;
      Odd[s].w += dd * qtv[s].w * uw;
    }
    asm volatile("" ::: "memory");

    // ---- phase A: s~[g][n] via MFMA (A-fragments in registers) ----
    const shortx8 b0 = *(const shortx8_a*)&Ub[l15 * 72 + 8 * q];
    const shortx8 b1 = *(const shortx8_a*)&Ub[l15 * 72 + 8 * q + 32];
#pragma unroll
    for (int tt = 0; tt < 4; ++tt) {
      floatx4 z = {0.f, 0.f, 0.f, 0.f};
      floatx4 sre = __builtin_amdgcn_mfma_f32_16x16x32_bf16(paR[tt][0], b0, z, 0, 0, 0);
      sre = __builtin_amdgcn_mfma_f32_16x16x32_bf16(paR[tt][1], b1, sre, 0, 0, 0);
      floatx4 sim = __builtin_amdgcn_mfma_f32_16x16x32_bf16(paI[tt][0], b0, z, 0, 0, 0);
      sim = __builtin_amdgcn_mfma_f32_16x16x32_bf16(paI[tt][1], b1, sim, 0, 0, 0);
      // interleaved: row g=l15, columns 2n..2n+7 for n = tt*16+4q+(0..3)
      uint4_a wv;
      wv[0] = (unsigned int)f2bf(sre[0]) | ((unsigned int)f2bf(sim[0]) << 16);
      wv[1] = (unsigned int)f2bf(sre[1]) | ((unsigned int)f2bf(sim[1]) << 16);
      wv[2] = (unsigned int)f2bf(sre[2]) | ((unsigned int)f2bf(sim[2]) << 16);
      wv[3] = (unsigned int)f2bf(sre[3]) | ((unsigned int)f2bf(sim[3]) << 16);
      *(uint4_a*)&SXY[l15 * 136 + 32 * tt + 8 * q] = wv;
    }
    asm volatile("" ::: "memory");

    // ---- register scan: batch-load packed Sc, pure-VALU recurrence ----
    {
      unsigned int rdv[16];
#pragma unroll
      for (int g = 0; g < 16; ++g) rdv[g] = *(const uint_a*)&SXY[g * 136 + 2 * l];
      float xr = 0.f, xi = 0.f;
#pragma unroll
      for (int g = 0; g < 16; ++g) {
        *(uint_a*)&SXY[g * 136 + 2 * l] =
            (unsigned int)f2bf(c2r * xr - c2i * xi) |
            ((unsigned int)f2bf(c2r * xi + c2i * xr) << 16);
        union { unsigned int u; float f; } lo, hi;
        lo.u = rdv[g] << 16;
        hi.u = rdv[g] & 0xffff0000u;
        const float nr = er * xr - ei * xi + lo.f;
        xi = er * xi + ei * xr + hi.f;
        xr = nr;
      }
    }
    asm volatile("" ::: "memory");

    // ---- qD loads (L2-warm; consumed after phase C -> latency covered) ----
    float qD[16];
    {
      const int qb = dk * S + 256 * q + l15;
#pragma unroll
      for (int tt = 0; tt < 4; ++tt)
#pragma unroll
        for (int v = 0; v < 4; ++v)
          qD[4 * tt + v] = QT[qb + 64 * v + 16 * tt];
    }

    // ---- phase C MFMAs (B-fragments in registers) ----
    floatx4 acc[4];
#pragma unroll
    for (int tt = 0; tt < 4; ++tt) acc[tt] = (floatx4){0.f, 0.f, 0.f, 0.f};
#pragma unroll
    for (int k = 0; k < 4; ++k) {
      const shortx8 xa = *(const shortx8_a*)&SXY[l15 * 136 + 8 * q + 32 * k];
#pragma unroll
      for (int tt = 0; tt < 4; ++tt)
        acc[tt] = __builtin_amdgcn_mfma_f32_16x16x32_bf16(xa, pcb[k][tt], acc[tt], 0, 0, 0);
    }
#pragma unroll
    for (int k = 0; k < 2; ++k) {
      const shortx8 ua = (k == 0) ? b0 : b1;
#pragma unroll
      for (int tt = 0; tt < 4; ++tt) {
        const int r = tt * 16 + l15;
        const int sSh = (4 - (r & 3)) & 3;
        const int addr = sSh * 136 + (64 - r - sSh) + 8 * q + 32 * k;
        const shortx4_a lo = *(const shortx4_a*)&kdSH[addr];
        const shortx4_a hi = *(const shortx4_a*)&kdSH[addr + 4];
        const shortx8 kb8 = __builtin_shufflevector(lo, hi, 0, 1, 2, 3, 4, 5, 6, 7);
        acc[tt] = __builtin_amdgcn_mfma_f32_16x16x32_bf16(ua, kb8, acc[tt], 0, 0, 0);
      }
    }
    // ---- accumulate O in D-layout ----
#pragma unroll
    for (int tt = 0; tt < 4; ++tt)
#pragma unroll
      for (int v = 0; v < 4; ++v)
        OaccD[tt][v] += qD[4 * tt + v] * acc[tt][v];
    // ---- rotate per-channel scalars ----
    c2r = nc2r; c2i = nc2i; kdv = nkdv; dd = ndd;
  }

  // ---- once-per-block: redistribute D-layout O to t-layout, fold dd-term ----
  asm volatile("" ::: "memory");
  {
    float_a* Ored = (float_a*)WB;  // padded [1028]: idx' = t + (t>>8)
#pragma unroll
    for (int tt = 0; tt < 4; ++tt)
#pragma unroll
      for (int v = 0; v < 4; ++v)
        Ored[256 * q + 64 * v + 16 * tt + l15 + q] = OaccD[tt][v];
    asm volatile("" ::: "memory");
    float4 Oa[4];
#pragma unroll
    for (int s = 0; s < 4; ++s) {
      const float4_a y4 = *(const float4_a*)&Ored[4 * l + 257 * s];
      Oa[s].x = y4.x + Odd[s].x;
      Oa[s].y = y4.y + Odd[s].y;
      Oa[s].z = y4.z + Odd[s].z;
      Oa[s].w = y4.w + Odd[s].w;
    }
    asm volatile("" ::: "memory");
#pragma unroll
    for (int s = 0; s < 4; ++s) {
      float4_a vv = {Oa[s].x, Oa[s].y, Oa[s].z, Oa[s].w};
      *(float4_a*)&Ored[4 * l + 256 * s] = vv;
    }
  }
  __syncthreads();
  {
    const int tq = 256 * w + 4 * l;
    float4_a acc = {0.f, 0.f, 0.f, 0.f};
#pragma unroll
    for (int w2 = 0; w2 < 4; ++w2) {
      const float_a* Ow2 = (const float_a*)(SHu + w2 * 4048);
      acc += *(const float4_a*)&Ow2[tq];
    }
    *(float4_a*)&OTout[dv * S + tq] = acc;
  }
}

// ====== L4: out[m][n] = sum_k (OT0+OT1)[k][m]*WO[n][k], bf16 hi/lo MFMA =====
__global__ __launch_bounds__(256) void gemm_outT(const float* __restrict__ OT,
                                                 const float* __restrict__ OT1,
                                                 const float* __restrict__ WO,
                                                 float* __restrict__ out) {
  __shared__ __align__(16) char LB[20480];
  unsigned short* Wh = (unsigned short*)LB;  // [64][40] WO planes
  unsigned short* Wl = Wh + 2560;
  unsigned short* Xh = Wl + 2560;            // [64][40] O1 planes (m rows)
  unsigned short* Xl = Xh + 2560;
  float_a* Ct = (float_a*)LB;                // [64][68] aliased
  const int tid = threadIdx.x;
  const int l = tid & 63, w = tid >> 6;
  const int l15 = l & 15, q = l >> 4;
  const int n0 = (blockIdx.x & 7) * 64, m0 = (blockIdx.x >> 3) * 64;

  floatx4 acc[4];
#pragma unroll
  for (int nt = 0; nt < 4; ++nt) acc[nt] = (floatx4){0.f, 0.f, 0.f, 0.f};

  for (int k0 = 0; k0 < D; k0 += 32) {
    if (k0) __syncthreads();
#pragma unroll
    for (int p = 0; p < 2; ++p) {
      const int idx = tid + 256 * p;
      // WO rows (n-local), k-contiguous
      {
        const int row = idx >> 3, c4 = (idx & 7) * 4;
        const float4 wv = *(const float4*)&WO[(n0 + row) * D + k0 + c4];
        unsigned short h0, h1, h2, h3, g0, g1, g2, g3;
        cvt_hilo(wv.x, h0, g0); cvt_hilo(wv.y, h1, g1);
        cvt_hilo(wv.z, h2, g2); cvt_hilo(wv.w, h3, g3);
        uint2_a hv = {(unsigned int)h0 | ((unsigned int)h1 << 16),
                      (unsigned int)h2 | ((unsigned int)h3 << 16)};
        uint2_a lv = {(unsigned int)g0 | ((unsigned int)g1 << 16),
                      (unsigned int)g2 | ((unsigned int)g3 << 16)};
        *(uint2_a*)&Wh[row * 40 + c4] = hv;
        *(uint2_a*)&Wl[row * 40 + c4] = lv;
      }
      // OT tile: read both halves [k][m] coalesced, sum, store transposed [m][k]
      {
        const int kk = idx >> 4, m4 = (idx & 15) * 4;
        const float4 o0 = *(const float4*)&OT[(k0 + kk) * S + m0 + m4];
        const float4 o1 = *(const float4*)&OT1[(k0 + kk) * S + m0 + m4];
        const float4 ov = make_float4(o0.x + o1.x, o0.y + o1.y,
                                      o0.z + o1.z, o0.w + o1.w);
        unsigned short h, g;
        cvt_hilo(ov.x, h, g); Xh[(m4 + 0) * 40 + kk] = h; Xl[(m4 + 0) * 40 + kk] = g;
        cvt_hilo(ov.y, h, g); Xh[(m4 + 1) * 40 + kk] = h; Xl[(m4 + 1) * 40 + kk] = g;
        cvt_hilo(ov.z, h, g); Xh[(m4 + 2) * 40 + kk] = h; Xl[(m4 + 2) * 40 + kk] = g;
        cvt_hilo(ov.w, h, g); Xh[(m4 + 3) * 40 + kk] = h; Xl[(m4 + 3) * 40 + kk] = g;
      }
    }
    __syncthreads();
    const shortx8 xh = *(const shortx8_a*)&Xh[(16 * w + l15) * 40 + 8 * q];
    const shortx8 xl = *(const shortx8_a*)&Xl[(16 * w + l15) * 40 + 8 * q];
#pragma unroll
    for (int nt = 0; nt < 4; ++nt) {
      const shortx8 wh = *(const shortx8_a*)&Wh[(16 * nt + l15) * 40 + 8 * q];
      const shortx8 wl = *(const shortx8_a*)&Wl[(16 * nt + l15) * 40 + 8 * q];
      acc[nt] = __builtin_amdgcn_mfma_f32_16x16x32_bf16(wh, xh, acc[nt], 0, 0, 0);
      acc[nt] = __builtin_amdgcn_mfma_f32_16x16x32_bf16(wh, xl, acc[nt], 0, 0, 0);
      acc[nt] = __builtin_amdgcn_mfma_f32_16x16x32_bf16(wl, xh, acc[nt], 0, 0, 0);
    }
  }
  __syncthreads();
  // lane holds D[n = 16nt+4q+v][m = 16w+l15] -> Ct[m][n]
#pragma unroll
  for (int nt = 0; nt < 4; ++nt)
#pragma unroll
    for (int v = 0; v < 4; ++v)
      Ct[(16 * w + l15) * 68 + 16 * nt + 4 * q + v] = acc[nt][v];
  __syncthreads();
#pragma unroll
  for (int p = 0; p < 4; ++p) {
    const int row = (tid >> 4) + 16 * p;
    const int col4 = (tid & 15) * 4;
    *(float4_a*)&out[(m0 + row) * D + n0 + col4] = *(const float4_a*)&Ct[row * 68 + col4];
  }
}

extern "C" void kernel_launch(void* const* d_in, const int* in_sizes, int n_in,
                              void* d_out, int out_size, void* d_ws, size_t ws_size,
                              hipStream_t stream) {
  const float* x   = (const float*)d_in[0];
  const float* WQ  = (const float*)d_in[1];
  const float* WK  = (const float*)d_in[2];
  const float* WV  = (const float*)d_in[3];
  const float* WO  = (const float*)d_in[4];
  const float* Cs  = (const float*)d_in[5];
  const float* Ds  = (const float*)d_in[6];
  const float* Are = (const float*)d_in[7];
  const float* Aim = (const float*)d_in[8];
  const float* Cre = (const float*)d_in[9];
  const float* Cim = (const float*)d_in[10];
  const float* Dd  = (const float*)d_in[11];
  float* out = (float*)d_out;

  char* ws = (char*)d_ws;
  const size_t SD = (size_t)S * D * 4;   // 2 MB
  float* QT    = (float*)(ws + 0 * SD);
  float* KrawT = (float*)(ws + 1 * SD);  // dead after shift_ssmT -> reused as OT1
  float* VT    = (float*)(ws + 2 * SD);
  float* KnT   = (float*)(ws + 3 * SD);
  float* OT    = (float*)(ws + 4 * SD);
  float* OT1   = KrawT;
  unsigned short* cb2pack = (unsigned short*)(ws + 5 * SD);            // 8 MB
  unsigned short* kdpack  = (unsigned short*)(ws + 5 * SD + 8388608);  // 8 MB

  fused_qkv_cbkd<<<384 + CD / 16, 256, 0, stream>>>(
      x, WQ, WK, WV, Are, Aim, Cre, Cim, QT, KrawT, VT, cb2pack, kdpack);
  shift_ssmT<<<512, 256, 0, stream>>>(KrawT, Cs, Ds, KnT);
  s4d_fused<<<1024, 256, 0, stream>>>(KnT, VT, QT, Are, Aim, cb2pack, kdpack, Dd, OT, OT1);
  gemm_outT<<<128, 256, 0, stream>>>(OT, OT1, WO, out);
}

// Round 4
// 190.272 us; speedup vs baseline: 1.7754x; 1.7754x over previous
//
#include <hip/hip_runtime.h>

#define S 1024
#define D 512
#define HID 64
#define CD 32768
#define DT 0.1f

typedef __attribute__((ext_vector_type(4))) float floatx4;
typedef __attribute__((ext_vector_type(8))) short shortx8;
// may_alias variants for type-punned LDS/global access (TBAA-safe)
typedef short shortx8_a __attribute__((ext_vector_type(8), may_alias));
typedef short shortx4_a __attribute__((ext_vector_type(4), may_alias));
typedef unsigned int uint_a __attribute__((may_alias));
typedef unsigned int uint2_a __attribute__((ext_vector_type(2), may_alias));
typedef unsigned int uint4_a __attribute__((ext_vector_type(4), may_alias));
typedef float float4_a __attribute__((ext_vector_type(4), may_alias));
typedef float float_a __attribute__((may_alias));

__device__ __forceinline__ unsigned short f2bf(float f) {
  union { float f; unsigned int u; } v;
  v.f = f;
  unsigned int r = v.u + 0x7FFFu + ((v.u >> 16) & 1u);
  return (unsigned short)(r >> 16);
}
__device__ __forceinline__ float bf2f(unsigned short h) {
  union { unsigned int u; float f; } v;
  v.u = ((unsigned int)h) << 16;
  return v.f;
}
// hi/lo split: v ~= bf2f(h) + bf2f(lo), ~16-bit mantissa accuracy
__device__ __forceinline__ void cvt_hilo(float v, unsigned short& h, unsigned short& lo) {
  h = f2bf(v);
  lo = f2bf(v - bf2f(h));
}

// =====================  L1: fused QKV-GEMM + cbkd  ==========================
// blocks [0,384): {Q,Kraw,V}T[n][m] = sum_k x[m][k]*W[n][k] via bf16 hi/lo MFMA
// blocks [384,2432): per-16-channel cb2 + kd build (inline dA-power table)
__global__ __launch_bounds__(256) void fused_qkv_cbkd(
    const float* __restrict__ x, const float* __restrict__ WQ,
    const float* __restrict__ WK, const float* __restrict__ WV,
    const float* __restrict__ Are, const float* __restrict__ Aim,
    const float* __restrict__ Cre, const float* __restrict__ Cim,
    float* __restrict__ QT, float* __restrict__ KrawT, float* __restrict__ VT,
    unsigned short* __restrict__ cb2pack, unsigned short* __restrict__ kdpack) {
  __shared__ __align__(16) char LB[21760];
  const int tid = threadIdx.x;
  const int bid = blockIdx.x;
  const int l = tid & 63, w = tid >> 6;
  const int l15 = l & 15, q = l >> 4;

  if (bid < 384) {
    // ---------------- QKV GEMM: 64x64 tile, K=512, BK=32 ----------------
    unsigned short* Wh = (unsigned short*)LB;     // [64][40]
    unsigned short* Wl = Wh + 2560;
    unsigned short* Xh = Wl + 2560;
    unsigned short* Xl = Xh + 2560;
    float_a* Ct = (float_a*)LB;                   // [64][68], aliased after loop
    const int mat = bid >> 7;                     // /128
    const int rem = bid & 127;
    const int n0 = (rem & 7) * 64, m0 = (rem >> 3) * 64;
    const float* Wsel = (mat == 0) ? WQ : (mat == 1) ? WK : WV;
    float* CT = (mat == 0) ? QT : (mat == 1) ? KrawT : VT;

    floatx4 acc[4];
#pragma unroll
    for (int nt = 0; nt < 4; ++nt) acc[nt] = (floatx4){0.f, 0.f, 0.f, 0.f};

    for (int k0 = 0; k0 < D; k0 += 32) {
      if (k0) __syncthreads();
#pragma unroll
      for (int p = 0; p < 2; ++p) {
        const int idx = tid + 256 * p;
        const int row = idx >> 3, c4 = (idx & 7) * 4;
        const float4 wv = *(const float4*)&Wsel[(n0 + row) * D + k0 + c4];
        const float4 xv = *(const float4*)&x[(m0 + row) * D + k0 + c4];
        unsigned short h0, h1, h2, h3, g0, g1, g2, g3;
        cvt_hilo(wv.x, h0, g0); cvt_hilo(wv.y, h1, g1);
        cvt_hilo(wv.z, h2, g2); cvt_hilo(wv.w, h3, g3);
        uint2_a hv = {(unsigned int)h0 | ((unsigned int)h1 << 16),
                      (unsigned int)h2 | ((unsigned int)h3 << 16)};
        uint2_a lv = {(unsigned int)g0 | ((unsigned int)g1 << 16),
                      (unsigned int)g2 | ((unsigned int)g3 << 16)};
        *(uint2_a*)&Wh[row * 40 + c4] = hv;
        *(uint2_a*)&Wl[row * 40 + c4] = lv;
        cvt_hilo(xv.x, h0, g0); cvt_hilo(xv.y, h1, g1);
        cvt_hilo(xv.z, h2, g2); cvt_hilo(xv.w, h3, g3);
        uint2_a hv2 = {(unsigned int)h0 | ((unsigned int)h1 << 16),
                       (unsigned int)h2 | ((unsigned int)h3 << 16)};
        uint2_a lv2 = {(unsigned int)g0 | ((unsigned int)g1 << 16),
                       (unsigned int)g2 | ((unsigned int)g3 << 16)};
        *(uint2_a*)&Xh[row * 40 + c4] = hv2;
        *(uint2_a*)&Xl[row * 40 + c4] = lv2;
      }
      __syncthreads();
      const shortx8 xh = *(const shortx8_a*)&Xh[(16 * w + l15) * 40 + 8 * q];
      const shortx8 xl = *(const shortx8_a*)&Xl[(16 * w + l15) * 40 + 8 * q];
#pragma unroll
      for (int nt = 0; nt < 4; ++nt) {
        const shortx8 wh = *(const shortx8_a*)&Wh[(16 * nt + l15) * 40 + 8 * q];
        const shortx8 wl = *(const shortx8_a*)&Wl[(16 * nt + l15) * 40 + 8 * q];
        acc[nt] = __builtin_amdgcn_mfma_f32_16x16x32_bf16(wh, xh, acc[nt], 0, 0, 0);
        acc[nt] = __builtin_amdgcn_mfma_f32_16x16x32_bf16(wh, xl, acc[nt], 0, 0, 0);
        acc[nt] = __builtin_amdgcn_mfma_f32_16x16x32_bf16(wl, xh, acc[nt], 0, 0, 0);
      }
    }
    __syncthreads();
    // lane holds D[n = 16nt+4q+v][m = 16w+l15] -> Ct[n][m]
#pragma unroll
    for (int nt = 0; nt < 4; ++nt)
#pragma unroll
      for (int v = 0; v < 4; ++v)
        Ct[(16 * nt + 4 * q + v) * 68 + 16 * w + l15] = acc[nt][v];
    __syncthreads();
#pragma unroll
    for (int p = 0; p < 4; ++p) {
      const int row = (tid >> 4) + 16 * p;
      const int col4 = (tid & 15) * 4;
      *(float4_a*)&CT[(n0 + row) * S + m0 + col4] = *(const float4_a*)&Ct[row * 68 + col4];
    }
  } else {
    // ---------------- cbkd: c0 = (bid-384)*16 ----------------
    unsigned short* cbs = (unsigned short*)LB;          // [16][136]
    unsigned short* PCc2s = (unsigned short*)(LB + 4352);  // [64][136]
    const int c0 = (bid - 384) << 4;
    // inline PCc2 table build: thread (n=l, seg=w)
    {
      const int n = l, seg = w;
      const float ar = Are[n], ai = Aim[n];
      const float den_re = 1.0f - 0.05f * ar;
      const float den_im = -0.05f * ai;
      const float num_re = 1.0f + 0.05f * ar;
      const float num_im = 0.05f * ai;
      const float inv_d2 = 1.0f / (den_re * den_re + den_im * den_im);
      const float dAr = (num_re * den_re + num_im * den_im) * inv_d2;
      const float dAi = (num_im * den_re - num_re * den_im) * inv_d2;
      float e2r = dAr * dAr - dAi * dAi, e2i = 2.0f * dAr * dAi;
      float e4r = e2r * e2r - e2i * e2i, e4i = 2.0f * e2r * e2i;
      float e8r = e4r * e4r - e4i * e4i, e8i = 2.0f * e4r * e4i;
      float e16r = e8r * e8r - e8i * e8i, e16i = 2.0f * e8r * e8i;
      float br = 1.0f, bi = 0.0f;
      for (int sgo = 0; sgo < seg; ++sgo) {
        const float nr = br * e16r - bi * e16i;
        bi = br * e16i + bi * e16r;
        br = nr;
      }
      float pr = br, pi = bi;
      for (int k = 16 * seg + 1; k <= 16 * seg + 16; ++k) {
        const float nr = pr * dAr - pi * dAi;
        pi = pr * dAi + pi * dAr;
        pr = nr;
        if (k <= 63) {
          PCc2s[k * 136 + n] = f2bf(pr);
          PCc2s[k * 136 + 64 + n] = f2bf(-pi);
        }
      }
      if (seg == 0) {
        PCc2s[n] = f2bf(1.0f);
        PCc2s[64 + n] = 0;
      }
    }
    // cb2 build
#pragma unroll
    for (int ii = 0; ii < 4; ++ii) {
      const int idx = tid + 256 * ii;
      const int ci = idx >> 6, n = idx & 63;
      const int c = c0 + ci;
      const float ar = Are[n], ai = Aim[n];
      const float den_re = 1.0f - 0.05f * ar;
      const float den_im = -0.05f * ai;
      const float inv_d2 = 1.0f / (den_re * den_re + den_im * den_im);
      const float dBr = DT * den_re * inv_d2;
      const float dBi = -DT * den_im * inv_d2;
      const float cr = Cre[c * HID + n], cim = Cim[c * HID + n];
      const unsigned short re = f2bf(2.0f * (cr * dBr - cim * dBi));
      const unsigned short im = f2bf(2.0f * (cr * dBi + cim * dBr));
      cbs[ci * 136 + n] = re;
      cbs[ci * 136 + 64 + n] = im;
      cb2pack[c * 128 + n] = re;
      cb2pack[c * 128 + 64 + n] = im;
    }
    __syncthreads();
    // kd GEMM -> kdpack (kdR layout)
    floatx4 acc = {0.f, 0.f, 0.f, 0.f};
#pragma unroll
    for (int k = 0; k < 4; ++k) {
      const shortx8 a = *(const shortx8_a*)&cbs[l15 * 136 + 8 * q + 32 * k];
      const shortx8 b = *(const shortx8_a*)&PCc2s[(16 * w + l15) * 136 + 8 * q + 32 * k];
      acc = __builtin_amdgcn_mfma_f32_16x16x32_bf16(a, b, acc, 0, 0, 0);
    }
    const int dlt = 16 * w + l15;
#pragma unroll
    for (int v = 0; v < 4; ++v)
      kdpack[(c0 + 4 * q + v) * 128 + 64 - dlt] = f2bf(acc[v]);
    const int row = tid >> 4, p = tid & 15;
#pragma unroll
    for (int k2 = 0; k2 < 4; ++k2) {
      const int idx = p + 16 * k2;
      const int m = (idx == 0) ? 0 : 64 + idx;
      kdpack[(c0 + row) * 128 + m] = 0;
    }
  }
}

// ======= L2: shift SSM, [d][t] domain, taps via scalar loads ================
__global__ __launch_bounds__(256) void shift_ssmT(const float* __restrict__ KrawT,
                                                  const float* __restrict__ Cs,
                                                  const float* __restrict__ Ds,
                                                  float* __restrict__ KnT) {
  __shared__ float kpad[64 + S];
  const int d = blockIdx.x, tid = threadIdx.x;
  if (tid < 64) kpad[tid] = 0.0f;
  *(float4_a*)&kpad[64 + 4 * tid] = *(const float4_a*)&KrawT[d * S + 4 * tid];
  const float dskip = Ds[d];
  const float* taps = Cs + d * HID;  // block-uniform -> scalar loads
  __syncthreads();
  float acc[4];
#pragma unroll
  for (int s = 0; s < 4; ++s) acc[s] = dskip * kpad[64 + tid + 256 * s];
  for (int j = 0; j < 64; ++j) {
    const float tj = taps[j];
#pragma unroll
    for (int s = 0; s < 4; ++s) acc[s] += tj * kpad[64 + tid + 256 * s - j];
  }
#pragma unroll
  for (int s = 0; s < 4; ++s) KnT[d * S + tid + 256 * s] = acc[s];
}

// =============== L3: s4d_fused (channel-split, natural regalloc) ============
// Round-4 changes vs round 3:
//  * KEEP the grid-1024 channel split (it reached 44% occupancy even while
//    spilling — the split works).
//  * REVERT __launch_bounds__ to (256,2): round-3's (256,4) capped the
//    unified VGPR+AGPR budget at 128 total -> compiler allocated 64 arch
//    VGPRs -> massive scratch spill (FETCH_SIZE 26->537 MB, dur 57->203us).
//    With cap 256 the allocator naturally chooses 128 (round-2 evidence),
//    which is exactly the 4-blocks/CU occupancy step (16 waves/CU), and
//    LDS 4x36352=142KB also fits 4 blocks/CU.
__global__ __launch_bounds__(256, 2) void s4d_fused(
    const float* __restrict__ KnT, const float* __restrict__ VT,
    const float* __restrict__ QT,
    const float* __restrict__ Are, const float* __restrict__ Aim,
    const unsigned short* __restrict__ cb2pack,
    const unsigned short* __restrict__ kdpack,
    const float* __restrict__ Dd, float* __restrict__ OT,
    float* __restrict__ OT1) {
  __shared__ __align__(16) unsigned short SHu[18176];  // 36352 B
  const int tid = threadIdx.x;
  const int l = tid & 63, w = tid >> 6;
  const int l15 = l & 15, q = l >> 4;
  const int half = blockIdx.x & 1;
  const int dv = blockIdx.x >> 1;            // 0..511 (halves adjacent: L2 share)
  const int h = dv >> 6, j = dv & 63;
  float* __restrict__ OTout = half ? OT1 : OT;

  // ---- inline table build: PAre/PAim [n][72], PCc [64][136] interleaved, dA64 ----
  {
    const int n = l, seg = w;
    unsigned short* PAreW = SHu;
    unsigned short* PAimW = SHu + 4608;
    unsigned short* PCcW = SHu + 9216;
    float_a* dA64W = (float_a*)(SHu + 17920);
    const float ar = Are[n], ai = Aim[n];
    const float den_re = 1.0f - 0.05f * ar;
    const float den_im = -0.05f * ai;
    const float num_re = 1.0f + 0.05f * ar;
    const float num_im = 0.05f * ai;
    const float inv_d2 = 1.0f / (den_re * den_re + den_im * den_im);
    const float dAr = (num_re * den_re + num_im * den_im) * inv_d2;
    const float dAi = (num_im * den_re - num_re * den_im) * inv_d2;
    float e2r = dAr * dAr - dAi * dAi, e2i = 2.0f * dAr * dAi;
    float e4r = e2r * e2r - e2i * e2i, e4i = 2.0f * e2r * e2i;
    float e8r = e4r * e4r - e4i * e4i, e8i = 2.0f * e4r * e4i;
    float e16r = e8r * e8r - e8i * e8i, e16i = 2.0f * e8r * e8i;
    float br = 1.0f, bi = 0.0f;
    for (int sgo = 0; sgo < seg; ++sgo) {
      const float nr = br * e16r - bi * e16i;
      bi = br * e16i + bi * e16r;
      br = nr;
    }
    float pr = br, pi = bi;
    for (int k = 16 * seg + 1; k <= 16 * seg + 16; ++k) {
      const float nr = pr * dAr - pi * dAi;
      pi = pr * dAi + pi * dAr;
      pr = nr;
      if (k <= 63) {
        PAreW[n * 72 + 63 - k] = f2bf(pr);
        PAimW[n * 72 + 63 - k] = f2bf(pi);
      }
      // interleaved (re, -im) pairs at columns 2n, 2n+1
      PCcW[(k - 1) * 136 + 2 * n] = f2bf(pr);
      PCcW[(k - 1) * 136 + 2 * n + 1] = f2bf(-pi);
      if (k == 64) {
        dA64W[2 * n] = pr;
        dA64W[2 * n + 1] = pi;
      }
    }
    if (seg == 0) {
      PAreW[n * 72 + 63] = f2bf(1.0f);
      PAimW[n * 72 + 63] = 0;
    }
  }
  // ---- V row slice in registers ----
  float4 vvr[4];
#pragma unroll
  for (int s = 0; s < 4; ++s)
    vvr[s] = *(const float4*)&VT[dv * S + 4 * l + 256 * s];

  // ---- initial per-channel scalar prefetch (channel i = half*32 + w) ----
  float c2r, c2i, dd;
  unsigned int kdv;
  {
    const int c = (h << 12) + ((half * 32 + w) << 6) + j;
    c2r = bf2f(cb2pack[c * 128 + l]);
    c2i = bf2f(cb2pack[c * 128 + 64 + l]);
    kdv = *(const uint_a*)&kdpack[c * 128 + 2 * l];
    dd = Dd[c];
  }
  __syncthreads();

  // ---- hoist table fragments into registers (once per block) ----
  const unsigned short* PAre = SHu;
  const unsigned short* PAim = SHu + 4608;
  const unsigned short* PCc = SHu + 9216;
  const float_a* dA64v = (const float_a*)(SHu + 17920);
  const float er = dA64v[2 * l], ei = dA64v[2 * l + 1];
  shortx8 paR[4][2], paI[4][2];
#pragma unroll
  for (int tt = 0; tt < 4; ++tt) {
    const int rowb = (tt * 16 + l15) * 72 + 8 * q;
    paR[tt][0] = *(const shortx8_a*)&PAre[rowb];
    paR[tt][1] = *(const shortx8_a*)&PAre[rowb + 32];
    paI[tt][0] = *(const shortx8_a*)&PAim[rowb];
    paI[tt][1] = *(const shortx8_a*)&PAim[rowb + 32];
  }
  shortx8 pcb[4][4];
#pragma unroll
  for (int k = 0; k < 4; ++k)
#pragma unroll
    for (int tt = 0; tt < 4; ++tt)
      pcb[k][tt] = *(const shortx8_a*)&PCc[(tt * 16 + l15) * 136 + 8 * q + 32 * k];
  __syncthreads();  // all table reads done before workspace aliases tables

  // ---- per-wave workspace, aliased over the table region ----
  unsigned short* WB = SHu + w * 4048;
  unsigned short* Ub = WB;                    // [16][72] bf16
  unsigned short* SXY = WB + 1152;            // [16][136]: Sc -> Xcb interleaved
  uint_a* kdR32 = (uint_a*)(WB + 3328);       // 68 uints (+pad)
  unsigned short* kdSH = WB + 3472;           // [4][136]

  floatx4 OaccD[4];
  float4 Odd[4];
#pragma unroll
  for (int tt = 0; tt < 4; ++tt) OaccD[tt] = (floatx4){0.f, 0.f, 0.f, 0.f};
#pragma unroll
  for (int s = 0; s < 4; ++s) Odd[s] = make_float4(0.f, 0.f, 0.f, 0.f);

#pragma unroll 1
  for (int itl = 0; itl < 8; ++itl) {
    // ---- prefetch next channel's HBM-cold scalars ----
    float nc2r = 0.f, nc2i = 0.f, ndd = 0.f;
    unsigned int nkdv = 0;
    if (itl < 7) {
      const int c = (h << 12) + ((half * 32 + (itl + 1) * 4 + w) << 6) + j;
      nc2r = bf2f(cb2pack[c * 128 + l]);
      nc2i = bf2f(cb2pack[c * 128 + 64 + l]);
      nkdv = *(const uint_a*)&kdpack[c * 128 + 2 * l];
      ndd = Dd[c];
    }
    // ---- current-channel row loads (L2-warm: shared across 64 j-blocks) ----
    const int dk = (h << 6) + half * 32 + itl * 4 + w;
    const int kb = dk * S + 4 * l;
    float4 kx[4], qtv[4];
#pragma unroll
    for (int s = 0; s < 4; ++s) {
      kx[s] = *(const float4*)&KnT[kb + 256 * s];
      qtv[s] = *(const float4*)&QT[kb + 256 * s];
    }

    // ---- kdR + 4 shifted copies (uses prefetched kdv; covers row loads) ----
    kdR32[l] = kdv;
    if (l < 4) kdR32[64 + l] = 0;
    asm volatile("" ::: "memory");
#pragma unroll
    for (int s2 = 0; s2 < 4; ++s2) {
      unsigned int v;
      if (s2 == 0) {
        v = kdR32[l];
      } else if (s2 == 1) {
        v = (kdR32[l] >> 16) | (kdR32[l + 1] << 16);
      } else if (s2 == 2) {
        v = kdR32[l + 1];
      } else {
        v = (kdR32[l + 1] >> 16) | (kdR32[l + 2] << 16);
      }
      *(uint_a*)&kdSH[s2 * 136 + 2 * l] = v;
    }
    asm volatile("" ::: "memory");

    // ---- u fill + dd-skip accumulation (kx/qtv die here) ----
#pragma unroll
    for (int s = 0; s < 4; ++s) {
      const int t = 4 * l + 256 * s;
      const int g = t >> 6, r = t & 63;
      const float ux = kx[s].x * vvr[s].x;
      const float uy = kx[s].y * vvr[s].y;
      const float uz = kx[s].z * vvr[s].z;
      const float uw = kx[s].w * vvr[s].w;
      uint2_a pp;
      pp.x = (unsigned int)f2bf(ux) | ((unsigned int)f2bf(uy) << 16);
      pp.y = (unsigned int)f2bf(uz) | ((unsigned int)f2bf(uw) << 16);
      *(uint2_a*)&Ub[g * 72 + r] = pp;
      Odd[s].x += dd * qtv[s].x * ux;
      Odd[s].y += dd * qtv[s].y * uy;
      Odd[s].z += dd * qtv[s].z * uz;
      Odd[s].w += dd * qtv[s].w * uw;
    }
    asm volatile("" ::: "memory");

    // ---- phase A: s~[g][n] via MFMA (A-fragments in registers) ----
    const shortx8 b0 = *(const shortx8_a*)&Ub[l15 * 72 + 8 * q];
    const shortx8 b1 = *(const shortx8_a*)&Ub[l15 * 72 + 8 * q + 32];
#pragma unroll
    for (int tt = 0; tt < 4; ++tt) {
      floatx4 z = {0.f, 0.f, 0.f, 0.f};
      floatx4 sre = __builtin_amdgcn_mfma_f32_16x16x32_bf16(paR[tt][0], b0, z, 0, 0, 0);
      sre = __builtin_amdgcn_mfma_f32_16x16x32_bf16(paR[tt][1], b1, sre, 0, 0, 0);
      floatx4 sim = __builtin_amdgcn_mfma_f32_16x16x32_bf16(paI[tt][0], b0, z, 0, 0, 0);
      sim = __builtin_amdgcn_mfma_f32_16x16x32_bf16(paI[tt][1], b1, sim, 0, 0, 0);
      // interleaved: row g=l15, columns 2n..2n+7 for n = tt*16+4q+(0..3)
      uint4_a wv;
      wv[0] = (unsigned int)f2bf(sre[0]) | ((unsigned int)f2bf(sim[0]) << 16);
      wv[1] = (unsigned int)f2bf(sre[1]) | ((unsigned int)f2bf(sim[1]) << 16);
      wv[2] = (unsigned int)f2bf(sre[2]) | ((unsigned int)f2bf(sim[2]) << 16);
      wv[3] = (unsigned int)f2bf(sre[3]) | ((unsigned int)f2bf(sim[3]) << 16);
      *(uint4_a*)&SXY[l15 * 136 + 32 * tt + 8 * q] = wv;
    }
    asm volatile("" ::: "memory");

    // ---- register scan: batch-load packed Sc, pure-VALU recurrence ----
    {
      unsigned int rdv[16];
#pragma unroll
      for (int g = 0; g < 16; ++g) rdv[g] = *(const uint_a*)&SXY[g * 136 + 2 * l];
      float xr = 0.f, xi = 0.f;
#pragma unroll
      for (int g = 0; g < 16; ++g) {
        *(uint_a*)&SXY[g * 136 + 2 * l] =
            (unsigned int)f2bf(c2r * xr - c2i * xi) |
            ((unsigned int)f2bf(c2r * xi + c2i * xr) << 16);
        union { unsigned int u; float f; } lo, hi;
        lo.u = rdv[g] << 16;
        hi.u = rdv[g] & 0xffff0000u;
        const float nr = er * xr - ei * xi + lo.f;
        xi = er * xi + ei * xr + hi.f;
        xr = nr;
      }
    }
    asm volatile("" ::: "memory");

    // ---- qD loads (L2-warm; consumed after phase C -> latency covered) ----
    float qD[16];
    {
      const int qb = dk * S + 256 * q + l15;
#pragma unroll
      for (int tt = 0; tt < 4; ++tt)
#pragma unroll
        for (int v = 0; v < 4; ++v)
          qD[4 * tt + v] = QT[qb + 64 * v + 16 * tt];
    }

    // ---- phase C MFMAs (B-fragments in registers) ----
    floatx4 acc[4];
#pragma unroll
    for (int tt = 0; tt < 4; ++tt) acc[tt] = (floatx4){0.f, 0.f, 0.f, 0.f};
#pragma unroll
    for (int k = 0; k < 4; ++k) {
      const shortx8 xa = *(const shortx8_a*)&SXY[l15 * 136 + 8 * q + 32 * k];
#pragma unroll
      for (int tt = 0; tt < 4; ++tt)
        acc[tt] = __builtin_amdgcn_mfma_f32_16x16x32_bf16(xa, pcb[k][tt], acc[tt], 0, 0, 0);
    }
#pragma unroll
    for (int k = 0; k < 2; ++k) {
      const shortx8 ua = (k == 0) ? b0 : b1;
#pragma unroll
      for (int tt = 0; tt < 4; ++tt) {
        const int r = tt * 16 + l15;
        const int sSh = (4 - (r & 3)) & 3;
        const int addr = sSh * 136 + (64 - r - sSh) + 8 * q + 32 * k;
        const shortx4_a lo = *(const shortx4_a*)&kdSH[addr];
        const shortx4_a hi = *(const shortx4_a*)&kdSH[addr + 4];
        const shortx8 kb8 = __builtin_shufflevector(lo, hi, 0, 1, 2, 3, 4, 5, 6, 7);
        acc[tt] = __builtin_amdgcn_mfma_f32_16x16x32_bf16(ua, kb8, acc[tt], 0, 0, 0);
      }
    }
    // ---- accumulate O in D-layout ----
#pragma unroll
    for (int tt = 0; tt < 4; ++tt)
#pragma unroll
      for (int v = 0; v < 4; ++v)
        OaccD[tt][v] += qD[4 * tt + v] * acc[tt][v];
    // ---- rotate per-channel scalars ----
    c2r = nc2r; c2i = nc2i; kdv = nkdv; dd = ndd;
  }

  // ---- once-per-block: redistribute D-layout O to t-layout, fold dd-term ----
  asm volatile("" ::: "memory");
  {
    float_a* Ored = (float_a*)WB;  // padded [1028]: idx' = t + (t>>8)
#pragma unroll
    for (int tt = 0; tt < 4; ++tt)
#pragma unroll
      for (int v = 0; v < 4; ++v)
        Ored[256 * q + 64 * v + 16 * tt + l15 + q] = OaccD[tt][v];
    asm volatile("" ::: "memory");
    float4 Oa[4];
#pragma unroll
    for (int s = 0; s < 4; ++s) {
      const float4_a y4 = *(const float4_a*)&Ored[4 * l + 257 * s];
      Oa[s].x = y4.x + Odd[s].x;
      Oa[s].y = y4.y + Odd[s].y;
      Oa[s].z = y4.z + Odd[s].z;
      Oa[s].w = y4.w + Odd[s].w;
    }
    asm volatile("" ::: "memory");
#pragma unroll
    for (int s = 0; s < 4; ++s) {
      float4_a vv = {Oa[s].x, Oa[s].y, Oa[s].z, Oa[s].w};
      *(float4_a*)&Ored[4 * l + 256 * s] = vv;
    }
  }
  __syncthreads();
  {
    const int tq = 256 * w + 4 * l;
    float4_a acc = {0.f, 0.f, 0.f, 0.f};
#pragma unroll
    for (int w2 = 0; w2 < 4; ++w2) {
      const float_a* Ow2 = (const float_a*)(SHu + w2 * 4048);
      acc += *(const float4_a*)&Ow2[tq];
    }
    *(float4_a*)&OTout[dv * S + tq] = acc;
  }
}

// ====== L4: out[m][n] = sum_k (OT0+OT1)[k][m]*WO[n][k], bf16 hi/lo MFMA =====
__global__ __launch_bounds__(256) void gemm_outT(const float* __restrict__ OT,
                                                 const float* __restrict__ OT1,
                                                 const float* __restrict__ WO,
                                                 float* __restrict__ out) {
  __shared__ __align__(16) char LB[20480];
  unsigned short* Wh = (unsigned short*)LB;  // [64][40] WO planes
  unsigned short* Wl = Wh + 2560;
  unsigned short* Xh = Wl + 2560;            // [64][40] O1 planes (m rows)
  unsigned short* Xl = Xh + 2560;
  float_a* Ct = (float_a*)LB;                // [64][68] aliased
  const int tid = threadIdx.x;
  const int l = tid & 63, w = tid >> 6;
  const int l15 = l & 15, q = l >> 4;
  const int n0 = (blockIdx.x & 7) * 64, m0 = (blockIdx.x >> 3) * 64;

  floatx4 acc[4];
#pragma unroll
  for (int nt = 0; nt < 4; ++nt) acc[nt] = (floatx4){0.f, 0.f, 0.f, 0.f};

  for (int k0 = 0; k0 < D; k0 += 32) {
    if (k0) __syncthreads();
#pragma unroll
    for (int p = 0; p < 2; ++p) {
      const int idx = tid + 256 * p;
      // WO rows (n-local), k-contiguous
      {
        const int row = idx >> 3, c4 = (idx & 7) * 4;
        const float4 wv = *(const float4*)&WO[(n0 + row) * D + k0 + c4];
        unsigned short h0, h1, h2, h3, g0, g1, g2, g3;
        cvt_hilo(wv.x, h0, g0); cvt_hilo(wv.y, h1, g1);
        cvt_hilo(wv.z, h2, g2); cvt_hilo(wv.w, h3, g3);
        uint2_a hv = {(unsigned int)h0 | ((unsigned int)h1 << 16),
                      (unsigned int)h2 | ((unsigned int)h3 << 16)};
        uint2_a lv = {(unsigned int)g0 | ((unsigned int)g1 << 16),
                      (unsigned int)g2 | ((unsigned int)g3 << 16)};
        *(uint2_a*)&Wh[row * 40 + c4] = hv;
        *(uint2_a*)&Wl[row * 40 + c4] = lv;
      }
      // OT tile: read both halves [k][m] coalesced, sum, store transposed [m][k]
      {
        const int kk = idx >> 4, m4 = (idx & 15) * 4;
        const float4 o0 = *(const float4*)&OT[(k0 + kk) * S + m0 + m4];
        const float4 o1 = *(const float4*)&OT1[(k0 + kk) * S + m0 + m4];
        const float4 ov = make_float4(o0.x + o1.x, o0.y + o1.y,
                                      o0.z + o1.z, o0.w + o1.w);
        unsigned short h, g;
        cvt_hilo(ov.x, h, g); Xh[(m4 + 0) * 40 + kk] = h; Xl[(m4 + 0) * 40 + kk] = g;
        cvt_hilo(ov.y, h, g); Xh[(m4 + 1) * 40 + kk] = h; Xl[(m4 + 1) * 40 + kk] = g;
        cvt_hilo(ov.z, h, g); Xh[(m4 + 2) * 40 + kk] = h; Xl[(m4 + 2) * 40 + kk] = g;
        cvt_hilo(ov.w, h, g); Xh[(m4 + 3) * 40 + kk] = h; Xl[(m4 + 3) * 40 + kk] = g;
      }
    }
    __syncthreads();
    const shortx8 xh = *(const shortx8_a*)&Xh[(16 * w + l15) * 40 + 8 * q];
    const shortx8 xl = *(const shortx8_a*)&Xl[(16 * w + l15) * 40 + 8 * q];
#pragma unroll
    for (int nt = 0; nt < 4; ++nt) {
      const shortx8 wh = *(const shortx8_a*)&Wh[(16 * nt + l15) * 40 + 8 * q];
      const shortx8 wl = *(const shortx8_a*)&Wl[(16 * nt + l15) * 40 + 8 * q];
      acc[nt] = __builtin_amdgcn_mfma_f32_16x16x32_bf16(wh, xh, acc[nt], 0, 0, 0);
      acc[nt] = __builtin_amdgcn_mfma_f32_16x16x32_bf16(wh, xl, acc[nt], 0, 0, 0);
      acc[nt] = __builtin_amdgcn_mfma_f32_16x16x32_bf16(wl, xh, acc[nt], 0, 0, 0);
    }
  }
  __syncthreads();
  // lane holds D[n = 16nt+4q+v][m = 16w+l15] -> Ct[m][n]
#pragma unroll
  for (int nt = 0; nt < 4; ++nt)
#pragma unroll
    for (int v = 0; v < 4; ++v)
      Ct[(16 * w + l15) * 68 + 16 * nt + 4 * q + v] = acc[nt][v];
  __syncthreads();
#pragma unroll
  for (int p = 0; p < 4; ++p) {
    const int row = (tid >> 4) + 16 * p;
    const int col4 = (tid & 15) * 4;
    *(float4_a*)&out[(m0 + row) * D + n0 + col4] = *(const float4_a*)&Ct[row * 68 + col4];
  }
}

extern "C" void kernel_launch(void* const* d_in, const int* in_sizes, int n_in,
                              void* d_out, int out_size, void* d_ws, size_t ws_size,
                              hipStream_t stream) {
  const float* x   = (const float*)d_in[0];
  const float* WQ  = (const float*)d_in[1];
  const float* WK  = (const float*)d_in[2];
  const float* WV  = (const float*)d_in[3];
  const float* WO  = (const float*)d_in[4];
  const float* Cs  = (const float*)d_in[5];
  const float* Ds  = (const float*)d_in[6];
  const float* Are = (const float*)d_in[7];
  const float* Aim = (const float*)d_in[8];
  const float* Cre = (const float*)d_in[9];
  const float* Cim = (const float*)d_in[10];
  const float* Dd  = (const float*)d_in[11];
  float* out = (float*)d_out;

  char* ws = (char*)d_ws;
  const size_t SD = (size_t)S * D * 4;   // 2 MB
  float* QT    = (float*)(ws + 0 * SD);
  float* KrawT = (float*)(ws + 1 * SD);  // dead after shift_ssmT -> reused as OT1
  float* VT    = (float*)(ws + 2 * SD);
  float* KnT   = (float*)(ws + 3 * SD);
  float* OT    = (float*)(ws + 4 * SD);
  float* OT1   = KrawT;
  unsigned short* cb2pack = (unsigned short*)(ws + 5 * SD);            // 8 MB
  unsigned short* kdpack  = (unsigned short*)(ws + 5 * SD + 8388608);  // 8 MB

  fused_qkv_cbkd<<<384 + CD / 16, 256, 0, stream>>>(
      x, WQ, WK, WV, Are, Aim, Cre, Cim, QT, KrawT, VT, cb2pack, kdpack);
  shift_ssmT<<<512, 256, 0, stream>>>(KrawT, Cs, Ds, KnT);
  s4d_fused<<<1024, 256, 0, stream>>>(KnT, VT, QT, Are, Aim, cb2pack, kdpack, Dd, OT, OT1);
  gemm_outT<<<128, 256, 0, stream>>>(OT, OT1, WO, out);
}

// Round 6
// 179.977 us; speedup vs baseline: 1.8770x; 1.0572x over previous
//
#include <hip/hip_runtime.h>

#define S 1024
#define D 512
#define HID 64
#define CD 32768
#define DT 0.1f

typedef __attribute__((ext_vector_type(4))) float floatx4;
typedef __attribute__((ext_vector_type(8))) short shortx8;
// may_alias variants for type-punned LDS/global access (TBAA-safe)
typedef short shortx8_a __attribute__((ext_vector_type(8), may_alias));
typedef short shortx4_a __attribute__((ext_vector_type(4), may_alias));
typedef unsigned int uint_a __attribute__((may_alias));
typedef unsigned int uint2_a __attribute__((ext_vector_type(2), may_alias));
typedef unsigned int uint4_a __attribute__((ext_vector_type(4), may_alias));
typedef float float4_a __attribute__((ext_vector_type(4), may_alias));
typedef float float_a __attribute__((may_alias));

__device__ __forceinline__ unsigned short f2bf(float f) {
  union { float f; unsigned int u; } v;
  v.f = f;
  unsigned int r = v.u + 0x7FFFu + ((v.u >> 16) & 1u);
  return (unsigned short)(r >> 16);
}
__device__ __forceinline__ float bf2f(unsigned short h) {
  union { unsigned int u; float f; } v;
  v.u = ((unsigned int)h) << 16;
  return v.f;
}
// hi/lo split: v ~= bf2f(h) + bf2f(lo), ~16-bit mantissa accuracy
__device__ __forceinline__ void cvt_hilo(float v, unsigned short& h, unsigned short& lo) {
  h = f2bf(v);
  lo = f2bf(v - bf2f(h));
}
// packed f32x2 -> bf16x2: round-half-up (+0x8000) then one v_perm_b32 byte
// pack. perm(A,B,sel): sel bytes 0-3 index B (low source), 4-7 index A, so
// sel 0x07060302 = {A.b3,A.b2,B.b3,B.b2} -> a lands in dst[15:0] exactly like
// f2bf(a)|f2bf(b)<<16. Half-up differs from RNE only on exact ties (<=1 ulp,
// ~2^-17 probability) — negligible. 3 VALU ops/pair vs ~8 for integer RNE.
// (Round-5 post-mortem: v_cvt_pk_bf16_f32 inline-asm silently mis-packs on
// gfx950 — absmax 21.5; replaced with documented primitives.)
__device__ __forceinline__ unsigned int pk_bf16(float a, float b) {
  union { float f; unsigned int u; } va, vb;
  va.f = a; vb.f = b;
  return __builtin_amdgcn_perm(vb.u + 0x8000u, va.u + 0x8000u, 0x07060302u);
}

// =====================  L1: fused QKV-GEMM + cbkd  ==========================
// blocks [0,384): {Q,Kraw,V}T[n][m] = sum_k x[m][k]*W[n][k] via bf16 hi/lo MFMA
// blocks [384,2432): per-16-channel cb2 + kd build (inline dA-power table)
__global__ __launch_bounds__(256) void fused_qkv_cbkd(
    const float* __restrict__ x, const float* __restrict__ WQ,
    const float* __restrict__ WK, const float* __restrict__ WV,
    const float* __restrict__ Are, const float* __restrict__ Aim,
    const float* __restrict__ Cre, const float* __restrict__ Cim,
    float* __restrict__ QT, float* __restrict__ KrawT, float* __restrict__ VT,
    unsigned short* __restrict__ cb2pack, unsigned short* __restrict__ kdpack) {
  __shared__ __align__(16) char LB[21760];
  const int tid = threadIdx.x;
  const int bid = blockIdx.x;
  const int l = tid & 63, w = tid >> 6;
  const int l15 = l & 15, q = l >> 4;

  if (bid < 384) {
    // ---------------- QKV GEMM: 64x64 tile, K=512, BK=32 ----------------
    unsigned short* Wh = (unsigned short*)LB;     // [64][40]
    unsigned short* Wl = Wh + 2560;
    unsigned short* Xh = Wl + 2560;
    unsigned short* Xl = Xh + 2560;
    float_a* Ct = (float_a*)LB;                   // [64][68], aliased after loop
    const int mat = bid >> 7;                     // /128
    const int rem = bid & 127;
    const int n0 = (rem & 7) * 64, m0 = (rem >> 3) * 64;
    const float* Wsel = (mat == 0) ? WQ : (mat == 1) ? WK : WV;
    float* CT = (mat == 0) ? QT : (mat == 1) ? KrawT : VT;

    floatx4 acc[4];
#pragma unroll
    for (int nt = 0; nt < 4; ++nt) acc[nt] = (floatx4){0.f, 0.f, 0.f, 0.f};

    for (int k0 = 0; k0 < D; k0 += 32) {
      if (k0) __syncthreads();
#pragma unroll
      for (int p = 0; p < 2; ++p) {
        const int idx = tid + 256 * p;
        const int row = idx >> 3, c4 = (idx & 7) * 4;
        const float4 wv = *(const float4*)&Wsel[(n0 + row) * D + k0 + c4];
        const float4 xv = *(const float4*)&x[(m0 + row) * D + k0 + c4];
        unsigned short h0, h1, h2, h3, g0, g1, g2, g3;
        cvt_hilo(wv.x, h0, g0); cvt_hilo(wv.y, h1, g1);
        cvt_hilo(wv.z, h2, g2); cvt_hilo(wv.w, h3, g3);
        uint2_a hv = {(unsigned int)h0 | ((unsigned int)h1 << 16),
                      (unsigned int)h2 | ((unsigned int)h3 << 16)};
        uint2_a lv = {(unsigned int)g0 | ((unsigned int)g1 << 16),
                      (unsigned int)g2 | ((unsigned int)g3 << 16)};
        *(uint2_a*)&Wh[row * 40 + c4] = hv;
        *(uint2_a*)&Wl[row * 40 + c4] = lv;
        cvt_hilo(xv.x, h0, g0); cvt_hilo(xv.y, h1, g1);
        cvt_hilo(xv.z, h2, g2); cvt_hilo(xv.w, h3, g3);
        uint2_a hv2 = {(unsigned int)h0 | ((unsigned int)h1 << 16),
                       (unsigned int)h2 | ((unsigned int)h3 << 16)};
        uint2_a lv2 = {(unsigned int)g0 | ((unsigned int)g1 << 16),
                       (unsigned int)g2 | ((unsigned int)g3 << 16)};
        *(uint2_a*)&Xh[row * 40 + c4] = hv2;
        *(uint2_a*)&Xl[row * 40 + c4] = lv2;
      }
      __syncthreads();
      const shortx8 xh = *(const shortx8_a*)&Xh[(16 * w + l15) * 40 + 8 * q];
      const shortx8 xl = *(const shortx8_a*)&Xl[(16 * w + l15) * 40 + 8 * q];
#pragma unroll
      for (int nt = 0; nt < 4; ++nt) {
        const shortx8 wh = *(const shortx8_a*)&Wh[(16 * nt + l15) * 40 + 8 * q];
        const shortx8 wl = *(const shortx8_a*)&Wl[(16 * nt + l15) * 40 + 8 * q];
        acc[nt] = __builtin_amdgcn_mfma_f32_16x16x32_bf16(wh, xh, acc[nt], 0, 0, 0);
        acc[nt] = __builtin_amdgcn_mfma_f32_16x16x32_bf16(wh, xl, acc[nt], 0, 0, 0);
        acc[nt] = __builtin_amdgcn_mfma_f32_16x16x32_bf16(wl, xh, acc[nt], 0, 0, 0);
      }
    }
    __syncthreads();
    // lane holds D[n = 16nt+4q+v][m = 16w+l15] -> Ct[n][m]
#pragma unroll
    for (int nt = 0; nt < 4; ++nt)
#pragma unroll
      for (int v = 0; v < 4; ++v)
        Ct[(16 * nt + 4 * q + v) * 68 + 16 * w + l15] = acc[nt][v];
    __syncthreads();
#pragma unroll
    for (int p = 0; p < 4; ++p) {
      const int row = (tid >> 4) + 16 * p;
      const int col4 = (tid & 15) * 4;
      *(float4_a*)&CT[(n0 + row) * S + m0 + col4] = *(const float4_a*)&Ct[row * 68 + col4];
    }
  } else {
    // ---------------- cbkd: c0 = (bid-384)*16 ----------------
    unsigned short* cbs = (unsigned short*)LB;          // [16][136]
    unsigned short* PCc2s = (unsigned short*)(LB + 4352);  // [64][136]
    const int c0 = (bid - 384) << 4;
    // inline PCc2 table build: thread (n=l, seg=w)
    {
      const int n = l, seg = w;
      const float ar = Are[n], ai = Aim[n];
      const float den_re = 1.0f - 0.05f * ar;
      const float den_im = -0.05f * ai;
      const float num_re = 1.0f + 0.05f * ar;
      const float num_im = 0.05f * ai;
      const float inv_d2 = 1.0f / (den_re * den_re + den_im * den_im);
      const float dAr = (num_re * den_re + num_im * den_im) * inv_d2;
      const float dAi = (num_im * den_re - num_re * den_im) * inv_d2;
      float e2r = dAr * dAr - dAi * dAi, e2i = 2.0f * dAr * dAi;
      float e4r = e2r * e2r - e2i * e2i, e4i = 2.0f * e2r * e2i;
      float e8r = e4r * e4r - e4i * e4i, e8i = 2.0f * e4r * e4i;
      float e16r = e8r * e8r - e8i * e8i, e16i = 2.0f * e8r * e8i;
      float br = 1.0f, bi = 0.0f;
      for (int sgo = 0; sgo < seg; ++sgo) {
        const float nr = br * e16r - bi * e16i;
        bi = br * e16i + bi * e16r;
        br = nr;
      }
      float pr = br, pi = bi;
      for (int k = 16 * seg + 1; k <= 16 * seg + 16; ++k) {
        const float nr = pr * dAr - pi * dAi;
        pi = pr * dAi + pi * dAr;
        pr = nr;
        if (k <= 63) {
          PCc2s[k * 136 + n] = f2bf(pr);
          PCc2s[k * 136 + 64 + n] = f2bf(-pi);
        }
      }
      if (seg == 0) {
        PCc2s[n] = f2bf(1.0f);
        PCc2s[64 + n] = 0;
      }
    }
    // cb2 build
#pragma unroll
    for (int ii = 0; ii < 4; ++ii) {
      const int idx = tid + 256 * ii;
      const int ci = idx >> 6, n = idx & 63;
      const int c = c0 + ci;
      const float ar = Are[n], ai = Aim[n];
      const float den_re = 1.0f - 0.05f * ar;
      const float den_im = -0.05f * ai;
      const float inv_d2 = 1.0f / (den_re * den_re + den_im * den_im);
      const float dBr = DT * den_re * inv_d2;
      const float dBi = -DT * den_im * inv_d2;
      const float cr = Cre[c * HID + n], cim = Cim[c * HID + n];
      const unsigned short re = f2bf(2.0f * (cr * dBr - cim * dBi));
      const unsigned short im = f2bf(2.0f * (cr * dBi + cim * dBr));
      cbs[ci * 136 + n] = re;
      cbs[ci * 136 + 64 + n] = im;
      cb2pack[c * 128 + n] = re;
      cb2pack[c * 128 + 64 + n] = im;
    }
    __syncthreads();
    // kd GEMM -> kdpack (kdR layout)
    floatx4 acc = {0.f, 0.f, 0.f, 0.f};
#pragma unroll
    for (int k = 0; k < 4; ++k) {
      const shortx8 a = *(const shortx8_a*)&cbs[l15 * 136 + 8 * q + 32 * k];
      const shortx8 b = *(const shortx8_a*)&PCc2s[(16 * w + l15) * 136 + 8 * q + 32 * k];
      acc = __builtin_amdgcn_mfma_f32_16x16x32_bf16(a, b, acc, 0, 0, 0);
    }
    const int dlt = 16 * w + l15;
#pragma unroll
    for (int v = 0; v < 4; ++v)
      kdpack[(c0 + 4 * q + v) * 128 + 64 - dlt] = f2bf(acc[v]);
    const int row = tid >> 4, p = tid & 15;
#pragma unroll
    for (int k2 = 0; k2 < 4; ++k2) {
      const int idx = p + 16 * k2;
      const int m = (idx == 0) ? 0 : 64 + idx;
      kdpack[(c0 + row) * 128 + m] = 0;
    }
  }
}

// ======= L2: shift SSM, [d][t] domain, taps via scalar loads ================
__global__ __launch_bounds__(256) void shift_ssmT(const float* __restrict__ KrawT,
                                                  const float* __restrict__ Cs,
                                                  const float* __restrict__ Ds,
                                                  float* __restrict__ KnT) {
  __shared__ float kpad[64 + S];
  const int d = blockIdx.x, tid = threadIdx.x;
  if (tid < 64) kpad[tid] = 0.0f;
  *(float4_a*)&kpad[64 + 4 * tid] = *(const float4_a*)&KrawT[d * S + 4 * tid];
  const float dskip = Ds[d];
  const float* taps = Cs + d * HID;  // block-uniform -> scalar loads
  __syncthreads();
  float acc[4];
#pragma unroll
  for (int s = 0; s < 4; ++s) acc[s] = dskip * kpad[64 + tid + 256 * s];
  for (int j = 0; j < 64; ++j) {
    const float tj = taps[j];
#pragma unroll
    for (int s = 0; s < 4; ++s) acc[s] += tj * kpad[64 + tid + 256 * s - j];
  }
#pragma unroll
  for (int s = 0; s < 4; ++s) KnT[d * S + tid + 256 * s] = acc[s];
}

// =============== L3: s4d_fused (perm-pack + setprio) ========================
// Round-6 changes (vs known-good round-2 structure):
//  * pk_bf16 via +0x8000 round + v_perm_b32 byte-pack (documented builtin;
//    round-5's v_cvt_pk_bf16_f32 asm mis-packed -> absmax 21.5). 3 VALU
//    ops/pair vs ~8 for the integer RNE idiom; ~290 -> ~110 conversion ops
//    per wave-iter out of ~690 total VALU.
//  * s_setprio(1) around phase-A / phase-C MFMA clusters: the main loop has
//    no block barrier, waves run phase-staggered -> priority helps CU
//    arbitration keep the MFMA pipe fed (T5 applies to staggered schedules).
__global__ __launch_bounds__(256, 2) void s4d_fused(
    const float* __restrict__ KnT, const float* __restrict__ VT,
    const float* __restrict__ QT,
    const float* __restrict__ Are, const float* __restrict__ Aim,
    const unsigned short* __restrict__ cb2pack,
    const unsigned short* __restrict__ kdpack,
    const float* __restrict__ Dd, float* __restrict__ OT) {
  __shared__ __align__(16) unsigned short SHu[18176];  // 36352 B
  const int tid = threadIdx.x;
  const int l = tid & 63, w = tid >> 6;
  const int l15 = l & 15, q = l >> 4;
  const int h = blockIdx.x >> 6, j = blockIdx.x & 63;
  const int dv = (h << 6) + j;

  // ---- inline table build: PAre/PAim [n][72], PCc [64][136] interleaved, dA64 ----
  {
    const int n = l, seg = w;
    unsigned short* PAreW = SHu;
    unsigned short* PAimW = SHu + 4608;
    unsigned short* PCcW = SHu + 9216;
    float_a* dA64W = (float_a*)(SHu + 17920);
    const float ar = Are[n], ai = Aim[n];
    const float den_re = 1.0f - 0.05f * ar;
    const float den_im = -0.05f * ai;
    const float num_re = 1.0f + 0.05f * ar;
    const float num_im = 0.05f * ai;
    const float inv_d2 = 1.0f / (den_re * den_re + den_im * den_im);
    const float dAr = (num_re * den_re + num_im * den_im) * inv_d2;
    const float dAi = (num_im * den_re - num_re * den_im) * inv_d2;
    float e2r = dAr * dAr - dAi * dAi, e2i = 2.0f * dAr * dAi;
    float e4r = e2r * e2r - e2i * e2i, e4i = 2.0f * e2r * e2i;
    float e8r = e4r * e4r - e4i * e4i, e8i = 2.0f * e4r * e4i;
    float e16r = e8r * e8r - e8i * e8i, e16i = 2.0f * e8r * e8i;
    float br = 1.0f, bi = 0.0f;
    for (int sgo = 0; sgo < seg; ++sgo) {
      const float nr = br * e16r - bi * e16i;
      bi = br * e16i + bi * e16r;
      br = nr;
    }
    float pr = br, pi = bi;
    for (int k = 16 * seg + 1; k <= 16 * seg + 16; ++k) {
      const float nr = pr * dAr - pi * dAi;
      pi = pr * dAi + pi * dAr;
      pr = nr;
      if (k <= 63) {
        PAreW[n * 72 + 63 - k] = f2bf(pr);
        PAimW[n * 72 + 63 - k] = f2bf(pi);
      }
      // interleaved (re, -im) pairs at columns 2n, 2n+1
      PCcW[(k - 1) * 136 + 2 * n] = f2bf(pr);
      PCcW[(k - 1) * 136 + 2 * n + 1] = f2bf(-pi);
      if (k == 64) {
        dA64W[2 * n] = pr;
        dA64W[2 * n + 1] = pi;
      }
    }
    if (seg == 0) {
      PAreW[n * 72 + 63] = f2bf(1.0f);
      PAimW[n * 72 + 63] = 0;
    }
  }
  // ---- V row slice in registers ----
  float4 vvr[4];
#pragma unroll
  for (int s = 0; s < 4; ++s)
    vvr[s] = *(const float4*)&VT[dv * S + 4 * l + 256 * s];

  // ---- initial per-channel scalar prefetch (channel i = w) ----
  float c2r, c2i, dd;
  unsigned int kdv;
  {
    const int c = (h << 12) + (w << 6) + j;
    c2r = bf2f(cb2pack[c * 128 + l]);
    c2i = bf2f(cb2pack[c * 128 + 64 + l]);
    kdv = *(const uint_a*)&kdpack[c * 128 + 2 * l];
    dd = Dd[c];
  }
  __syncthreads();

  // ---- hoist table fragments into registers (once per block) ----
  const unsigned short* PAre = SHu;
  const unsigned short* PAim = SHu + 4608;
  const unsigned short* PCc = SHu + 9216;
  const float_a* dA64v = (const float_a*)(SHu + 17920);
  const float er = dA64v[2 * l], ei = dA64v[2 * l + 1];
  shortx8 paR[4][2], paI[4][2];
#pragma unroll
  for (int tt = 0; tt < 4; ++tt) {
    const int rowb = (tt * 16 + l15) * 72 + 8 * q;
    paR[tt][0] = *(const shortx8_a*)&PAre[rowb];
    paR[tt][1] = *(const shortx8_a*)&PAre[rowb + 32];
    paI[tt][0] = *(const shortx8_a*)&PAim[rowb];
    paI[tt][1] = *(const shortx8_a*)&PAim[rowb + 32];
  }
  shortx8 pcb[4][4];
#pragma unroll
  for (int k = 0; k < 4; ++k)
#pragma unroll
    for (int tt = 0; tt < 4; ++tt)
      pcb[k][tt] = *(const shortx8_a*)&PCc[(tt * 16 + l15) * 136 + 8 * q + 32 * k];
  __syncthreads();  // all table reads done before workspace aliases tables

  // ---- per-wave workspace, aliased over the table region ----
  unsigned short* WB = SHu + w * 4048;
  unsigned short* Ub = WB;                    // [16][72] bf16
  unsigned short* SXY = WB + 1152;            // [16][136]: Sc -> Xcb interleaved
  uint_a* kdR32 = (uint_a*)(WB + 3328);       // 68 uints (+pad)
  unsigned short* kdSH = WB + 3472;           // [4][136]

  floatx4 OaccD[4];
  float4 Odd[4];
#pragma unroll
  for (int tt = 0; tt < 4; ++tt) OaccD[tt] = (floatx4){0.f, 0.f, 0.f, 0.f};
#pragma unroll
  for (int s = 0; s < 4; ++s) Odd[s] = make_float4(0.f, 0.f, 0.f, 0.f);

#pragma unroll 1
  for (int it = 0; it < 16; ++it) {
    // ---- prefetch next channel's HBM-cold scalars ----
    float nc2r = 0.f, nc2i = 0.f, ndd = 0.f;
    unsigned int nkdv = 0;
    if (it < 15) {
      const int c = (h << 12) + (((it + 1) * 4 + w) << 6) + j;
      nc2r = bf2f(cb2pack[c * 128 + l]);
      nc2i = bf2f(cb2pack[c * 128 + 64 + l]);
      nkdv = *(const uint_a*)&kdpack[c * 128 + 2 * l];
      ndd = Dd[c];
    }
    // ---- current-channel row loads (L2-warm: shared across 64 j-blocks) ----
    const int dk = (h << 6) + it * 4 + w;
    const int kb = dk * S + 4 * l;
    float4 kx[4], qtv[4];
#pragma unroll
    for (int s = 0; s < 4; ++s) {
      kx[s] = *(const float4*)&KnT[kb + 256 * s];
      qtv[s] = *(const float4*)&QT[kb + 256 * s];
    }

    // ---- kdR + 4 shifted copies (uses prefetched kdv; covers row loads) ----
    kdR32[l] = kdv;
    if (l < 4) kdR32[64 + l] = 0;
    asm volatile("" ::: "memory");
#pragma unroll
    for (int s2 = 0; s2 < 4; ++s2) {
      unsigned int v;
      if (s2 == 0) {
        v = kdR32[l];
      } else if (s2 == 1) {
        v = (kdR32[l] >> 16) | (kdR32[l + 1] << 16);
      } else if (s2 == 2) {
        v = kdR32[l + 1];
      } else {
        v = (kdR32[l + 1] >> 16) | (kdR32[l + 2] << 16);
      }
      *(uint_a*)&kdSH[s2 * 136 + 2 * l] = v;
    }
    asm volatile("" ::: "memory");

    // ---- u fill + dd-skip accumulation (kx/qtv die here) ----
#pragma unroll
    for (int s = 0; s < 4; ++s) {
      const int t = 4 * l + 256 * s;
      const int g = t >> 6, r = t & 63;
      const float ux = kx[s].x * vvr[s].x;
      const float uy = kx[s].y * vvr[s].y;
      const float uz = kx[s].z * vvr[s].z;
      const float uw = kx[s].w * vvr[s].w;
      uint2_a pp;
      pp.x = pk_bf16(ux, uy);
      pp.y = pk_bf16(uz, uw);
      *(uint2_a*)&Ub[g * 72 + r] = pp;
      Odd[s].x += dd * qtv[s].x * ux;
      Odd[s].y += dd * qtv[s].y * uy;
      Odd[s].z += dd * qtv[s].z * uz;
      Odd[s].w += dd * qtv[s].w * uw;
    }
    asm volatile("" ::: "memory");

    // ---- phase A: s~[g][n] via MFMA (A-fragments in registers) ----
    const shortx8 b0 = *(const shortx8_a*)&Ub[l15 * 72 + 8 * q];
    const shortx8 b1 = *(const shortx8_a*)&Ub[l15 * 72 + 8 * q + 32];
    __builtin_amdgcn_s_setprio(1);
#pragma unroll
    for (int tt = 0; tt < 4; ++tt) {
      floatx4 z = {0.f, 0.f, 0.f, 0.f};
      floatx4 sre = __builtin_amdgcn_mfma_f32_16x16x32_bf16(paR[tt][0], b0, z, 0, 0, 0);
      sre = __builtin_amdgcn_mfma_f32_16x16x32_bf16(paR[tt][1], b1, sre, 0, 0, 0);
      floatx4 sim = __builtin_amdgcn_mfma_f32_16x16x32_bf16(paI[tt][0], b0, z, 0, 0, 0);
      sim = __builtin_amdgcn_mfma_f32_16x16x32_bf16(paI[tt][1], b1, sim, 0, 0, 0);
      // interleaved: row g=l15, columns 2n..2n+7 for n = tt*16+4q+(0..3)
      uint4_a wv;
      wv[0] = pk_bf16(sre[0], sim[0]);
      wv[1] = pk_bf16(sre[1], sim[1]);
      wv[2] = pk_bf16(sre[2], sim[2]);
      wv[3] = pk_bf16(sre[3], sim[3]);
      *(uint4_a*)&SXY[l15 * 136 + 32 * tt + 8 * q] = wv;
    }
    __builtin_amdgcn_s_setprio(0);
    asm volatile("" ::: "memory");

    // ---- register scan: batch-load packed Sc, pure-VALU recurrence ----
    {
      unsigned int rdv[16];
#pragma unroll
      for (int g = 0; g < 16; ++g) rdv[g] = *(const uint_a*)&SXY[g * 136 + 2 * l];
      float xr = 0.f, xi = 0.f;
#pragma unroll
      for (int g = 0; g < 16; ++g) {
        *(uint_a*)&SXY[g * 136 + 2 * l] =
            pk_bf16(c2r * xr - c2i * xi, c2r * xi + c2i * xr);
        union { unsigned int u; float f; } lo, hi;
        lo.u = rdv[g] << 16;
        hi.u = rdv[g] & 0xffff0000u;
        const float nr = er * xr - ei * xi + lo.f;
        xi = er * xi + ei * xr + hi.f;
        xr = nr;
      }
    }
    asm volatile("" ::: "memory");

    // ---- qD loads (L2-warm; consumed after phase C -> latency covered) ----
    float qD[16];
    {
      const int qb = dk * S + 256 * q + l15;
#pragma unroll
      for (int tt = 0; tt < 4; ++tt)
#pragma unroll
        for (int v = 0; v < 4; ++v)
          qD[4 * tt + v] = QT[qb + 64 * v + 16 * tt];
    }

    // ---- phase C MFMAs (B-fragments in registers) ----
    floatx4 acc[4];
#pragma unroll
    for (int tt = 0; tt < 4; ++tt) acc[tt] = (floatx4){0.f, 0.f, 0.f, 0.f};
    __builtin_amdgcn_s_setprio(1);
#pragma unroll
    for (int k = 0; k < 4; ++k) {
      const shortx8 xa = *(const shortx8_a*)&SXY[l15 * 136 + 8 * q + 32 * k];
#pragma unroll
      for (int tt = 0; tt < 4; ++tt)
        acc[tt] = __builtin_amdgcn_mfma_f32_16x16x32_bf16(xa, pcb[k][tt], acc[tt], 0, 0, 0);
    }
#pragma unroll
    for (int k = 0; k < 2; ++k) {
      const shortx8 ua = (k == 0) ? b0 : b1;
#pragma unroll
      for (int tt = 0; tt < 4; ++tt) {
        const int r = tt * 16 + l15;
        const int sSh = (4 - (r & 3)) & 3;
        const int addr = sSh * 136 + (64 - r - sSh) + 8 * q + 32 * k;
        const shortx4_a lo = *(const shortx4_a*)&kdSH[addr];
        const shortx4_a hi = *(const shortx4_a*)&kdSH[addr + 4];
        const shortx8 kb8 = __builtin_shufflevector(lo, hi, 0, 1, 2, 3, 4, 5, 6, 7);
        acc[tt] = __builtin_amdgcn_mfma_f32_16x16x32_bf16(ua, kb8, acc[tt], 0, 0, 0);
      }
    }
    __builtin_amdgcn_s_setprio(0);
    // ---- accumulate O in D-layout ----
#pragma unroll
    for (int tt = 0; tt < 4; ++tt)
#pragma unroll
      for (int v = 0; v < 4; ++v)
        OaccD[tt][v] += qD[4 * tt + v] * acc[tt][v];
    // ---- rotate per-channel scalars ----
    c2r = nc2r; c2i = nc2i; kdv = nkdv; dd = ndd;
  }

  // ---- once-per-block: redistribute D-layout O to t-layout, fold dd-term ----
  asm volatile("" ::: "memory");
  {
    float_a* Ored = (float_a*)WB;  // padded [1028]: idx' = t + (t>>8)
#pragma unroll
    for (int tt = 0; tt < 4; ++tt)
#pragma unroll
      for (int v = 0; v < 4; ++v)
        Ored[256 * q + 64 * v + 16 * tt + l15 + q] = OaccD[tt][v];
    asm volatile("" ::: "memory");
    float4 Oa[4];
#pragma unroll
    for (int s = 0; s < 4; ++s) {
      const float4_a y4 = *(const float4_a*)&Ored[4 * l + 257 * s];
      Oa[s].x = y4.x + Odd[s].x;
      Oa[s].y = y4.y + Odd[s].y;
      Oa[s].z = y4.z + Odd[s].z;
      Oa[s].w = y4.w + Odd[s].w;
    }
    asm volatile("" ::: "memory");
#pragma unroll
    for (int s = 0; s < 4; ++s) {
      float4_a vv = {Oa[s].x, Oa[s].y, Oa[s].z, Oa[s].w};
      *(float4_a*)&Ored[4 * l + 256 * s] = vv;
    }
  }
  __syncthreads();
  {
    const int tq = 256 * w + 4 * l;
    float4_a acc = {0.f, 0.f, 0.f, 0.f};
#pragma unroll
    for (int w2 = 0; w2 < 4; ++w2) {
      const float_a* Ow2 = (const float_a*)(SHu + w2 * 4048);
      acc += *(const float4_a*)&Ow2[tq];
    }
    *(float4_a*)&OT[dv * S + tq] = acc;
  }
}

// ====== L4: out[m][n] = sum_k OT[k][m]*WO[n][k] via bf16 hi/lo MFMA =========
__global__ __launch_bounds__(256) void gemm_outT(const float* __restrict__ OT,
                                                 const float* __restrict__ WO,
                                                 float* __restrict__ out) {
  __shared__ __align__(16) char LB[20480];
  unsigned short* Wh = (unsigned short*)LB;  // [64][40] WO planes
  unsigned short* Wl = Wh + 2560;
  unsigned short* Xh = Wl + 2560;            // [64][40] O1 planes (m rows)
  unsigned short* Xl = Xh + 2560;
  float_a* Ct = (float_a*)LB;                // [64][68] aliased
  const int tid = threadIdx.x;
  const int l = tid & 63, w = tid >> 6;
  const int l15 = l & 15, q = l >> 4;
  const int n0 = (blockIdx.x & 7) * 64, m0 = (blockIdx.x >> 3) * 64;

  floatx4 acc[4];
#pragma unroll
  for (int nt = 0; nt < 4; ++nt) acc[nt] = (floatx4){0.f, 0.f, 0.f, 0.f};

  for (int k0 = 0; k0 < D; k0 += 32) {
    if (k0) __syncthreads();
#pragma unroll
    for (int p = 0; p < 2; ++p) {
      const int idx = tid + 256 * p;
      // WO rows (n-local), k-contiguous
      {
        const int row = idx >> 3, c4 = (idx & 7) * 4;
        const float4 wv = *(const float4*)&WO[(n0 + row) * D + k0 + c4];
        unsigned short h0, h1, h2, h3, g0, g1, g2, g3;
        cvt_hilo(wv.x, h0, g0); cvt_hilo(wv.y, h1, g1);
        cvt_hilo(wv.z, h2, g2); cvt_hilo(wv.w, h3, g3);
        uint2_a hv = {(unsigned int)h0 | ((unsigned int)h1 << 16),
                      (unsigned int)h2 | ((unsigned int)h3 << 16)};
        uint2_a lv = {(unsigned int)g0 | ((unsigned int)g1 << 16),
                      (unsigned int)g2 | ((unsigned int)g3 << 16)};
        *(uint2_a*)&Wh[row * 40 + c4] = hv;
        *(uint2_a*)&Wl[row * 40 + c4] = lv;
      }
      // OT tile: read [k][m] coalesced, store transposed [m][k]
      {
        const int kk = idx >> 4, m4 = (idx & 15) * 4;
        const float4 ov = *(const float4*)&OT[(k0 + kk) * S + m0 + m4];
        unsigned short h, g;
        cvt_hilo(ov.x, h, g); Xh[(m4 + 0) * 40 + kk] = h; Xl[(m4 + 0) * 40 + kk] = g;
        cvt_hilo(ov.y, h, g); Xh[(m4 + 1) * 40 + kk] = h; Xl[(m4 + 1) * 40 + kk] = g;
        cvt_hilo(ov.z, h, g); Xh[(m4 + 2) * 40 + kk] = h; Xl[(m4 + 2) * 40 + kk] = g;
        cvt_hilo(ov.w, h, g); Xh[(m4 + 3) * 40 + kk] = h; Xl[(m4 + 3) * 40 + kk] = g;
      }
    }
    __syncthreads();
    const shortx8 xh = *(const shortx8_a*)&Xh[(16 * w + l15) * 40 + 8 * q];
    const shortx8 xl = *(const shortx8_a*)&Xl[(16 * w + l15) * 40 + 8 * q];
#pragma unroll
    for (int nt = 0; nt < 4; ++nt) {
      const shortx8 wh = *(const shortx8_a*)&Wh[(16 * nt + l15) * 40 + 8 * q];
      const shortx8 wl = *(const shortx8_a*)&Wl[(16 * nt + l15) * 40 + 8 * q];
      acc[nt] = __builtin_amdgcn_mfma_f32_16x16x32_bf16(wh, xh, acc[nt], 0, 0, 0);
      acc[nt] = __builtin_amdgcn_mfma_f32_16x16x32_bf16(wh, xl, acc[nt], 0, 0, 0);
      acc[nt] = __builtin_amdgcn_mfma_f32_16x16x32_bf16(wl, xh, acc[nt], 0, 0, 0);
    }
  }
  __syncthreads();
  // lane holds D[n = 16nt+4q+v][m = 16w+l15] -> Ct[m][n]
#pragma unroll
  for (int nt = 0; nt < 4; ++nt)
#pragma unroll
    for (int v = 0; v < 4; ++v)
      Ct[(16 * w + l15) * 68 + 16 * nt + 4 * q + v] = acc[nt][v];
  __syncthreads();
#pragma unroll
  for (int p = 0; p < 4; ++p) {
    const int row = (tid >> 4) + 16 * p;
    const int col4 = (tid & 15) * 4;
    *(float4_a*)&out[(m0 + row) * D + n0 + col4] = *(const float4_a*)&Ct[row * 68 + col4];
  }
}

extern "C" void kernel_launch(void* const* d_in, const int* in_sizes, int n_in,
                              void* d_out, int out_size, void* d_ws, size_t ws_size,
                              hipStream_t stream) {
  const float* x   = (const float*)d_in[0];
  const float* WQ  = (const float*)d_in[1];
  const float* WK  = (const float*)d_in[2];
  const float* WV  = (const float*)d_in[3];
  const float* WO  = (const float*)d_in[4];
  const float* Cs  = (const float*)d_in[5];
  const float* Ds  = (const float*)d_in[6];
  const float* Are = (const float*)d_in[7];
  const float* Aim = (const float*)d_in[8];
  const float* Cre = (const float*)d_in[9];
  const float* Cim = (const float*)d_in[10];
  const float* Dd  = (const float*)d_in[11];
  float* out = (float*)d_out;

  char* ws = (char*)d_ws;
  const size_t SD = (size_t)S * D * 4;   // 2 MB
  float* QT    = (float*)(ws + 0 * SD);
  float* KrawT = (float*)(ws + 1 * SD);
  float* VT    = (float*)(ws + 2 * SD);
  float* KnT   = (float*)(ws + 3 * SD);
  float* OT    = (float*)(ws + 4 * SD);
  unsigned short* cb2pack = (unsigned short*)(ws + 5 * SD);            // 8 MB
  unsigned short* kdpack  = (unsigned short*)(ws + 5 * SD + 8388608);  // 8 MB

  fused_qkv_cbkd<<<384 + CD / 16, 256, 0, stream>>>(
      x, WQ, WK, WV, Are, Aim, Cre, Cim, QT, KrawT, VT, cb2pack, kdpack);
  shift_ssmT<<<512, 256, 0, stream>>>(KrawT, Cs, Ds, KnT);
  s4d_fused<<<512, 256, 0, stream>>>(KnT, VT, QT, Are, Aim, cb2pack, kdpack, Dd, OT);
  gemm_outT<<<128, 256, 0, stream>>>(OT, WO, out);
}

// Round 8
// 177.604 us; speedup vs baseline: 1.9021x; 1.0134x over previous
//
#include <hip/hip_runtime.h>

#define S 1024
#define D 512
#define HID 64
#define CD 32768
#define DT 0.1f

typedef __attribute__((ext_vector_type(4))) float floatx4;
typedef __attribute__((ext_vector_type(8))) short shortx8;
// may_alias variants for type-punned LDS/global access (TBAA-safe)
typedef short shortx8_a __attribute__((ext_vector_type(8), may_alias));
typedef short shortx4_a __attribute__((ext_vector_type(4), may_alias));
typedef unsigned int uint_a __attribute__((may_alias));
typedef unsigned int uint2_a __attribute__((ext_vector_type(2), may_alias));
typedef unsigned int uint4_a __attribute__((ext_vector_type(4), may_alias));
typedef float float4_a __attribute__((ext_vector_type(4), may_alias));
typedef float float_a __attribute__((may_alias));

__device__ __forceinline__ unsigned short f2bf(float f) {
  union { float f; unsigned int u; } v;
  v.f = f;
  unsigned int r = v.u + 0x7FFFu + ((v.u >> 16) & 1u);
  return (unsigned short)(r >> 16);
}
__device__ __forceinline__ float bf2f(unsigned short h) {
  union { unsigned int u; float f; } v;
  v.u = ((unsigned int)h) << 16;
  return v.f;
}
// hi/lo split: v ~= bf2f(h) + bf2f(lo), ~16-bit mantissa accuracy
__device__ __forceinline__ void cvt_hilo(float v, unsigned short& h, unsigned short& lo) {
  h = f2bf(v);
  lo = f2bf(v - bf2f(h));
}
// packed f32x2 -> bf16x2: round-half-up (+0x8000) then one v_perm_b32 byte
// pack. perm(A,B,sel): sel bytes 0-3 index B (low source), 4-7 index A, so
// sel 0x07060302 = {A.b3,A.b2,B.b3,B.b2} -> a lands in dst[15:0] exactly like
// f2bf(a)|f2bf(b)<<16. Half-up differs from RNE only on exact ties (<=1 ulp,
// ~2^-17 probability) — negligible (round-6 verified: absmax 0.59 vs 1.49).
__device__ __forceinline__ unsigned int pk_bf16(float a, float b) {
  union { float f; unsigned int u; } va, vb;
  va.f = a; vb.f = b;
  return __builtin_amdgcn_perm(vb.u + 0x8000u, va.u + 0x8000u, 0x07060302u);
}
// fast hi/lo pair: half-up hi plane + residual lo plane, packed. Returned by
// value (vector elements can't bind to non-const refs — round-7 compile fix).
struct hilo_pair { unsigned int hp, lp; };
__device__ __forceinline__ hilo_pair cvt_hilo_pk(float a, float b) {
  union { float f; unsigned int u; } va, vb;
  va.f = a; vb.f = b;
  const unsigned int ra = va.u + 0x8000u, rb = vb.u + 0x8000u;
  hilo_pair r;
  r.hp = __builtin_amdgcn_perm(rb, ra, 0x07060302u);
  union { unsigned int u; float f; } ha, hb;
  ha.u = ra & 0xffff0000u;   // bf2f(hi_a)
  hb.u = rb & 0xffff0000u;
  union { float f; unsigned int u; } la, lb;
  la.f = a - ha.f; lb.f = b - hb.f;
  r.lp = __builtin_amdgcn_perm(lb.u + 0x8000u, la.u + 0x8000u, 0x07060302u);
  return r;
}
// fast scalar hi/lo (for transpose stores where pairs land in different rows)
__device__ __forceinline__ void cvt_hilo_fast(float v, unsigned short& h,
                                              unsigned short& lo) {
  union { float f; unsigned int u; } x;
  x.f = v;
  const unsigned int r = x.u + 0x8000u;
  h = (unsigned short)(r >> 16);
  union { unsigned int u; float f; } hf;
  hf.u = r & 0xffff0000u;
  union { float f; unsigned int u; } l;
  l.f = v - hf.f;
  lo = (unsigned short)((l.u + 0x8000u) >> 16);
}

// =====================  L1: fused QKV-GEMM + cbkd  ==========================
// blocks [0,384): {Q,Kraw,V}T[n][m] = sum_k x[m][k]*W[n][k] via bf16 hi/lo MFMA
// blocks [384,2432): per-16-channel cb2 + kd build (inline dA-power table)
// Round-8: QKV staging uses cvt_hilo_pk (half-up + perm pack): ~80 VALU ops
// per thread per K-step for the 8 staged values vs ~160 with integer RNE.
__global__ __launch_bounds__(256) void fused_qkv_cbkd(
    const float* __restrict__ x, const float* __restrict__ WQ,
    const float* __restrict__ WK, const float* __restrict__ WV,
    const float* __restrict__ Are, const float* __restrict__ Aim,
    const float* __restrict__ Cre, const float* __restrict__ Cim,
    float* __restrict__ QT, float* __restrict__ KrawT, float* __restrict__ VT,
    unsigned short* __restrict__ cb2pack, unsigned short* __restrict__ kdpack) {
  __shared__ __align__(16) char LB[21760];
  const int tid = threadIdx.x;
  const int bid = blockIdx.x;
  const int l = tid & 63, w = tid >> 6;
  const int l15 = l & 15, q = l >> 4;

  if (bid < 384) {
    // ---------------- QKV GEMM: 64x64 tile, K=512, BK=32 ----------------
    unsigned short* Wh = (unsigned short*)LB;     // [64][40]
    unsigned short* Wl = Wh + 2560;
    unsigned short* Xh = Wl + 2560;
    unsigned short* Xl = Xh + 2560;
    float_a* Ct = (float_a*)LB;                   // [64][68], aliased after loop
    const int mat = bid >> 7;                     // /128
    const int rem = bid & 127;
    const int n0 = (rem & 7) * 64, m0 = (rem >> 3) * 64;
    const float* Wsel = (mat == 0) ? WQ : (mat == 1) ? WK : WV;
    float* CT = (mat == 0) ? QT : (mat == 1) ? KrawT : VT;

    floatx4 acc[4];
#pragma unroll
    for (int nt = 0; nt < 4; ++nt) acc[nt] = (floatx4){0.f, 0.f, 0.f, 0.f};

    for (int k0 = 0; k0 < D; k0 += 32) {
      if (k0) __syncthreads();
#pragma unroll
      for (int p = 0; p < 2; ++p) {
        const int idx = tid + 256 * p;
        const int row = idx >> 3, c4 = (idx & 7) * 4;
        const float4 wv = *(const float4*)&Wsel[(n0 + row) * D + k0 + c4];
        const float4 xv = *(const float4*)&x[(m0 + row) * D + k0 + c4];
        const hilo_pair w01 = cvt_hilo_pk(wv.x, wv.y);
        const hilo_pair w23 = cvt_hilo_pk(wv.z, wv.w);
        uint2_a hv = {w01.hp, w23.hp};
        uint2_a lv = {w01.lp, w23.lp};
        *(uint2_a*)&Wh[row * 40 + c4] = hv;
        *(uint2_a*)&Wl[row * 40 + c4] = lv;
        const hilo_pair x01 = cvt_hilo_pk(xv.x, xv.y);
        const hilo_pair x23 = cvt_hilo_pk(xv.z, xv.w);
        uint2_a hv2 = {x01.hp, x23.hp};
        uint2_a lv2 = {x01.lp, x23.lp};
        *(uint2_a*)&Xh[row * 40 + c4] = hv2;
        *(uint2_a*)&Xl[row * 40 + c4] = lv2;
      }
      __syncthreads();
      const shortx8 xh = *(const shortx8_a*)&Xh[(16 * w + l15) * 40 + 8 * q];
      const shortx8 xl = *(const shortx8_a*)&Xl[(16 * w + l15) * 40 + 8 * q];
#pragma unroll
      for (int nt = 0; nt < 4; ++nt) {
        const shortx8 wh = *(const shortx8_a*)&Wh[(16 * nt + l15) * 40 + 8 * q];
        const shortx8 wl = *(const shortx8_a*)&Wl[(16 * nt + l15) * 40 + 8 * q];
        acc[nt] = __builtin_amdgcn_mfma_f32_16x16x32_bf16(wh, xh, acc[nt], 0, 0, 0);
        acc[nt] = __builtin_amdgcn_mfma_f32_16x16x32_bf16(wh, xl, acc[nt], 0, 0, 0);
        acc[nt] = __builtin_amdgcn_mfma_f32_16x16x32_bf16(wl, xh, acc[nt], 0, 0, 0);
      }
    }
    __syncthreads();
    // lane holds D[n = 16nt+4q+v][m = 16w+l15] -> Ct[n][m]
#pragma unroll
    for (int nt = 0; nt < 4; ++nt)
#pragma unroll
      for (int v = 0; v < 4; ++v)
        Ct[(16 * nt + 4 * q + v) * 68 + 16 * w + l15] = acc[nt][v];
    __syncthreads();
#pragma unroll
    for (int p = 0; p < 4; ++p) {
      const int row = (tid >> 4) + 16 * p;
      const int col4 = (tid & 15) * 4;
      *(float4_a*)&CT[(n0 + row) * S + m0 + col4] = *(const float4_a*)&Ct[row * 68 + col4];
    }
  } else {
    // ---------------- cbkd: c0 = (bid-384)*16 ----------------
    unsigned short* cbs = (unsigned short*)LB;          // [16][136]
    unsigned short* PCc2s = (unsigned short*)(LB + 4352);  // [64][136]
    const int c0 = (bid - 384) << 4;
    // inline PCc2 table build: thread (n=l, seg=w)
    {
      const int n = l, seg = w;
      const float ar = Are[n], ai = Aim[n];
      const float den_re = 1.0f - 0.05f * ar;
      const float den_im = -0.05f * ai;
      const float num_re = 1.0f + 0.05f * ar;
      const float num_im = 0.05f * ai;
      const float inv_d2 = 1.0f / (den_re * den_re + den_im * den_im);
      const float dAr = (num_re * den_re + num_im * den_im) * inv_d2;
      const float dAi = (num_im * den_re - num_re * den_im) * inv_d2;
      float e2r = dAr * dAr - dAi * dAi, e2i = 2.0f * dAr * dAi;
      float e4r = e2r * e2r - e2i * e2i, e4i = 2.0f * e2r * e2i;
      float e8r = e4r * e4r - e4i * e4i, e8i = 2.0f * e4r * e4i;
      float e16r = e8r * e8r - e8i * e8i, e16i = 2.0f * e8r * e8i;
      float br = 1.0f, bi = 0.0f;
      for (int sgo = 0; sgo < seg; ++sgo) {
        const float nr = br * e16r - bi * e16i;
        bi = br * e16i + bi * e16r;
        br = nr;
      }
      float pr = br, pi = bi;
      for (int k = 16 * seg + 1; k <= 16 * seg + 16; ++k) {
        const float nr = pr * dAr - pi * dAi;
        pi = pr * dAi + pi * dAr;
        pr = nr;
        if (k <= 63) {
          PCc2s[k * 136 + n] = f2bf(pr);
          PCc2s[k * 136 + 64 + n] = f2bf(-pi);
        }
      }
      if (seg == 0) {
        PCc2s[n] = f2bf(1.0f);
        PCc2s[64 + n] = 0;
      }
    }
    // cb2 build
#pragma unroll
    for (int ii = 0; ii < 4; ++ii) {
      const int idx = tid + 256 * ii;
      const int ci = idx >> 6, n = idx & 63;
      const int c = c0 + ci;
      const float ar = Are[n], ai = Aim[n];
      const float den_re = 1.0f - 0.05f * ar;
      const float den_im = -0.05f * ai;
      const float inv_d2 = 1.0f / (den_re * den_re + den_im * den_im);
      const float dBr = DT * den_re * inv_d2;
      const float dBi = -DT * den_im * inv_d2;
      const float cr = Cre[c * HID + n], cim = Cim[c * HID + n];
      const unsigned short re = f2bf(2.0f * (cr * dBr - cim * dBi));
      const unsigned short im = f2bf(2.0f * (cr * dBi + cim * dBr));
      cbs[ci * 136 + n] = re;
      cbs[ci * 136 + 64 + n] = im;
      cb2pack[c * 128 + n] = re;
      cb2pack[c * 128 + 64 + n] = im;
    }
    __syncthreads();
    // kd GEMM -> kdpack (kdR layout)
    floatx4 acc = {0.f, 0.f, 0.f, 0.f};
#pragma unroll
    for (int k = 0; k < 4; ++k) {
      const shortx8 a = *(const shortx8_a*)&cbs[l15 * 136 + 8 * q + 32 * k];
      const shortx8 b = *(const shortx8_a*)&PCc2s[(16 * w + l15) * 136 + 8 * q + 32 * k];
      acc = __builtin_amdgcn_mfma_f32_16x16x32_bf16(a, b, acc, 0, 0, 0);
    }
    const int dlt = 16 * w + l15;
#pragma unroll
    for (int v = 0; v < 4; ++v)
      kdpack[(c0 + 4 * q + v) * 128 + 64 - dlt] = f2bf(acc[v]);
    const int row = tid >> 4, p = tid & 15;
#pragma unroll
    for (int k2 = 0; k2 < 4; ++k2) {
      const int idx = p + 16 * k2;
      const int m = (idx == 0) ? 0 : 64 + idx;
      kdpack[(c0 + row) * 128 + m] = 0;
    }
  }
}

// ======= L2: shift SSM, [d][t] domain, taps via scalar loads ================
__global__ __launch_bounds__(256) void shift_ssmT(const float* __restrict__ KrawT,
                                                  const float* __restrict__ Cs,
                                                  const float* __restrict__ Ds,
                                                  float* __restrict__ KnT) {
  __shared__ float kpad[64 + S];
  const int d = blockIdx.x, tid = threadIdx.x;
  if (tid < 64) kpad[tid] = 0.0f;
  *(float4_a*)&kpad[64 + 4 * tid] = *(const float4_a*)&KrawT[d * S + 4 * tid];
  const float dskip = Ds[d];
  const float* taps = Cs + d * HID;  // block-uniform -> scalar loads
  __syncthreads();
  float acc[4];
#pragma unroll
  for (int s = 0; s < 4; ++s) acc[s] = dskip * kpad[64 + tid + 256 * s];
  for (int j = 0; j < 64; ++j) {
    const float tj = taps[j];
#pragma unroll
    for (int s = 0; s < 4; ++s) acc[s] += tj * kpad[64 + tid + 256 * s - j];
  }
#pragma unroll
  for (int s = 0; s < 4; ++s) KnT[d * S + tid + 256 * s] = acc[s];
}

// =============== L3: s4d_fused (perm-pack + setprio) — unchanged r6 =========
__global__ __launch_bounds__(256, 2) void s4d_fused(
    const float* __restrict__ KnT, const float* __restrict__ VT,
    const float* __restrict__ QT,
    const float* __restrict__ Are, const float* __restrict__ Aim,
    const unsigned short* __restrict__ cb2pack,
    const unsigned short* __restrict__ kdpack,
    const float* __restrict__ Dd, float* __restrict__ OT) {
  __shared__ __align__(16) unsigned short SHu[18176];  // 36352 B
  const int tid = threadIdx.x;
  const int l = tid & 63, w = tid >> 6;
  const int l15 = l & 15, q = l >> 4;
  const int h = blockIdx.x >> 6, j = blockIdx.x & 63;
  const int dv = (h << 6) + j;

  // ---- inline table build: PAre/PAim [n][72], PCc [64][136] interleaved, dA64 ----
  {
    const int n = l, seg = w;
    unsigned short* PAreW = SHu;
    unsigned short* PAimW = SHu + 4608;
    unsigned short* PCcW = SHu + 9216;
    float_a* dA64W = (float_a*)(SHu + 17920);
    const float ar = Are[n], ai = Aim[n];
    const float den_re = 1.0f - 0.05f * ar;
    const float den_im = -0.05f * ai;
    const float num_re = 1.0f + 0.05f * ar;
    const float num_im = 0.05f * ai;
    const float inv_d2 = 1.0f / (den_re * den_re + den_im * den_im);
    const float dAr = (num_re * den_re + num_im * den_im) * inv_d2;
    const float dAi = (num_im * den_re - num_re * den_im) * inv_d2;
    float e2r = dAr * dAr - dAi * dAi, e2i = 2.0f * dAr * dAi;
    float e4r = e2r * e2r - e2i * e2i, e4i = 2.0f * e2r * e2i;
    float e8r = e4r * e4r - e4i * e4i, e8i = 2.0f * e4r * e4i;
    float e16r = e8r * e8r - e8i * e8i, e16i = 2.0f * e8r * e8i;
    float br = 1.0f, bi = 0.0f;
    for (int sgo = 0; sgo < seg; ++sgo) {
      const float nr = br * e16r - bi * e16i;
      bi = br * e16i + bi * e16r;
      br = nr;
    }
    float pr = br, pi = bi;
    for (int k = 16 * seg + 1; k <= 16 * seg + 16; ++k) {
      const float nr = pr * dAr - pi * dAi;
      pi = pr * dAi + pi * dAr;
      pr = nr;
      if (k <= 63) {
        PAreW[n * 72 + 63 - k] = f2bf(pr);
        PAimW[n * 72 + 63 - k] = f2bf(pi);
      }
      // interleaved (re, -im) pairs at columns 2n, 2n+1
      PCcW[(k - 1) * 136 + 2 * n] = f2bf(pr);
      PCcW[(k - 1) * 136 + 2 * n + 1] = f2bf(-pi);
      if (k == 64) {
        dA64W[2 * n] = pr;
        dA64W[2 * n + 1] = pi;
      }
    }
    if (seg == 0) {
      PAreW[n * 72 + 63] = f2bf(1.0f);
      PAimW[n * 72 + 63] = 0;
    }
  }
  // ---- V row slice in registers ----
  float4 vvr[4];
#pragma unroll
  for (int s = 0; s < 4; ++s)
    vvr[s] = *(const float4*)&VT[dv * S + 4 * l + 256 * s];

  // ---- initial per-channel scalar prefetch (channel i = w) ----
  float c2r, c2i, dd;
  unsigned int kdv;
  {
    const int c = (h << 12) + (w << 6) + j;
    c2r = bf2f(cb2pack[c * 128 + l]);
    c2i = bf2f(cb2pack[c * 128 + 64 + l]);
    kdv = *(const uint_a*)&kdpack[c * 128 + 2 * l];
    dd = Dd[c];
  }
  __syncthreads();

  // ---- hoist table fragments into registers (once per block) ----
  const unsigned short* PAre = SHu;
  const unsigned short* PAim = SHu + 4608;
  const unsigned short* PCc = SHu + 9216;
  const float_a* dA64v = (const float_a*)(SHu + 17920);
  const float er = dA64v[2 * l], ei = dA64v[2 * l + 1];
  shortx8 paR[4][2], paI[4][2];
#pragma unroll
  for (int tt = 0; tt < 4; ++tt) {
    const int rowb = (tt * 16 + l15) * 72 + 8 * q;
    paR[tt][0] = *(const shortx8_a*)&PAre[rowb];
    paR[tt][1] = *(const shortx8_a*)&PAre[rowb + 32];
    paI[tt][0] = *(const shortx8_a*)&PAim[rowb];
    paI[tt][1] = *(const shortx8_a*)&PAim[rowb + 32];
  }
  shortx8 pcb[4][4];
#pragma unroll
  for (int k = 0; k < 4; ++k)
#pragma unroll
    for (int tt = 0; tt < 4; ++tt)
      pcb[k][tt] = *(const shortx8_a*)&PCc[(tt * 16 + l15) * 136 + 8 * q + 32 * k];
  __syncthreads();  // all table reads done before workspace aliases tables

  // ---- per-wave workspace, aliased over the table region ----
  unsigned short* WB = SHu + w * 4048;
  unsigned short* Ub = WB;                    // [16][72] bf16
  unsigned short* SXY = WB + 1152;            // [16][136]: Sc -> Xcb interleaved
  uint_a* kdR32 = (uint_a*)(WB + 3328);       // 68 uints (+pad)
  unsigned short* kdSH = WB + 3472;           // [4][136]

  floatx4 OaccD[4];
  float4 Odd[4];
#pragma unroll
  for (int tt = 0; tt < 4; ++tt) OaccD[tt] = (floatx4){0.f, 0.f, 0.f, 0.f};
#pragma unroll
  for (int s = 0; s < 4; ++s) Odd[s] = make_float4(0.f, 0.f, 0.f, 0.f);

#pragma unroll 1
  for (int it = 0; it < 16; ++it) {
    // ---- prefetch next channel's HBM-cold scalars ----
    float nc2r = 0.f, nc2i = 0.f, ndd = 0.f;
    unsigned int nkdv = 0;
    if (it < 15) {
      const int c = (h << 12) + (((it + 1) * 4 + w) << 6) + j;
      nc2r = bf2f(cb2pack[c * 128 + l]);
      nc2i = bf2f(cb2pack[c * 128 + 64 + l]);
      nkdv = *(const uint_a*)&kdpack[c * 128 + 2 * l];
      ndd = Dd[c];
    }
    // ---- current-channel row loads (L2-warm: shared across 64 j-blocks) ----
    const int dk = (h << 6) + it * 4 + w;
    const int kb = dk * S + 4 * l;
    float4 kx[4], qtv[4];
#pragma unroll
    for (int s = 0; s < 4; ++s) {
      kx[s] = *(const float4*)&KnT[kb + 256 * s];
      qtv[s] = *(const float4*)&QT[kb + 256 * s];
    }

    // ---- kdR + 4 shifted copies (uses prefetched kdv; covers row loads) ----
    kdR32[l] = kdv;
    if (l < 4) kdR32[64 + l] = 0;
    asm volatile("" ::: "memory");
#pragma unroll
    for (int s2 = 0; s2 < 4; ++s2) {
      unsigned int v;
      if (s2 == 0) {
        v = kdR32[l];
      } else if (s2 == 1) {
        v = (kdR32[l] >> 16) | (kdR32[l + 1] << 16);
      } else if (s2 == 2) {
        v = kdR32[l + 1];
      } else {
        v = (kdR32[l + 1] >> 16) | (kdR32[l + 2] << 16);
      }
      *(uint_a*)&kdSH[s2 * 136 + 2 * l] = v;
    }
    asm volatile("" ::: "memory");

    // ---- u fill + dd-skip accumulation (kx/qtv die here) ----
#pragma unroll
    for (int s = 0; s < 4; ++s) {
      const int t = 4 * l + 256 * s;
      const int g = t >> 6, r = t & 63;
      const float ux = kx[s].x * vvr[s].x;
      const float uy = kx[s].y * vvr[s].y;
      const float uz = kx[s].z * vvr[s].z;
      const float uw = kx[s].w * vvr[s].w;
      uint2_a pp;
      pp.x = pk_bf16(ux, uy);
      pp.y = pk_bf16(uz, uw);
      *(uint2_a*)&Ub[g * 72 + r] = pp;
      Odd[s].x += dd * qtv[s].x * ux;
      Odd[s].y += dd * qtv[s].y * uy;
      Odd[s].z += dd * qtv[s].z * uz;
      Odd[s].w += dd * qtv[s].w * uw;
    }
    asm volatile("" ::: "memory");

    // ---- phase A: s~[g][n] via MFMA (A-fragments in registers) ----
    const shortx8 b0 = *(const shortx8_a*)&Ub[l15 * 72 + 8 * q];
    const shortx8 b1 = *(const shortx8_a*)&Ub[l15 * 72 + 8 * q + 32];
    __builtin_amdgcn_s_setprio(1);
#pragma unroll
    for (int tt = 0; tt < 4; ++tt) {
      floatx4 z = {0.f, 0.f, 0.f, 0.f};
      floatx4 sre = __builtin_amdgcn_mfma_f32_16x16x32_bf16(paR[tt][0], b0, z, 0, 0, 0);
      sre = __builtin_amdgcn_mfma_f32_16x16x32_bf16(paR[tt][1], b1, sre, 0, 0, 0);
      floatx4 sim = __builtin_amdgcn_mfma_f32_16x16x32_bf16(paI[tt][0], b0, z, 0, 0, 0);
      sim = __builtin_amdgcn_mfma_f32_16x16x32_bf16(paI[tt][1], b1, sim, 0, 0, 0);
      // interleaved: row g=l15, columns 2n..2n+7 for n = tt*16+4q+(0..3)
      uint4_a wv;
      wv[0] = pk_bf16(sre[0], sim[0]);
      wv[1] = pk_bf16(sre[1], sim[1]);
      wv[2] = pk_bf16(sre[2], sim[2]);
      wv[3] = pk_bf16(sre[3], sim[3]);
      *(uint4_a*)&SXY[l15 * 136 + 32 * tt + 8 * q] = wv;
    }
    __builtin_amdgcn_s_setprio(0);
    asm volatile("" ::: "memory");

    // ---- register scan: batch-load packed Sc, pure-VALU recurrence ----
    {
      unsigned int rdv[16];
#pragma unroll
      for (int g = 0; g < 16; ++g) rdv[g] = *(const uint_a*)&SXY[g * 136 + 2 * l];
      float xr = 0.f, xi = 0.f;
#pragma unroll
      for (int g = 0; g < 16; ++g) {
        *(uint_a*)&SXY[g * 136 + 2 * l] =
            pk_bf16(c2r * xr - c2i * xi, c2r * xi + c2i * xr);
        union { unsigned int u; float f; } lo, hi;
        lo.u = rdv[g] << 16;
        hi.u = rdv[g] & 0xffff0000u;
        const float nr = er * xr - ei * xi + lo.f;
        xi = er * xi + ei * xr + hi.f;
        xr = nr;
      }
    }
    asm volatile("" ::: "memory");

    // ---- qD loads (L2-warm; consumed after phase C -> latency covered) ----
    float qD[16];
    {
      const int qb = dk * S + 256 * q + l15;
#pragma unroll
      for (int tt = 0; tt < 4; ++tt)
#pragma unroll
        for (int v = 0; v < 4; ++v)
          qD[4 * tt + v] = QT[qb + 64 * v + 16 * tt];
    }

    // ---- phase C MFMAs (B-fragments in registers) ----
    floatx4 acc[4];
#pragma unroll
    for (int tt = 0; tt < 4; ++tt) acc[tt] = (floatx4){0.f, 0.f, 0.f, 0.f};
    __builtin_amdgcn_s_setprio(1);
#pragma unroll
    for (int k = 0; k < 4; ++k) {
      const shortx8 xa = *(const shortx8_a*)&SXY[l15 * 136 + 8 * q + 32 * k];
#pragma unroll
      for (int tt = 0; tt < 4; ++tt)
        acc[tt] = __builtin_amdgcn_mfma_f32_16x16x32_bf16(xa, pcb[k][tt], acc[tt], 0, 0, 0);
    }
#pragma unroll
    for (int k = 0; k < 2; ++k) {
      const shortx8 ua = (k == 0) ? b0 : b1;
#pragma unroll
      for (int tt = 0; tt < 4; ++tt) {
        const int r = tt * 16 + l15;
        const int sSh = (4 - (r & 3)) & 3;
        const int addr = sSh * 136 + (64 - r - sSh) + 8 * q + 32 * k;
        const shortx4_a lo = *(const shortx4_a*)&kdSH[addr];
        const shortx4_a hi = *(const shortx4_a*)&kdSH[addr + 4];
        const shortx8 kb8 = __builtin_shufflevector(lo, hi, 0, 1, 2, 3, 4, 5, 6, 7);
        acc[tt] = __builtin_amdgcn_mfma_f32_16x16x32_bf16(ua, kb8, acc[tt], 0, 0, 0);
      }
    }
    __builtin_amdgcn_s_setprio(0);
    // ---- accumulate O in D-layout ----
#pragma unroll
    for (int tt = 0; tt < 4; ++tt)
#pragma unroll
      for (int v = 0; v < 4; ++v)
        OaccD[tt][v] += qD[4 * tt + v] * acc[tt][v];
    // ---- rotate per-channel scalars ----
    c2r = nc2r; c2i = nc2i; kdv = nkdv; dd = ndd;
  }

  // ---- once-per-block: redistribute D-layout O to t-layout, fold dd-term ----
  asm volatile("" ::: "memory");
  {
    float_a* Ored = (float_a*)WB;  // padded [1028]: idx' = t + (t>>8)
#pragma unroll
    for (int tt = 0; tt < 4; ++tt)
#pragma unroll
      for (int v = 0; v < 4; ++v)
        Ored[256 * q + 64 * v + 16 * tt + l15 + q] = OaccD[tt][v];
    asm volatile("" ::: "memory");
    float4 Oa[4];
#pragma unroll
    for (int s = 0; s < 4; ++s) {
      const float4_a y4 = *(const float4_a*)&Ored[4 * l + 257 * s];
      Oa[s].x = y4.x + Odd[s].x;
      Oa[s].y = y4.y + Odd[s].y;
      Oa[s].z = y4.z + Odd[s].z;
      Oa[s].w = y4.w + Odd[s].w;
    }
    asm volatile("" ::: "memory");
#pragma unroll
    for (int s = 0; s < 4; ++s) {
      float4_a vv = {Oa[s].x, Oa[s].y, Oa[s].z, Oa[s].w};
      *(float4_a*)&Ored[4 * l + 256 * s] = vv;
    }
  }
  __syncthreads();
  {
    const int tq = 256 * w + 4 * l;
    float4_a acc = {0.f, 0.f, 0.f, 0.f};
#pragma unroll
    for (int w2 = 0; w2 < 4; ++w2) {
      const float_a* Ow2 = (const float_a*)(SHu + w2 * 4048);
      acc += *(const float4_a*)&Ow2[tq];
    }
    *(float4_a*)&OT[dv * S + tq] = acc;
  }
}

// ====== L4: out[m][n] = sum_k OT[k][m]*WO[n][k] via bf16 hi/lo MFMA =========
// Round-8: staging conversions use cvt_hilo_pk (W side, pair-packable) and
// cvt_hilo_fast (OT transpose side, scalar stores) — ~2x staging VALU cut.
__global__ __launch_bounds__(256) void gemm_outT(const float* __restrict__ OT,
                                                 const float* __restrict__ WO,
                                                 float* __restrict__ out) {
  __shared__ __align__(16) char LB[20480];
  unsigned short* Wh = (unsigned short*)LB;  // [64][40] WO planes
  unsigned short* Wl = Wh + 2560;
  unsigned short* Xh = Wl + 2560;            // [64][40] O1 planes (m rows)
  unsigned short* Xl = Xh + 2560;
  float_a* Ct = (float_a*)LB;                // [64][68] aliased
  const int tid = threadIdx.x;
  const int l = tid & 63, w = tid >> 6;
  const int l15 = l & 15, q = l >> 4;
  const int n0 = (blockIdx.x & 7) * 64, m0 = (blockIdx.x >> 3) * 64;

  floatx4 acc[4];
#pragma unroll
  for (int nt = 0; nt < 4; ++nt) acc[nt] = (floatx4){0.f, 0.f, 0.f, 0.f};

  for (int k0 = 0; k0 < D; k0 += 32) {
    if (k0) __syncthreads();
#pragma unroll
    for (int p = 0; p < 2; ++p) {
      const int idx = tid + 256 * p;
      // WO rows (n-local), k-contiguous
      {
        const int row = idx >> 3, c4 = (idx & 7) * 4;
        const float4 wv = *(const float4*)&WO[(n0 + row) * D + k0 + c4];
        const hilo_pair w01 = cvt_hilo_pk(wv.x, wv.y);
        const hilo_pair w23 = cvt_hilo_pk(wv.z, wv.w);
        uint2_a hv = {w01.hp, w23.hp};
        uint2_a lv = {w01.lp, w23.lp};
        *(uint2_a*)&Wh[row * 40 + c4] = hv;
        *(uint2_a*)&Wl[row * 40 + c4] = lv;
      }
      // OT tile: read [k][m] coalesced, store transposed [m][k]
      {
        const int kk = idx >> 4, m4 = (idx & 15) * 4;
        const float4 ov = *(const float4*)&OT[(k0 + kk) * S + m0 + m4];
        unsigned short h, g;
        cvt_hilo_fast(ov.x, h, g); Xh[(m4 + 0) * 40 + kk] = h; Xl[(m4 + 0) * 40 + kk] = g;
        cvt_hilo_fast(ov.y, h, g); Xh[(m4 + 1) * 40 + kk] = h; Xl[(m4 + 1) * 40 + kk] = g;
        cvt_hilo_fast(ov.z, h, g); Xh[(m4 + 2) * 40 + kk] = h; Xl[(m4 + 2) * 40 + kk] = g;
        cvt_hilo_fast(ov.w, h, g); Xh[(m4 + 3) * 40 + kk] = h; Xl[(m4 + 3) * 40 + kk] = g;
      }
    }
    __syncthreads();
    const shortx8 xh = *(const shortx8_a*)&Xh[(16 * w + l15) * 40 + 8 * q];
    const shortx8 xl = *(const shortx8_a*)&Xl[(16 * w + l15) * 40 + 8 * q];
#pragma unroll
    for (int nt = 0; nt < 4; ++nt) {
      const shortx8 wh = *(const shortx8_a*)&Wh[(16 * nt + l15) * 40 + 8 * q];
      const shortx8 wl = *(const shortx8_a*)&Wl[(16 * nt + l15) * 40 + 8 * q];
      acc[nt] = __builtin_amdgcn_mfma_f32_16x16x32_bf16(wh, xh, acc[nt], 0, 0, 0);
      acc[nt] = __builtin_amdgcn_mfma_f32_16x16x32_bf16(wh, xl, acc[nt], 0, 0, 0);
      acc[nt] = __builtin_amdgcn_mfma_f32_16x16x32_bf16(wl, xh, acc[nt], 0, 0, 0);
    }
  }
  __syncthreads();
  // lane holds D[n = 16nt+4q+v][m = 16w+l15] -> Ct[m][n]
#pragma unroll
  for (int nt = 0; nt < 4; ++nt)
#pragma unroll
    for (int v = 0; v < 4; ++v)
      Ct[(16 * w + l15) * 68 + 16 * nt + 4 * q + v] = acc[nt][v];
  __syncthreads();
#pragma unroll
  for (int p = 0; p < 4; ++p) {
    const int row = (tid >> 4) + 16 * p;
    const int col4 = (tid & 15) * 4;
    *(float4_a*)&out[(m0 + row) * D + n0 + col4] = *(const float4_a*)&Ct[row * 68 + col4];
  }
}

extern "C" void kernel_launch(void* const* d_in, const int* in_sizes, int n_in,
                              void* d_out, int out_size, void* d_ws, size_t ws_size,
                              hipStream_t stream) {
  const float* x   = (const float*)d_in[0];
  const float* WQ  = (const float*)d_in[1];
  const float* WK  = (const float*)d_in[2];
  const float* WV  = (const float*)d_in[3];
  const float* WO  = (const float*)d_in[4];
  const float* Cs  = (const float*)d_in[5];
  const float* Ds  = (const float*)d_in[6];
  const float* Are = (const float*)d_in[7];
  const float* Aim = (const float*)d_in[8];
  const float* Cre = (const float*)d_in[9];
  const float* Cim = (const float*)d_in[10];
  const float* Dd  = (const float*)d_in[11];
  float* out = (float*)d_out;

  char* ws = (char*)d_ws;
  const size_t SD = (size_t)S * D * 4;   // 2 MB
  float* QT    = (float*)(ws + 0 * SD);
  float* KrawT = (float*)(ws + 1 * SD);
  float* VT    = (float*)(ws + 2 * SD);
  float* KnT   = (float*)(ws + 3 * SD);
  float* OT    = (float*)(ws + 4 * SD);
  unsigned short* cb2pack = (unsigned short*)(ws + 5 * SD);            // 8 MB
  unsigned short* kdpack  = (unsigned short*)(ws + 5 * SD + 8388608);  // 8 MB

  fused_qkv_cbkd<<<384 + CD / 16, 256, 0, stream>>>(
      x, WQ, WK, WV, Are, Aim, Cre, Cim, QT, KrawT, VT, cb2pack, kdpack);
  shift_ssmT<<<512, 256, 0, stream>>>(KrawT, Cs, Ds, KnT);
  s4d_fused<<<512, 256, 0, stream>>>(KnT, VT, QT, Are, Aim, cb2pack, kdpack, Dd, OT);
  gemm_outT<<<128, 256, 0, stream>>>(OT, WO, out);
}

// Round 9
// 176.145 us; speedup vs baseline: 1.9178x; 1.0083x over previous
//
#include <hip/hip_runtime.h>

#define S 1024
#define D 512
#define HID 64
#define CD 32768
#define DT 0.1f

typedef __attribute__((ext_vector_type(4))) float floatx4;
typedef __attribute__((ext_vector_type(8))) short shortx8;
// may_alias variants for type-punned LDS/global access (TBAA-safe)
typedef short shortx8_a __attribute__((ext_vector_type(8), may_alias));
typedef short shortx4_a __attribute__((ext_vector_type(4), may_alias));
typedef unsigned int uint_a __attribute__((may_alias));
typedef unsigned int uint2_a __attribute__((ext_vector_type(2), may_alias));
typedef unsigned int uint4_a __attribute__((ext_vector_type(4), may_alias));
typedef float float4_a __attribute__((ext_vector_type(4), may_alias));
typedef float float_a __attribute__((may_alias));

__device__ __forceinline__ unsigned short f2bf(float f) {
  union { float f; unsigned int u; } v;
  v.f = f;
  unsigned int r = v.u + 0x7FFFu + ((v.u >> 16) & 1u);
  return (unsigned short)(r >> 16);
}
__device__ __forceinline__ float bf2f(unsigned short h) {
  union { unsigned int u; float f; } v;
  v.u = ((unsigned int)h) << 16;
  return v.f;
}
// hi/lo split: v ~= bf2f(h) + bf2f(lo), ~16-bit mantissa accuracy
__device__ __forceinline__ void cvt_hilo(float v, unsigned short& h, unsigned short& lo) {
  h = f2bf(v);
  lo = f2bf(v - bf2f(h));
}
// packed f32x2 -> bf16x2: round-half-up (+0x8000) then one v_perm_b32 byte
// pack. perm(A,B,sel): sel bytes 0-3 index B (low source), 4-7 index A, so
// sel 0x07060302 = {A.b3,A.b2,B.b3,B.b2} -> a lands in dst[15:0] exactly like
// f2bf(a)|f2bf(b)<<16. Half-up differs from RNE only on exact ties (<=1 ulp,
// ~2^-17 probability) — negligible (round-6 verified: absmax 0.59 vs 1.49).
__device__ __forceinline__ unsigned int pk_bf16(float a, float b) {
  union { float f; unsigned int u; } va, vb;
  va.f = a; vb.f = b;
  return __builtin_amdgcn_perm(vb.u + 0x8000u, va.u + 0x8000u, 0x07060302u);
}
// fast hi/lo pair: half-up hi plane + residual lo plane, packed. Returned by
// value (vector elements can't bind to non-const refs — round-7 compile fix).
struct hilo_pair { unsigned int hp, lp; };
__device__ __forceinline__ hilo_pair cvt_hilo_pk(float a, float b) {
  union { float f; unsigned int u; } va, vb;
  va.f = a; vb.f = b;
  const unsigned int ra = va.u + 0x8000u, rb = vb.u + 0x8000u;
  hilo_pair r;
  r.hp = __builtin_amdgcn_perm(rb, ra, 0x07060302u);
  union { unsigned int u; float f; } ha, hb;
  ha.u = ra & 0xffff0000u;   // bf2f(hi_a)
  hb.u = rb & 0xffff0000u;
  union { float f; unsigned int u; } la, lb;
  la.f = a - ha.f; lb.f = b - hb.f;
  r.lp = __builtin_amdgcn_perm(lb.u + 0x8000u, la.u + 0x8000u, 0x07060302u);
  return r;
}
// fast scalar hi/lo (for transpose stores where pairs land in different rows)
__device__ __forceinline__ void cvt_hilo_fast(float v, unsigned short& h,
                                              unsigned short& lo) {
  union { float f; unsigned int u; } x;
  x.f = v;
  const unsigned int r = x.u + 0x8000u;
  h = (unsigned short)(r >> 16);
  union { unsigned int u; float f; } hf;
  hf.u = r & 0xffff0000u;
  union { float f; unsigned int u; } l;
  l.f = v - hf.f;
  lo = (unsigned short)((l.u + 0x8000u) >> 16);
}

// =====================  L1: fused QKV-GEMM + cbkd  ==========================
// blocks [0,384): {Q,Kraw,V}T[n][m] = sum_k x[m][k]*W[n][k] via bf16 hi/lo MFMA
// blocks [384,2432): per-16-channel cb2 + kd build (inline dA-power table)
__global__ __launch_bounds__(256) void fused_qkv_cbkd(
    const float* __restrict__ x, const float* __restrict__ WQ,
    const float* __restrict__ WK, const float* __restrict__ WV,
    const float* __restrict__ Are, const float* __restrict__ Aim,
    const float* __restrict__ Cre, const float* __restrict__ Cim,
    float* __restrict__ QT, float* __restrict__ KrawT, float* __restrict__ VT,
    unsigned short* __restrict__ cb2pack, unsigned short* __restrict__ kdpack) {
  __shared__ __align__(16) char LB[21760];
  const int tid = threadIdx.x;
  const int bid = blockIdx.x;
  const int l = tid & 63, w = tid >> 6;
  const int l15 = l & 15, q = l >> 4;

  if (bid < 384) {
    // ---------------- QKV GEMM: 64x64 tile, K=512, BK=32 ----------------
    unsigned short* Wh = (unsigned short*)LB;     // [64][40]
    unsigned short* Wl = Wh + 2560;
    unsigned short* Xh = Wl + 2560;
    unsigned short* Xl = Xh + 2560;
    float_a* Ct = (float_a*)LB;                   // [64][68], aliased after loop
    const int mat = bid >> 7;                     // /128
    const int rem = bid & 127;
    const int n0 = (rem & 7) * 64, m0 = (rem >> 3) * 64;
    const float* Wsel = (mat == 0) ? WQ : (mat == 1) ? WK : WV;
    float* CT = (mat == 0) ? QT : (mat == 1) ? KrawT : VT;

    floatx4 acc[4];
#pragma unroll
    for (int nt = 0; nt < 4; ++nt) acc[nt] = (floatx4){0.f, 0.f, 0.f, 0.f};

    for (int k0 = 0; k0 < D; k0 += 32) {
      if (k0) __syncthreads();
#pragma unroll
      for (int p = 0; p < 2; ++p) {
        const int idx = tid + 256 * p;
        const int row = idx >> 3, c4 = (idx & 7) * 4;
        const float4 wv = *(const float4*)&Wsel[(n0 + row) * D + k0 + c4];
        const float4 xv = *(const float4*)&x[(m0 + row) * D + k0 + c4];
        const hilo_pair w01 = cvt_hilo_pk(wv.x, wv.y);
        const hilo_pair w23 = cvt_hilo_pk(wv.z, wv.w);
        uint2_a hv = {w01.hp, w23.hp};
        uint2_a lv = {w01.lp, w23.lp};
        *(uint2_a*)&Wh[row * 40 + c4] = hv;
        *(uint2_a*)&Wl[row * 40 + c4] = lv;
        const hilo_pair x01 = cvt_hilo_pk(xv.x, xv.y);
        const hilo_pair x23 = cvt_hilo_pk(xv.z, xv.w);
        uint2_a hv2 = {x01.hp, x23.hp};
        uint2_a lv2 = {x01.lp, x23.lp};
        *(uint2_a*)&Xh[row * 40 + c4] = hv2;
        *(uint2_a*)&Xl[row * 40 + c4] = lv2;
      }
      __syncthreads();
      const shortx8 xh = *(const shortx8_a*)&Xh[(16 * w + l15) * 40 + 8 * q];
      const shortx8 xl = *(const shortx8_a*)&Xl[(16 * w + l15) * 40 + 8 * q];
#pragma unroll
      for (int nt = 0; nt < 4; ++nt) {
        const shortx8 wh = *(const shortx8_a*)&Wh[(16 * nt + l15) * 40 + 8 * q];
        const shortx8 wl = *(const shortx8_a*)&Wl[(16 * nt + l15) * 40 + 8 * q];
        acc[nt] = __builtin_amdgcn_mfma_f32_16x16x32_bf16(wh, xh, acc[nt], 0, 0, 0);
        acc[nt] = __builtin_amdgcn_mfma_f32_16x16x32_bf16(wh, xl, acc[nt], 0, 0, 0);
        acc[nt] = __builtin_amdgcn_mfma_f32_16x16x32_bf16(wl, xh, acc[nt], 0, 0, 0);
      }
    }
    __syncthreads();
    // lane holds D[n = 16nt+4q+v][m = 16w+l15] -> Ct[n][m]
#pragma unroll
    for (int nt = 0; nt < 4; ++nt)
#pragma unroll
      for (int v = 0; v < 4; ++v)
        Ct[(16 * nt + 4 * q + v) * 68 + 16 * w + l15] = acc[nt][v];
    __syncthreads();
#pragma unroll
    for (int p = 0; p < 4; ++p) {
      const int row = (tid >> 4) + 16 * p;
      const int col4 = (tid & 15) * 4;
      *(float4_a*)&CT[(n0 + row) * S + m0 + col4] = *(const float4_a*)&Ct[row * 68 + col4];
    }
  } else {
    // ---------------- cbkd: c0 = (bid-384)*16 ----------------
    unsigned short* cbs = (unsigned short*)LB;          // [16][136]
    unsigned short* PCc2s = (unsigned short*)(LB + 4352);  // [64][136]
    const int c0 = (bid - 384) << 4;
    // inline PCc2 table build: thread (n=l, seg=w)
    {
      const int n = l, seg = w;
      const float ar = Are[n], ai = Aim[n];
      const float den_re = 1.0f - 0.05f * ar;
      const float den_im = -0.05f * ai;
      const float num_re = 1.0f + 0.05f * ar;
      const float num_im = 0.05f * ai;
      const float inv_d2 = 1.0f / (den_re * den_re + den_im * den_im);
      const float dAr = (num_re * den_re + num_im * den_im) * inv_d2;
      const float dAi = (num_im * den_re - num_re * den_im) * inv_d2;
      float e2r = dAr * dAr - dAi * dAi, e2i = 2.0f * dAr * dAi;
      float e4r = e2r * e2r - e2i * e2i, e4i = 2.0f * e2r * e2i;
      float e8r = e4r * e4r - e4i * e4i, e8i = 2.0f * e4r * e4i;
      float e16r = e8r * e8r - e8i * e8i, e16i = 2.0f * e8r * e8i;
      float br = 1.0f, bi = 0.0f;
      for (int sgo = 0; sgo < seg; ++sgo) {
        const float nr = br * e16r - bi * e16i;
        bi = br * e16i + bi * e16r;
        br = nr;
      }
      float pr = br, pi = bi;
      for (int k = 16 * seg + 1; k <= 16 * seg + 16; ++k) {
        const float nr = pr * dAr - pi * dAi;
        pi = pr * dAi + pi * dAr;
        pr = nr;
        if (k <= 63) {
          PCc2s[k * 136 + n] = f2bf(pr);
          PCc2s[k * 136 + 64 + n] = f2bf(-pi);
        }
      }
      if (seg == 0) {
        PCc2s[n] = f2bf(1.0f);
        PCc2s[64 + n] = 0;
      }
    }
    // cb2 build
#pragma unroll
    for (int ii = 0; ii < 4; ++ii) {
      const int idx = tid + 256 * ii;
      const int ci = idx >> 6, n = idx & 63;
      const int c = c0 + ci;
      const float ar = Are[n], ai = Aim[n];
      const float den_re = 1.0f - 0.05f * ar;
      const float den_im = -0.05f * ai;
      const float inv_d2 = 1.0f / (den_re * den_re + den_im * den_im);
      const float dBr = DT * den_re * inv_d2;
      const float dBi = -DT * den_im * inv_d2;
      const float cr = Cre[c * HID + n], cim = Cim[c * HID + n];
      const unsigned short re = f2bf(2.0f * (cr * dBr - cim * dBi));
      const unsigned short im = f2bf(2.0f * (cr * dBi + cim * dBr));
      cbs[ci * 136 + n] = re;
      cbs[ci * 136 + 64 + n] = im;
      cb2pack[c * 128 + n] = re;
      cb2pack[c * 128 + 64 + n] = im;
    }
    __syncthreads();
    // kd GEMM -> kdpack (kdR layout)
    floatx4 acc = {0.f, 0.f, 0.f, 0.f};
#pragma unroll
    for (int k = 0; k < 4; ++k) {
      const shortx8 a = *(const shortx8_a*)&cbs[l15 * 136 + 8 * q + 32 * k];
      const shortx8 b = *(const shortx8_a*)&PCc2s[(16 * w + l15) * 136 + 8 * q + 32 * k];
      acc = __builtin_amdgcn_mfma_f32_16x16x32_bf16(a, b, acc, 0, 0, 0);
    }
    const int dlt = 16 * w + l15;
#pragma unroll
    for (int v = 0; v < 4; ++v)
      kdpack[(c0 + 4 * q + v) * 128 + 64 - dlt] = f2bf(acc[v]);
    const int row = tid >> 4, p = tid & 15;
#pragma unroll
    for (int k2 = 0; k2 < 4; ++k2) {
      const int idx = p + 16 * k2;
      const int m = (idx == 0) ? 0 : 64 + idx;
      kdpack[(c0 + row) * 128 + m] = 0;
    }
  }
}

// ======= L2: shift SSM, [d][t] domain — rolling-window float4 reads =========
// Round-9: per-thread 4 outputs (t = 4*tid..4*tid+3) with a rolling 2xfloat4
// window over the 64-tap history: 17 ds_read_b128/thread instead of 256
// ds_read_b32 (~7x LDS-pipe cut). Shuffled-window FMA operands are direct
// register-component references (zero extra instructions). Accumulation
// order per output is bitwise-identical to the previous version (j ascending).
__global__ __launch_bounds__(256) void shift_ssmT(const float* __restrict__ KrawT,
                                                  const float* __restrict__ Cs,
                                                  const float* __restrict__ Ds,
                                                  float* __restrict__ KnT) {
  __shared__ __align__(16) float kpad[64 + S];
  const int d = blockIdx.x, tid = threadIdx.x;
  if (tid < 64) kpad[tid] = 0.0f;
  *(float4_a*)&kpad[64 + 4 * tid] = *(const float4_a*)&KrawT[d * S + 4 * tid];
  const float dskip = Ds[d];
  const float* taps = Cs + d * HID;  // block-uniform -> scalar loads
  __syncthreads();
  const float4_a* kp4 = (const float4_a*)kpad;
  // outputs t = 4*tid+c; float base index tb = 64 + 4*tid = 4*(16+tid)
  float4_a B = kp4[16 + tid];
  float acc0 = dskip * B.x, acc1 = dskip * B.y, acc2 = dskip * B.z, acc3 = dskip * B.w;
#pragma unroll
  for (int j4 = 0; j4 < 64; j4 += 4) {
    const float4_a A = kp4[16 + tid - (j4 >> 2) - 1];  // floats tb-j4-4 .. tb-j4-1
    const float t0 = taps[j4], t1 = taps[j4 + 1];
    const float t2 = taps[j4 + 2], t3 = taps[j4 + 3];
    // r=0: kpad[tb+c-j4]      = {B.x,B.y,B.z,B.w}
    acc0 += t0 * B.x; acc1 += t0 * B.y; acc2 += t0 * B.z; acc3 += t0 * B.w;
    // r=1: kpad[tb+c-j4-1]    = {A.w,B.x,B.y,B.z}
    acc0 += t1 * A.w; acc1 += t1 * B.x; acc2 += t1 * B.y; acc3 += t1 * B.z;
    // r=2: kpad[tb+c-j4-2]    = {A.z,A.w,B.x,B.y}
    acc0 += t2 * A.z; acc1 += t2 * A.w; acc2 += t2 * B.x; acc3 += t2 * B.y;
    // r=3: kpad[tb+c-j4-3]    = {A.y,A.z,A.w,B.x}
    acc0 += t3 * A.y; acc1 += t3 * A.z; acc2 += t3 * A.w; acc3 += t3 * B.x;
    B = A;  // rolls: next group's B = kp4[16+tid-(j4+4)/4]
  }
  float4_a o = {acc0, acc1, acc2, acc3};
  *(float4_a*)&KnT[d * S + 4 * tid] = o;
}

// =============== L3: s4d_fused (perm-pack + setprio) ========================
// Round-9: hoisted the loop-invariant kdR32 zero-pad out of the channel loop.
__global__ __launch_bounds__(256, 2) void s4d_fused(
    const float* __restrict__ KnT, const float* __restrict__ VT,
    const float* __restrict__ QT,
    const float* __restrict__ Are, const float* __restrict__ Aim,
    const unsigned short* __restrict__ cb2pack,
    const unsigned short* __restrict__ kdpack,
    const float* __restrict__ Dd, float* __restrict__ OT) {
  __shared__ __align__(16) unsigned short SHu[18176];  // 36352 B
  const int tid = threadIdx.x;
  const int l = tid & 63, w = tid >> 6;
  const int l15 = l & 15, q = l >> 4;
  const int h = blockIdx.x >> 6, j = blockIdx.x & 63;
  const int dv = (h << 6) + j;

  // ---- inline table build: PAre/PAim [n][72], PCc [64][136] interleaved, dA64 ----
  {
    const int n = l, seg = w;
    unsigned short* PAreW = SHu;
    unsigned short* PAimW = SHu + 4608;
    unsigned short* PCcW = SHu + 9216;
    float_a* dA64W = (float_a*)(SHu + 17920);
    const float ar = Are[n], ai = Aim[n];
    const float den_re = 1.0f - 0.05f * ar;
    const float den_im = -0.05f * ai;
    const float num_re = 1.0f + 0.05f * ar;
    const float num_im = 0.05f * ai;
    const float inv_d2 = 1.0f / (den_re * den_re + den_im * den_im);
    const float dAr = (num_re * den_re + num_im * den_im) * inv_d2;
    const float dAi = (num_im * den_re - num_re * den_im) * inv_d2;
    float e2r = dAr * dAr - dAi * dAi, e2i = 2.0f * dAr * dAi;
    float e4r = e2r * e2r - e2i * e2i, e4i = 2.0f * e2r * e2i;
    float e8r = e4r * e4r - e4i * e4i, e8i = 2.0f * e4r * e4i;
    float e16r = e8r * e8r - e8i * e8i, e16i = 2.0f * e8r * e8i;
    float br = 1.0f, bi = 0.0f;
    for (int sgo = 0; sgo < seg; ++sgo) {
      const float nr = br * e16r - bi * e16i;
      bi = br * e16i + bi * e16r;
      br = nr;
    }
    float pr = br, pi = bi;
    for (int k = 16 * seg + 1; k <= 16 * seg + 16; ++k) {
      const float nr = pr * dAr - pi * dAi;
      pi = pr * dAi + pi * dAr;
      pr = nr;
      if (k <= 63) {
        PAreW[n * 72 + 63 - k] = f2bf(pr);
        PAimW[n * 72 + 63 - k] = f2bf(pi);
      }
      // interleaved (re, -im) pairs at columns 2n, 2n+1
      PCcW[(k - 1) * 136 + 2 * n] = f2bf(pr);
      PCcW[(k - 1) * 136 + 2 * n + 1] = f2bf(-pi);
      if (k == 64) {
        dA64W[2 * n] = pr;
        dA64W[2 * n + 1] = pi;
      }
    }
    if (seg == 0) {
      PAreW[n * 72 + 63] = f2bf(1.0f);
      PAimW[n * 72 + 63] = 0;
    }
  }
  // ---- V row slice in registers ----
  float4 vvr[4];
#pragma unroll
  for (int s = 0; s < 4; ++s)
    vvr[s] = *(const float4*)&VT[dv * S + 4 * l + 256 * s];

  // ---- initial per-channel scalar prefetch (channel i = w) ----
  float c2r, c2i, dd;
  unsigned int kdv;
  {
    const int c = (h << 12) + (w << 6) + j;
    c2r = bf2f(cb2pack[c * 128 + l]);
    c2i = bf2f(cb2pack[c * 128 + 64 + l]);
    kdv = *(const uint_a*)&kdpack[c * 128 + 2 * l];
    dd = Dd[c];
  }
  __syncthreads();

  // ---- hoist table fragments into registers (once per block) ----
  const unsigned short* PAre = SHu;
  const unsigned short* PAim = SHu + 4608;
  const unsigned short* PCc = SHu + 9216;
  const float_a* dA64v = (const float_a*)(SHu + 17920);
  const float er = dA64v[2 * l], ei = dA64v[2 * l + 1];
  shortx8 paR[4][2], paI[4][2];
#pragma unroll
  for (int tt = 0; tt < 4; ++tt) {
    const int rowb = (tt * 16 + l15) * 72 + 8 * q;
    paR[tt][0] = *(const shortx8_a*)&PAre[rowb];
    paR[tt][1] = *(const shortx8_a*)&PAre[rowb + 32];
    paI[tt][0] = *(const shortx8_a*)&PAim[rowb];
    paI[tt][1] = *(const shortx8_a*)&PAim[rowb + 32];
  }
  shortx8 pcb[4][4];
#pragma unroll
  for (int k = 0; k < 4; ++k)
#pragma unroll
    for (int tt = 0; tt < 4; ++tt)
      pcb[k][tt] = *(const shortx8_a*)&PCc[(tt * 16 + l15) * 136 + 8 * q + 32 * k];
  __syncthreads();  // all table reads done before workspace aliases tables

  // ---- per-wave workspace, aliased over the table region ----
  unsigned short* WB = SHu + w * 4048;
  unsigned short* Ub = WB;                    // [16][72] bf16
  unsigned short* SXY = WB + 1152;            // [16][136]: Sc -> Xcb interleaved
  uint_a* kdR32 = (uint_a*)(WB + 3328);       // 68 uints (+pad)
  unsigned short* kdSH = WB + 3472;           // [4][136]

  // loop-invariant zero-pad of kdR32 tail (round-9 hoist)
  if (l < 4) kdR32[64 + l] = 0;

  floatx4 OaccD[4];
  float4 Odd[4];
#pragma unroll
  for (int tt = 0; tt < 4; ++tt) OaccD[tt] = (floatx4){0.f, 0.f, 0.f, 0.f};
#pragma unroll
  for (int s = 0; s < 4; ++s) Odd[s] = make_float4(0.f, 0.f, 0.f, 0.f);

#pragma unroll 1
  for (int it = 0; it < 16; ++it) {
    // ---- prefetch next channel's HBM-cold scalars ----
    float nc2r = 0.f, nc2i = 0.f, ndd = 0.f;
    unsigned int nkdv = 0;
    if (it < 15) {
      const int c = (h << 12) + (((it + 1) * 4 + w) << 6) + j;
      nc2r = bf2f(cb2pack[c * 128 + l]);
      nc2i = bf2f(cb2pack[c * 128 + 64 + l]);
      nkdv = *(const uint_a*)&kdpack[c * 128 + 2 * l];
      ndd = Dd[c];
    }
    // ---- current-channel row loads (L2-warm: shared across 64 j-blocks) ----
    const int dk = (h << 6) + it * 4 + w;
    const int kb = dk * S + 4 * l;
    float4 kx[4], qtv[4];
#pragma unroll
    for (int s = 0; s < 4; ++s) {
      kx[s] = *(const float4*)&KnT[kb + 256 * s];
      qtv[s] = *(const float4*)&QT[kb + 256 * s];
    }

    // ---- kdR + 4 shifted copies (uses prefetched kdv; covers row loads) ----
    kdR32[l] = kdv;
    asm volatile("" ::: "memory");
#pragma unroll
    for (int s2 = 0; s2 < 4; ++s2) {
      unsigned int v;
      if (s2 == 0) {
        v = kdR32[l];
      } else if (s2 == 1) {
        v = (kdR32[l] >> 16) | (kdR32[l + 1] << 16);
      } else if (s2 == 2) {
        v = kdR32[l + 1];
      } else {
        v = (kdR32[l + 1] >> 16) | (kdR32[l + 2] << 16);
      }
      *(uint_a*)&kdSH[s2 * 136 + 2 * l] = v;
    }
    asm volatile("" ::: "memory");

    // ---- u fill + dd-skip accumulation (kx/qtv die here) ----
#pragma unroll
    for (int s = 0; s < 4; ++s) {
      const int t = 4 * l + 256 * s;
      const int g = t >> 6, r = t & 63;
      const float ux = kx[s].x * vvr[s].x;
      const float uy = kx[s].y * vvr[s].y;
      const float uz = kx[s].z * vvr[s].z;
      const float uw = kx[s].w * vvr[s].w;
      uint2_a pp;
      pp.x = pk_bf16(ux, uy);
      pp.y = pk_bf16(uz, uw);
      *(uint2_a*)&Ub[g * 72 + r] = pp;
      Odd[s].x += dd * qtv[s].x * ux;
      Odd[s].y += dd * qtv[s].y * uy;
      Odd[s].z += dd * qtv[s].z * uz;
      Odd[s].w += dd * qtv[s].w * uw;
    }
    asm volatile("" ::: "memory");

    // ---- phase A: s~[g][n] via MFMA (A-fragments in registers) ----
    const shortx8 b0 = *(const shortx8_a*)&Ub[l15 * 72 + 8 * q];
    const shortx8 b1 = *(const shortx8_a*)&Ub[l15 * 72 + 8 * q + 32];
    __builtin_amdgcn_s_setprio(1);
#pragma unroll
    for (int tt = 0; tt < 4; ++tt) {
      floatx4 z = {0.f, 0.f, 0.f, 0.f};
      floatx4 sre = __builtin_amdgcn_mfma_f32_16x16x32_bf16(paR[tt][0], b0, z, 0, 0, 0);
      sre = __builtin_amdgcn_mfma_f32_16x16x32_bf16(paR[tt][1], b1, sre, 0, 0, 0);
      floatx4 sim = __builtin_amdgcn_mfma_f32_16x16x32_bf16(paI[tt][0], b0, z, 0, 0, 0);
      sim = __builtin_amdgcn_mfma_f32_16x16x32_bf16(paI[tt][1], b1, sim, 0, 0, 0);
      // interleaved: row g=l15, columns 2n..2n+7 for n = tt*16+4q+(0..3)
      uint4_a wv;
      wv[0] = pk_bf16(sre[0], sim[0]);
      wv[1] = pk_bf16(sre[1], sim[1]);
      wv[2] = pk_bf16(sre[2], sim[2]);
      wv[3] = pk_bf16(sre[3], sim[3]);
      *(uint4_a*)&SXY[l15 * 136 + 32 * tt + 8 * q] = wv;
    }
    __builtin_amdgcn_s_setprio(0);
    asm volatile("" ::: "memory");

    // ---- register scan: batch-load packed Sc, pure-VALU recurrence ----
    {
      unsigned int rdv[16];
#pragma unroll
      for (int g = 0; g < 16; ++g) rdv[g] = *(const uint_a*)&SXY[g * 136 + 2 * l];
      float xr = 0.f, xi = 0.f;
#pragma unroll
      for (int g = 0; g < 16; ++g) {
        *(uint_a*)&SXY[g * 136 + 2 * l] =
            pk_bf16(c2r * xr - c2i * xi, c2r * xi + c2i * xr);
        union { unsigned int u; float f; } lo, hi;
        lo.u = rdv[g] << 16;
        hi.u = rdv[g] & 0xffff0000u;
        const float nr = er * xr - ei * xi + lo.f;
        xi = er * xi + ei * xr + hi.f;
        xr = nr;
      }
    }
    asm volatile("" ::: "memory");

    // ---- qD loads (L2-warm; consumed after phase C -> latency covered) ----
    float qD[16];
    {
      const int qb = dk * S + 256 * q + l15;
#pragma unroll
      for (int tt = 0; tt < 4; ++tt)
#pragma unroll
        for (int v = 0; v < 4; ++v)
          qD[4 * tt + v] = QT[qb + 64 * v + 16 * tt];
    }

    // ---- phase C MFMAs (B-fragments in registers) ----
    floatx4 acc[4];
#pragma unroll
    for (int tt = 0; tt < 4; ++tt) acc[tt] = (floatx4){0.f, 0.f, 0.f, 0.f};
    __builtin_amdgcn_s_setprio(1);
#pragma unroll
    for (int k = 0; k < 4; ++k) {
      const shortx8 xa = *(const shortx8_a*)&SXY[l15 * 136 + 8 * q + 32 * k];
#pragma unroll
      for (int tt = 0; tt < 4; ++tt)
        acc[tt] = __builtin_amdgcn_mfma_f32_16x16x32_bf16(xa, pcb[k][tt], acc[tt], 0, 0, 0);
    }
#pragma unroll
    for (int k = 0; k < 2; ++k) {
      const shortx8 ua = (k == 0) ? b0 : b1;
#pragma unroll
      for (int tt = 0; tt < 4; ++tt) {
        const int r = tt * 16 + l15;
        const int sSh = (4 - (r & 3)) & 3;
        const int addr = sSh * 136 + (64 - r - sSh) + 8 * q + 32 * k;
        const shortx4_a lo = *(const shortx4_a*)&kdSH[addr];
        const shortx4_a hi = *(const shortx4_a*)&kdSH[addr + 4];
        const shortx8 kb8 = __builtin_shufflevector(lo, hi, 0, 1, 2, 3, 4, 5, 6, 7);
        acc[tt] = __builtin_amdgcn_mfma_f32_16x16x32_bf16(ua, kb8, acc[tt], 0, 0, 0);
      }
    }
    __builtin_amdgcn_s_setprio(0);
    // ---- accumulate O in D-layout ----
#pragma unroll
    for (int tt = 0; tt < 4; ++tt)
#pragma unroll
      for (int v = 0; v < 4; ++v)
        OaccD[tt][v] += qD[4 * tt + v] * acc[tt][v];
    // ---- rotate per-channel scalars ----
    c2r = nc2r; c2i = nc2i; kdv = nkdv; dd = ndd;
  }

  // ---- once-per-block: redistribute D-layout O to t-layout, fold dd-term ----
  asm volatile("" ::: "memory");
  {
    float_a* Ored = (float_a*)WB;  // padded [1028]: idx' = t + (t>>8)
#pragma unroll
    for (int tt = 0; tt < 4; ++tt)
#pragma unroll
      for (int v = 0; v < 4; ++v)
        Ored[256 * q + 64 * v + 16 * tt + l15 + q] = OaccD[tt][v];
    asm volatile("" ::: "memory");
    float4 Oa[4];
#pragma unroll
    for (int s = 0; s < 4; ++s) {
      const float4_a y4 = *(const float4_a*)&Ored[4 * l + 257 * s];
      Oa[s].x = y4.x + Odd[s].x;
      Oa[s].y = y4.y + Odd[s].y;
      Oa[s].z = y4.z + Odd[s].z;
      Oa[s].w = y4.w + Odd[s].w;
    }
    asm volatile("" ::: "memory");
#pragma unroll
    for (int s = 0; s < 4; ++s) {
      float4_a vv = {Oa[s].x, Oa[s].y, Oa[s].z, Oa[s].w};
      *(float4_a*)&Ored[4 * l + 256 * s] = vv;
    }
  }
  __syncthreads();
  {
    const int tq = 256 * w + 4 * l;
    float4_a acc = {0.f, 0.f, 0.f, 0.f};
#pragma unroll
    for (int w2 = 0; w2 < 4; ++w2) {
      const float_a* Ow2 = (const float_a*)(SHu + w2 * 4048);
      acc += *(const float4_a*)&Ow2[tq];
    }
    *(float4_a*)&OT[dv * S + tq] = acc;
  }
}

// ====== L4: out[m][n] = sum_k OT[k][m]*WO[n][k] via bf16 hi/lo MFMA =========
// Round-9: 256 blocks (32n x 64m tiles) instead of 128 (64x64) — the old grid
// left half the CUs idle on a latency-bound kernel. nt loop 2, acc[2], W
// staging halves; X staging and MFMA row mapping unchanged.
__global__ __launch_bounds__(256) void gemm_outT(const float* __restrict__ OT,
                                                 const float* __restrict__ WO,
                                                 float* __restrict__ out) {
  __shared__ __align__(16) char LB[15360];
  unsigned short* Wh = (unsigned short*)LB;  // [32][40] WO planes
  unsigned short* Wl = Wh + 1280;
  unsigned short* Xh = Wl + 1280;            // [64][40] O planes (m rows)
  unsigned short* Xl = Xh + 2560;
  float_a* Ct = (float_a*)LB;                // [64][36] aliased
  const int tid = threadIdx.x;
  const int l = tid & 63, w = tid >> 6;
  const int l15 = l & 15, q = l >> 4;
  const int n0 = (blockIdx.x & 15) * 32, m0 = (blockIdx.x >> 4) * 64;

  floatx4 acc[2];
#pragma unroll
  for (int nt = 0; nt < 2; ++nt) acc[nt] = (floatx4){0.f, 0.f, 0.f, 0.f};

  for (int k0 = 0; k0 < D; k0 += 32) {
    if (k0) __syncthreads();
    // WO rows (n-local 0..31), k-contiguous: 256 float4 -> one pass
    {
      const int row = tid >> 3, c4 = (tid & 7) * 4;
      const float4 wv = *(const float4*)&WO[(n0 + row) * D + k0 + c4];
      const hilo_pair w01 = cvt_hilo_pk(wv.x, wv.y);
      const hilo_pair w23 = cvt_hilo_pk(wv.z, wv.w);
      uint2_a hv = {w01.hp, w23.hp};
      uint2_a lv = {w01.lp, w23.lp};
      *(uint2_a*)&Wh[row * 40 + c4] = hv;
      *(uint2_a*)&Wl[row * 40 + c4] = lv;
    }
    // OT tile: read [k][m] coalesced, store transposed [m][k]: 512 float4
#pragma unroll
    for (int p = 0; p < 2; ++p) {
      const int idx = tid + 256 * p;
      const int kk = idx >> 4, m4 = (idx & 15) * 4;
      const float4 ov = *(const float4*)&OT[(k0 + kk) * S + m0 + m4];
      unsigned short h, g;
      cvt_hilo_fast(ov.x, h, g); Xh[(m4 + 0) * 40 + kk] = h; Xl[(m4 + 0) * 40 + kk] = g;
      cvt_hilo_fast(ov.y, h, g); Xh[(m4 + 1) * 40 + kk] = h; Xl[(m4 + 1) * 40 + kk] = g;
      cvt_hilo_fast(ov.z, h, g); Xh[(m4 + 2) * 40 + kk] = h; Xl[(m4 + 2) * 40 + kk] = g;
      cvt_hilo_fast(ov.w, h, g); Xh[(m4 + 3) * 40 + kk] = h; Xl[(m4 + 3) * 40 + kk] = g;
    }
    __syncthreads();
    const shortx8 xh = *(const shortx8_a*)&Xh[(16 * w + l15) * 40 + 8 * q];
    const shortx8 xl = *(const shortx8_a*)&Xl[(16 * w + l15) * 40 + 8 * q];
#pragma unroll
    for (int nt = 0; nt < 2; ++nt) {
      const shortx8 wh = *(const shortx8_a*)&Wh[(16 * nt + l15) * 40 + 8 * q];
      const shortx8 wl = *(const shortx8_a*)&Wl[(16 * nt + l15) * 40 + 8 * q];
      acc[nt] = __builtin_amdgcn_mfma_f32_16x16x32_bf16(wh, xh, acc[nt], 0, 0, 0);
      acc[nt] = __builtin_amdgcn_mfma_f32_16x16x32_bf16(wh, xl, acc[nt], 0, 0, 0);
      acc[nt] = __builtin_amdgcn_mfma_f32_16x16x32_bf16(wl, xh, acc[nt], 0, 0, 0);
    }
  }
  __syncthreads();
  // lane holds D[n = 16nt+4q+v][m = 16w+l15] -> Ct[m][n] (stride 36)
#pragma unroll
  for (int nt = 0; nt < 2; ++nt)
#pragma unroll
    for (int v = 0; v < 4; ++v)
      Ct[(16 * w + l15) * 36 + 16 * nt + 4 * q + v] = acc[nt][v];
  __syncthreads();
#pragma unroll
  for (int p = 0; p < 2; ++p) {
    const int idx = tid + 256 * p;
    const int row = idx >> 3;          // 0..63 (m-local)
    const int col4 = (idx & 7) * 4;    // 0..28 (n-local)
    *(float4_a*)&out[(m0 + row) * D + n0 + col4] = *(const float4_a*)&Ct[row * 36 + col4];
  }
}

extern "C" void kernel_launch(void* const* d_in, const int* in_sizes, int n_in,
                              void* d_out, int out_size, void* d_ws, size_t ws_size,
                              hipStream_t stream) {
  const float* x   = (const float*)d_in[0];
  const float* WQ  = (const float*)d_in[1];
  const float* WK  = (const float*)d_in[2];
  const float* WV  = (const float*)d_in[3];
  const float* WO  = (const float*)d_in[4];
  const float* Cs  = (const float*)d_in[5];
  const float* Ds  = (const float*)d_in[6];
  const float* Are = (const float*)d_in[7];
  const float* Aim = (const float*)d_in[8];
  const float* Cre = (const float*)d_in[9];
  const float* Cim = (const float*)d_in[10];
  const float* Dd  = (const float*)d_in[11];
  float* out = (float*)d_out;

  char* ws = (char*)d_ws;
  const size_t SD = (size_t)S * D * 4;   // 2 MB
  float* QT    = (float*)(ws + 0 * SD);
  float* KrawT = (float*)(ws + 1 * SD);
  float* VT    = (float*)(ws + 2 * SD);
  float* KnT   = (float*)(ws + 3 * SD);
  float* OT    = (float*)(ws + 4 * SD);
  unsigned short* cb2pack = (unsigned short*)(ws + 5 * SD);            // 8 MB
  unsigned short* kdpack  = (unsigned short*)(ws + 5 * SD + 8388608);  // 8 MB

  fused_qkv_cbkd<<<384 + CD / 16, 256, 0, stream>>>(
      x, WQ, WK, WV, Are, Aim, Cre, Cim, QT, KrawT, VT, cb2pack, kdpack);
  shift_ssmT<<<512, 256, 0, stream>>>(KrawT, Cs, Ds, KnT);
  s4d_fused<<<512, 256, 0, stream>>>(KnT, VT, QT, Are, Aim, cb2pack, kdpack, Dd, OT);
  gemm_outT<<<256, 256, 0, stream>>>(OT, WO, out);
}

// Round 10
// 165.684 us; speedup vs baseline: 2.0389x; 1.0631x over previous
//
#include <hip/hip_runtime.h>

#define S 1024
#define D 512
#define HID 64
#define CD 32768
#define DT 0.1f

typedef __attribute__((ext_vector_type(4))) float floatx4;
typedef __attribute__((ext_vector_type(8))) short shortx8;
// may_alias variants for type-punned LDS/global access (TBAA-safe)
typedef short shortx8_a __attribute__((ext_vector_type(8), may_alias));
typedef short shortx4_a __attribute__((ext_vector_type(4), may_alias));
typedef unsigned int uint_a __attribute__((may_alias));
typedef unsigned int uint2_a __attribute__((ext_vector_type(2), may_alias));
typedef unsigned int uint4_a __attribute__((ext_vector_type(4), may_alias));
typedef float float4_a __attribute__((ext_vector_type(4), may_alias));
typedef float float_a __attribute__((may_alias));

__device__ __forceinline__ unsigned short f2bf(float f) {
  union { float f; unsigned int u; } v;
  v.f = f;
  unsigned int r = v.u + 0x7FFFu + ((v.u >> 16) & 1u);
  return (unsigned short)(r >> 16);
}
__device__ __forceinline__ float bf2f(unsigned short h) {
  union { unsigned int u; float f; } v;
  v.u = ((unsigned int)h) << 16;
  return v.f;
}
// hi/lo split: v ~= bf2f(h) + bf2f(lo), ~16-bit mantissa accuracy
__device__ __forceinline__ void cvt_hilo(float v, unsigned short& h, unsigned short& lo) {
  h = f2bf(v);
  lo = f2bf(v - bf2f(h));
}
// packed f32x2 -> bf16x2: round-half-up (+0x8000) then one v_perm_b32 byte
// pack. perm(A,B,sel): sel bytes 0-3 index B (low source), 4-7 index A, so
// sel 0x07060302 = {A.b3,A.b2,B.b3,B.b2} -> a lands in dst[15:0] exactly like
// f2bf(a)|f2bf(b)<<16. Half-up differs from RNE only on exact ties (<=1 ulp,
// ~2^-17 probability) — negligible (round-6 verified: absmax 0.59 vs 1.49).
__device__ __forceinline__ unsigned int pk_bf16(float a, float b) {
  union { float f; unsigned int u; } va, vb;
  va.f = a; vb.f = b;
  return __builtin_amdgcn_perm(vb.u + 0x8000u, va.u + 0x8000u, 0x07060302u);
}
// fast hi/lo pair: half-up hi plane + residual lo plane, packed. Returned by
// value (vector elements can't bind to non-const refs — round-7 compile fix).
struct hilo_pair { unsigned int hp, lp; };
__device__ __forceinline__ hilo_pair cvt_hilo_pk(float a, float b) {
  union { float f; unsigned int u; } va, vb;
  va.f = a; vb.f = b;
  const unsigned int ra = va.u + 0x8000u, rb = vb.u + 0x8000u;
  hilo_pair r;
  r.hp = __builtin_amdgcn_perm(rb, ra, 0x07060302u);
  union { unsigned int u; float f; } ha, hb;
  ha.u = ra & 0xffff0000u;   // bf2f(hi_a)
  hb.u = rb & 0xffff0000u;
  union { float f; unsigned int u; } la, lb;
  la.f = a - ha.f; lb.f = b - hb.f;
  r.lp = __builtin_amdgcn_perm(lb.u + 0x8000u, la.u + 0x8000u, 0x07060302u);
  return r;
}
// fast scalar hi/lo (for transpose stores where pairs land in different rows)
__device__ __forceinline__ void cvt_hilo_fast(float v, unsigned short& h,
                                              unsigned short& lo) {
  union { float f; unsigned int u; } x;
  x.f = v;
  const unsigned int r = x.u + 0x8000u;
  h = (unsigned short)(r >> 16);
  union { unsigned int u; float f; } hf;
  hf.u = r & 0xffff0000u;
  union { float f; unsigned int u; } l;
  l.f = v - hf.f;
  lo = (unsigned short)((l.u + 0x8000u) >> 16);
}

// =====================  L1: fused QKV-GEMM + cbkd  ==========================
// blocks [0,384): {Q,Kraw,V}T[n][m] = sum_k x[m][k]*W[n][k] via bf16 hi/lo MFMA
// blocks [384,2432): per-16-channel cb2 + kd build (inline dA-power table)
__global__ __launch_bounds__(256) void fused_qkv_cbkd(
    const float* __restrict__ x, const float* __restrict__ WQ,
    const float* __restrict__ WK, const float* __restrict__ WV,
    const float* __restrict__ Are, const float* __restrict__ Aim,
    const float* __restrict__ Cre, const float* __restrict__ Cim,
    float* __restrict__ QT, float* __restrict__ KrawT, float* __restrict__ VT,
    unsigned short* __restrict__ cb2pack, unsigned short* __restrict__ kdpack) {
  __shared__ __align__(16) char LB[21760];
  const int tid = threadIdx.x;
  const int bid = blockIdx.x;
  const int l = tid & 63, w = tid >> 6;
  const int l15 = l & 15, q = l >> 4;

  if (bid < 384) {
    // ---------------- QKV GEMM: 64x64 tile, K=512, BK=32 ----------------
    unsigned short* Wh = (unsigned short*)LB;     // [64][40]
    unsigned short* Wl = Wh + 2560;
    unsigned short* Xh = Wl + 2560;
    unsigned short* Xl = Xh + 2560;
    float_a* Ct = (float_a*)LB;                   // [64][68], aliased after loop
    const int mat = bid >> 7;                     // /128
    const int rem = bid & 127;
    const int n0 = (rem & 7) * 64, m0 = (rem >> 3) * 64;
    const float* Wsel = (mat == 0) ? WQ : (mat == 1) ? WK : WV;
    float* CT = (mat == 0) ? QT : (mat == 1) ? KrawT : VT;

    floatx4 acc[4];
#pragma unroll
    for (int nt = 0; nt < 4; ++nt) acc[nt] = (floatx4){0.f, 0.f, 0.f, 0.f};

    for (int k0 = 0; k0 < D; k0 += 32) {
      if (k0) __syncthreads();
#pragma unroll
      for (int p = 0; p < 2; ++p) {
        const int idx = tid + 256 * p;
        const int row = idx >> 3, c4 = (idx & 7) * 4;
        const float4 wv = *(const float4*)&Wsel[(n0 + row) * D + k0 + c4];
        const float4 xv = *(const float4*)&x[(m0 + row) * D + k0 + c4];
        const hilo_pair w01 = cvt_hilo_pk(wv.x, wv.y);
        const hilo_pair w23 = cvt_hilo_pk(wv.z, wv.w);
        uint2_a hv = {w01.hp, w23.hp};
        uint2_a lv = {w01.lp, w23.lp};
        *(uint2_a*)&Wh[row * 40 + c4] = hv;
        *(uint2_a*)&Wl[row * 40 + c4] = lv;
        const hilo_pair x01 = cvt_hilo_pk(xv.x, xv.y);
        const hilo_pair x23 = cvt_hilo_pk(xv.z, xv.w);
        uint2_a hv2 = {x01.hp, x23.hp};
        uint2_a lv2 = {x01.lp, x23.lp};
        *(uint2_a*)&Xh[row * 40 + c4] = hv2;
        *(uint2_a*)&Xl[row * 40 + c4] = lv2;
      }
      __syncthreads();
      const shortx8 xh = *(const shortx8_a*)&Xh[(16 * w + l15) * 40 + 8 * q];
      const shortx8 xl = *(const shortx8_a*)&Xl[(16 * w + l15) * 40 + 8 * q];
#pragma unroll
      for (int nt = 0; nt < 4; ++nt) {
        const shortx8 wh = *(const shortx8_a*)&Wh[(16 * nt + l15) * 40 + 8 * q];
        const shortx8 wl = *(const shortx8_a*)&Wl[(16 * nt + l15) * 40 + 8 * q];
        acc[nt] = __builtin_amdgcn_mfma_f32_16x16x32_bf16(wh, xh, acc[nt], 0, 0, 0);
        acc[nt] = __builtin_amdgcn_mfma_f32_16x16x32_bf16(wh, xl, acc[nt], 0, 0, 0);
        acc[nt] = __builtin_amdgcn_mfma_f32_16x16x32_bf16(wl, xh, acc[nt], 0, 0, 0);
      }
    }
    __syncthreads();
    // lane holds D[n = 16nt+4q+v][m = 16w+l15] -> Ct[n][m]
#pragma unroll
    for (int nt = 0; nt < 4; ++nt)
#pragma unroll
      for (int v = 0; v < 4; ++v)
        Ct[(16 * nt + 4 * q + v) * 68 + 16 * w + l15] = acc[nt][v];
    __syncthreads();
#pragma unroll
    for (int p = 0; p < 4; ++p) {
      const int row = (tid >> 4) + 16 * p;
      const int col4 = (tid & 15) * 4;
      *(float4_a*)&CT[(n0 + row) * S + m0 + col4] = *(const float4_a*)&Ct[row * 68 + col4];
    }
  } else {
    // ---------------- cbkd: c0 = (bid-384)*16 ----------------
    unsigned short* cbs = (unsigned short*)LB;          // [16][136]
    unsigned short* PCc2s = (unsigned short*)(LB + 4352);  // [64][136]
    const int c0 = (bid - 384) << 4;
    // inline PCc2 table build: thread (n=l, seg=w)
    {
      const int n = l, seg = w;
      const float ar = Are[n], ai = Aim[n];
      const float den_re = 1.0f - 0.05f * ar;
      const float den_im = -0.05f * ai;
      const float num_re = 1.0f + 0.05f * ar;
      const float num_im = 0.05f * ai;
      const float inv_d2 = 1.0f / (den_re * den_re + den_im * den_im);
      const float dAr = (num_re * den_re + num_im * den_im) * inv_d2;
      const float dAi = (num_im * den_re - num_re * den_im) * inv_d2;
      float e2r = dAr * dAr - dAi * dAi, e2i = 2.0f * dAr * dAi;
      float e4r = e2r * e2r - e2i * e2i, e4i = 2.0f * e2r * e2i;
      float e8r = e4r * e4r - e4i * e4i, e8i = 2.0f * e4r * e4i;
      float e16r = e8r * e8r - e8i * e8i, e16i = 2.0f * e8r * e8i;
      float br = 1.0f, bi = 0.0f;
      for (int sgo = 0; sgo < seg; ++sgo) {
        const float nr = br * e16r - bi * e16i;
        bi = br * e16i + bi * e16r;
        br = nr;
      }
      float pr = br, pi = bi;
      for (int k = 16 * seg + 1; k <= 16 * seg + 16; ++k) {
        const float nr = pr * dAr - pi * dAi;
        pi = pr * dAi + pi * dAr;
        pr = nr;
        if (k <= 63) {
          PCc2s[k * 136 + n] = f2bf(pr);
          PCc2s[k * 136 + 64 + n] = f2bf(-pi);
        }
      }
      if (seg == 0) {
        PCc2s[n] = f2bf(1.0f);
        PCc2s[64 + n] = 0;
      }
    }
    // cb2 build
#pragma unroll
    for (int ii = 0; ii < 4; ++ii) {
      const int idx = tid + 256 * ii;
      const int ci = idx >> 6, n = idx & 63;
      const int c = c0 + ci;
      const float ar = Are[n], ai = Aim[n];
      const float den_re = 1.0f - 0.05f * ar;
      const float den_im = -0.05f * ai;
      const float inv_d2 = 1.0f / (den_re * den_re + den_im * den_im);
      const float dBr = DT * den_re * inv_d2;
      const float dBi = -DT * den_im * inv_d2;
      const float cr = Cre[c * HID + n], cim = Cim[c * HID + n];
      const unsigned short re = f2bf(2.0f * (cr * dBr - cim * dBi));
      const unsigned short im = f2bf(2.0f * (cr * dBi + cim * dBr));
      cbs[ci * 136 + n] = re;
      cbs[ci * 136 + 64 + n] = im;
      cb2pack[c * 128 + n] = re;
      cb2pack[c * 128 + 64 + n] = im;
    }
    __syncthreads();
    // kd GEMM -> kdpack (kdR layout)
    floatx4 acc = {0.f, 0.f, 0.f, 0.f};
#pragma unroll
    for (int k = 0; k < 4; ++k) {
      const shortx8 a = *(const shortx8_a*)&cbs[l15 * 136 + 8 * q + 32 * k];
      const shortx8 b = *(const shortx8_a*)&PCc2s[(16 * w + l15) * 136 + 8 * q + 32 * k];
      acc = __builtin_amdgcn_mfma_f32_16x16x32_bf16(a, b, acc, 0, 0, 0);
    }
    const int dlt = 16 * w + l15;
#pragma unroll
    for (int v = 0; v < 4; ++v)
      kdpack[(c0 + 4 * q + v) * 128 + 64 - dlt] = f2bf(acc[v]);
    const int row = tid >> 4, p = tid & 15;
#pragma unroll
    for (int k2 = 0; k2 < 4; ++k2) {
      const int idx = p + 16 * k2;
      const int m = (idx == 0) ? 0 : 64 + idx;
      kdpack[(c0 + row) * 128 + m] = 0;
    }
  }
}

// ======= L2: shift SSM, [d][t] domain — rolling-window float4 reads =========
// (round-9 winner, kept) 17 ds_read_b128/thread instead of 256 ds_read_b32.
__global__ __launch_bounds__(256) void shift_ssmT(const float* __restrict__ KrawT,
                                                  const float* __restrict__ Cs,
                                                  const float* __restrict__ Ds,
                                                  float* __restrict__ KnT) {
  __shared__ __align__(16) float kpad[64 + S];
  const int d = blockIdx.x, tid = threadIdx.x;
  if (tid < 64) kpad[tid] = 0.0f;
  *(float4_a*)&kpad[64 + 4 * tid] = *(const float4_a*)&KrawT[d * S + 4 * tid];
  const float dskip = Ds[d];
  const float* taps = Cs + d * HID;  // block-uniform -> scalar loads
  __syncthreads();
  const float4_a* kp4 = (const float4_a*)kpad;
  // outputs t = 4*tid+c; float base index tb = 64 + 4*tid = 4*(16+tid)
  float4_a B = kp4[16 + tid];
  float acc0 = dskip * B.x, acc1 = dskip * B.y, acc2 = dskip * B.z, acc3 = dskip * B.w;
#pragma unroll
  for (int j4 = 0; j4 < 64; j4 += 4) {
    const float4_a A = kp4[16 + tid - (j4 >> 2) - 1];  // floats tb-j4-4 .. tb-j4-1
    const float t0 = taps[j4], t1 = taps[j4 + 1];
    const float t2 = taps[j4 + 2], t3 = taps[j4 + 3];
    // r=0: kpad[tb+c-j4]      = {B.x,B.y,B.z,B.w}
    acc0 += t0 * B.x; acc1 += t0 * B.y; acc2 += t0 * B.z; acc3 += t0 * B.w;
    // r=1: kpad[tb+c-j4-1]    = {A.w,B.x,B.y,B.z}
    acc0 += t1 * A.w; acc1 += t1 * B.x; acc2 += t1 * B.y; acc3 += t1 * B.z;
    // r=2: kpad[tb+c-j4-2]    = {A.z,A.w,B.x,B.y}
    acc0 += t2 * A.z; acc1 += t2 * A.w; acc2 += t2 * B.x; acc3 += t2 * B.y;
    // r=3: kpad[tb+c-j4-3]    = {A.y,A.z,A.w,B.x}
    acc0 += t3 * A.y; acc1 += t3 * A.z; acc2 += t3 * A.w; acc3 += t3 * B.x;
    B = A;  // rolls: next group's B = kp4[16+tid-(j4+4)/4]
  }
  float4_a o = {acc0, acc1, acc2, acc3};
  *(float4_a*)&KnT[d * S + 4 * tid] = o;
}

// =============== L3: s4d_fused — EXACT round-8 version (51.2 us) ============
// Round-10: reverted the round-9 kdR zero-pad hoist. Post-mortem: the hoist
// perturbed regalloc at the exactly-full unified VGPR+AGPR budget -> hidden
// scratch spill (WRITE_SIZE 2048->8704 KB, FETCH +3.3 MB, dur 51->59 us).
__global__ __launch_bounds__(256, 2) void s4d_fused(
    const float* __restrict__ KnT, const float* __restrict__ VT,
    const float* __restrict__ QT,
    const float* __restrict__ Are, const float* __restrict__ Aim,
    const unsigned short* __restrict__ cb2pack,
    const unsigned short* __restrict__ kdpack,
    const float* __restrict__ Dd, float* __restrict__ OT) {
  __shared__ __align__(16) unsigned short SHu[18176];  // 36352 B
  const int tid = threadIdx.x;
  const int l = tid & 63, w = tid >> 6;
  const int l15 = l & 15, q = l >> 4;
  const int h = blockIdx.x >> 6, j = blockIdx.x & 63;
  const int dv = (h << 6) + j;

  // ---- inline table build: PAre/PAim [n][72], PCc [64][136] interleaved, dA64 ----
  {
    const int n = l, seg = w;
    unsigned short* PAreW = SHu;
    unsigned short* PAimW = SHu + 4608;
    unsigned short* PCcW = SHu + 9216;
    float_a* dA64W = (float_a*)(SHu + 17920);
    const float ar = Are[n], ai = Aim[n];
    const float den_re = 1.0f - 0.05f * ar;
    const float den_im = -0.05f * ai;
    const float num_re = 1.0f + 0.05f * ar;
    const float num_im = 0.05f * ai;
    const float inv_d2 = 1.0f / (den_re * den_re + den_im * den_im);
    const float dAr = (num_re * den_re + num_im * den_im) * inv_d2;
    const float dAi = (num_im * den_re - num_re * den_im) * inv_d2;
    float e2r = dAr * dAr - dAi * dAi, e2i = 2.0f * dAr * dAi;
    float e4r = e2r * e2r - e2i * e2i, e4i = 2.0f * e2r * e2i;
    float e8r = e4r * e4r - e4i * e4i, e8i = 2.0f * e4r * e4i;
    float e16r = e8r * e8r - e8i * e8i, e16i = 2.0f * e8r * e8i;
    float br = 1.0f, bi = 0.0f;
    for (int sgo = 0; sgo < seg; ++sgo) {
      const float nr = br * e16r - bi * e16i;
      bi = br * e16i + bi * e16r;
      br = nr;
    }
    float pr = br, pi = bi;
    for (int k = 16 * seg + 1; k <= 16 * seg + 16; ++k) {
      const float nr = pr * dAr - pi * dAi;
      pi = pr * dAi + pi * dAr;
      pr = nr;
      if (k <= 63) {
        PAreW[n * 72 + 63 - k] = f2bf(pr);
        PAimW[n * 72 + 63 - k] = f2bf(pi);
      }
      // interleaved (re, -im) pairs at columns 2n, 2n+1
      PCcW[(k - 1) * 136 + 2 * n] = f2bf(pr);
      PCcW[(k - 1) * 136 + 2 * n + 1] = f2bf(-pi);
      if (k == 64) {
        dA64W[2 * n] = pr;
        dA64W[2 * n + 1] = pi;
      }
    }
    if (seg == 0) {
      PAreW[n * 72 + 63] = f2bf(1.0f);
      PAimW[n * 72 + 63] = 0;
    }
  }
  // ---- V row slice in registers ----
  float4 vvr[4];
#pragma unroll
  for (int s = 0; s < 4; ++s)
    vvr[s] = *(const float4*)&VT[dv * S + 4 * l + 256 * s];

  // ---- initial per-channel scalar prefetch (channel i = w) ----
  float c2r, c2i, dd;
  unsigned int kdv;
  {
    const int c = (h << 12) + (w << 6) + j;
    c2r = bf2f(cb2pack[c * 128 + l]);
    c2i = bf2f(cb2pack[c * 128 + 64 + l]);
    kdv = *(const uint_a*)&kdpack[c * 128 + 2 * l];
    dd = Dd[c];
  }
  __syncthreads();

  // ---- hoist table fragments into registers (once per block) ----
  const unsigned short* PAre = SHu;
  const unsigned short* PAim = SHu + 4608;
  const unsigned short* PCc = SHu + 9216;
  const float_a* dA64v = (const float_a*)(SHu + 17920);
  const float er = dA64v[2 * l], ei = dA64v[2 * l + 1];
  shortx8 paR[4][2], paI[4][2];
#pragma unroll
  for (int tt = 0; tt < 4; ++tt) {
    const int rowb = (tt * 16 + l15) * 72 + 8 * q;
    paR[tt][0] = *(const shortx8_a*)&PAre[rowb];
    paR[tt][1] = *(const shortx8_a*)&PAre[rowb + 32];
    paI[tt][0] = *(const shortx8_a*)&PAim[rowb];
    paI[tt][1] = *(const shortx8_a*)&PAim[rowb + 32];
  }
  shortx8 pcb[4][4];
#pragma unroll
  for (int k = 0; k < 4; ++k)
#pragma unroll
    for (int tt = 0; tt < 4; ++tt)
      pcb[k][tt] = *(const shortx8_a*)&PCc[(tt * 16 + l15) * 136 + 8 * q + 32 * k];
  __syncthreads();  // all table reads done before workspace aliases tables

  // ---- per-wave workspace, aliased over the table region ----
  unsigned short* WB = SHu + w * 4048;
  unsigned short* Ub = WB;                    // [16][72] bf16
  unsigned short* SXY = WB + 1152;            // [16][136]: Sc -> Xcb interleaved
  uint_a* kdR32 = (uint_a*)(WB + 3328);       // 68 uints (+pad)
  unsigned short* kdSH = WB + 3472;           // [4][136]

  floatx4 OaccD[4];
  float4 Odd[4];
#pragma unroll
  for (int tt = 0; tt < 4; ++tt) OaccD[tt] = (floatx4){0.f, 0.f, 0.f, 0.f};
#pragma unroll
  for (int s = 0; s < 4; ++s) Odd[s] = make_float4(0.f, 0.f, 0.f, 0.f);

#pragma unroll 1
  for (int it = 0; it < 16; ++it) {
    // ---- prefetch next channel's HBM-cold scalars ----
    float nc2r = 0.f, nc2i = 0.f, ndd = 0.f;
    unsigned int nkdv = 0;
    if (it < 15) {
      const int c = (h << 12) + (((it + 1) * 4 + w) << 6) + j;
      nc2r = bf2f(cb2pack[c * 128 + l]);
      nc2i = bf2f(cb2pack[c * 128 + 64 + l]);
      nkdv = *(const uint_a*)&kdpack[c * 128 + 2 * l];
      ndd = Dd[c];
    }
    // ---- current-channel row loads (L2-warm: shared across 64 j-blocks) ----
    const int dk = (h << 6) + it * 4 + w;
    const int kb = dk * S + 4 * l;
    float4 kx[4], qtv[4];
#pragma unroll
    for (int s = 0; s < 4; ++s) {
      kx[s] = *(const float4*)&KnT[kb + 256 * s];
      qtv[s] = *(const float4*)&QT[kb + 256 * s];
    }

    // ---- kdR + 4 shifted copies (uses prefetched kdv; covers row loads) ----
    kdR32[l] = kdv;
    if (l < 4) kdR32[64 + l] = 0;
    asm volatile("" ::: "memory");
#pragma unroll
    for (int s2 = 0; s2 < 4; ++s2) {
      unsigned int v;
      if (s2 == 0) {
        v = kdR32[l];
      } else if (s2 == 1) {
        v = (kdR32[l] >> 16) | (kdR32[l + 1] << 16);
      } else if (s2 == 2) {
        v = kdR32[l + 1];
      } else {
        v = (kdR32[l + 1] >> 16) | (kdR32[l + 2] << 16);
      }
      *(uint_a*)&kdSH[s2 * 136 + 2 * l] = v;
    }
    asm volatile("" ::: "memory");

    // ---- u fill + dd-skip accumulation (kx/qtv die here) ----
#pragma unroll
    for (int s = 0; s < 4; ++s) {
      const int t = 4 * l + 256 * s;
      const int g = t >> 6, r = t & 63;
      const float ux = kx[s].x * vvr[s].x;
      const float uy = kx[s].y * vvr[s].y;
      const float uz = kx[s].z * vvr[s].z;
      const float uw = kx[s].w * vvr[s].w;
      uint2_a pp;
      pp.x = pk_bf16(ux, uy);
      pp.y = pk_bf16(uz, uw);
      *(uint2_a*)&Ub[g * 72 + r] = pp;
      Odd[s].x += dd * qtv[s].x * ux;
      Odd[s].y += dd * qtv[s].y * uy;
      Odd[s].z += dd * qtv[s].z * uz;
      Odd[s].w += dd * qtv[s].w * uw;
    }
    asm volatile("" ::: "memory");

    // ---- phase A: s~[g][n] via MFMA (A-fragments in registers) ----
    const shortx8 b0 = *(const shortx8_a*)&Ub[l15 * 72 + 8 * q];
    const shortx8 b1 = *(const shortx8_a*)&Ub[l15 * 72 + 8 * q + 32];
    __builtin_amdgcn_s_setprio(1);
#pragma unroll
    for (int tt = 0; tt < 4; ++tt) {
      floatx4 z = {0.f, 0.f, 0.f, 0.f};
      floatx4 sre = __builtin_amdgcn_mfma_f32_16x16x32_bf16(paR[tt][0], b0, z, 0, 0, 0);
      sre = __builtin_amdgcn_mfma_f32_16x16x32_bf16(paR[tt][1], b1, sre, 0, 0, 0);
      floatx4 sim = __builtin_amdgcn_mfma_f32_16x16x32_bf16(paI[tt][0], b0, z, 0, 0, 0);
      sim = __builtin_amdgcn_mfma_f32_16x16x32_bf16(paI[tt][1], b1, sim, 0, 0, 0);
      // interleaved: row g=l15, columns 2n..2n+7 for n = tt*16+4q+(0..3)
      uint4_a wv;
      wv[0] = pk_bf16(sre[0], sim[0]);
      wv[1] = pk_bf16(sre[1], sim[1]);
      wv[2] = pk_bf16(sre[2], sim[2]);
      wv[3] = pk_bf16(sre[3], sim[3]);
      *(uint4_a*)&SXY[l15 * 136 + 32 * tt + 8 * q] = wv;
    }
    __builtin_amdgcn_s_setprio(0);
    asm volatile("" ::: "memory");

    // ---- register scan: batch-load packed Sc, pure-VALU recurrence ----
    {
      unsigned int rdv[16];
#pragma unroll
      for (int g = 0; g < 16; ++g) rdv[g] = *(const uint_a*)&SXY[g * 136 + 2 * l];
      float xr = 0.f, xi = 0.f;
#pragma unroll
      for (int g = 0; g < 16; ++g) {
        *(uint_a*)&SXY[g * 136 + 2 * l] =
            pk_bf16(c2r * xr - c2i * xi, c2r * xi + c2i * xr);
        union { unsigned int u; float f; } lo, hi;
        lo.u = rdv[g] << 16;
        hi.u = rdv[g] & 0xffff0000u;
        const float nr = er * xr - ei * xi + lo.f;
        xi = er * xi + ei * xr + hi.f;
        xr = nr;
      }
    }
    asm volatile("" ::: "memory");

    // ---- qD loads (L2-warm; consumed after phase C -> latency covered) ----
    float qD[16];
    {
      const int qb = dk * S + 256 * q + l15;
#pragma unroll
      for (int tt = 0; tt < 4; ++tt)
#pragma unroll
        for (int v = 0; v < 4; ++v)
          qD[4 * tt + v] = QT[qb + 64 * v + 16 * tt];
    }

    // ---- phase C MFMAs (B-fragments in registers) ----
    floatx4 acc[4];
#pragma unroll
    for (int tt = 0; tt < 4; ++tt) acc[tt] = (floatx4){0.f, 0.f, 0.f, 0.f};
    __builtin_amdgcn_s_setprio(1);
#pragma unroll
    for (int k = 0; k < 4; ++k) {
      const shortx8 xa = *(const shortx8_a*)&SXY[l15 * 136 + 8 * q + 32 * k];
#pragma unroll
      for (int tt = 0; tt < 4; ++tt)
        acc[tt] = __builtin_amdgcn_mfma_f32_16x16x32_bf16(xa, pcb[k][tt], acc[tt], 0, 0, 0);
    }
#pragma unroll
    for (int k = 0; k < 2; ++k) {
      const shortx8 ua = (k == 0) ? b0 : b1;
#pragma unroll
      for (int tt = 0; tt < 4; ++tt) {
        const int r = tt * 16 + l15;
        const int sSh = (4 - (r & 3)) & 3;
        const int addr = sSh * 136 + (64 - r - sSh) + 8 * q + 32 * k;
        const shortx4_a lo = *(const shortx4_a*)&kdSH[addr];
        const shortx4_a hi = *(const shortx4_a*)&kdSH[addr + 4];
        const shortx8 kb8 = __builtin_shufflevector(lo, hi, 0, 1, 2, 3, 4, 5, 6, 7);
        acc[tt] = __builtin_amdgcn_mfma_f32_16x16x32_bf16(ua, kb8, acc[tt], 0, 0, 0);
      }
    }
    __builtin_amdgcn_s_setprio(0);
    // ---- accumulate O in D-layout ----
#pragma unroll
    for (int tt = 0; tt < 4; ++tt)
#pragma unroll
      for (int v = 0; v < 4; ++v)
        OaccD[tt][v] += qD[4 * tt + v] * acc[tt][v];
    // ---- rotate per-channel scalars ----
    c2r = nc2r; c2i = nc2i; kdv = nkdv; dd = ndd;
  }

  // ---- once-per-block: redistribute D-layout O to t-layout, fold dd-term ----
  asm volatile("" ::: "memory");
  {
    float_a* Ored = (float_a*)WB;  // padded [1028]: idx' = t + (t>>8)
#pragma unroll
    for (int tt = 0; tt < 4; ++tt)
#pragma unroll
      for (int v = 0; v < 4; ++v)
        Ored[256 * q + 64 * v + 16 * tt + l15 + q] = OaccD[tt][v];
    asm volatile("" ::: "memory");
    float4 Oa[4];
#pragma unroll
    for (int s = 0; s < 4; ++s) {
      const float4_a y4 = *(const float4_a*)&Ored[4 * l + 257 * s];
      Oa[s].x = y4.x + Odd[s].x;
      Oa[s].y = y4.y + Odd[s].y;
      Oa[s].z = y4.z + Odd[s].z;
      Oa[s].w = y4.w + Odd[s].w;
    }
    asm volatile("" ::: "memory");
#pragma unroll
    for (int s = 0; s < 4; ++s) {
      float4_a vv = {Oa[s].x, Oa[s].y, Oa[s].z, Oa[s].w};
      *(float4_a*)&Ored[4 * l + 256 * s] = vv;
    }
  }
  __syncthreads();
  {
    const int tq = 256 * w + 4 * l;
    float4_a acc = {0.f, 0.f, 0.f, 0.f};
#pragma unroll
    for (int w2 = 0; w2 < 4; ++w2) {
      const float_a* Ow2 = (const float_a*)(SHu + w2 * 4048);
      acc += *(const float4_a*)&Ow2[tq];
    }
    *(float4_a*)&OT[dv * S + tq] = acc;
  }
}

// ====== L4: out[m][n] = sum_k OT[k][m]*WO[n][k] via bf16 hi/lo MFMA =========
// (round-9 winner, kept) 256 blocks (32n x 64m tiles): one block per CU.
__global__ __launch_bounds__(256) void gemm_outT(const float* __restrict__ OT,
                                                 const float* __restrict__ WO,
                                                 float* __restrict__ out) {
  __shared__ __align__(16) char LB[15360];
  unsigned short* Wh = (unsigned short*)LB;  // [32][40] WO planes
  unsigned short* Wl = Wh + 1280;
  unsigned short* Xh = Wl + 1280;            // [64][40] O planes (m rows)
  unsigned short* Xl = Xh + 2560;
  float_a* Ct = (float_a*)LB;                // [64][36] aliased
  const int tid = threadIdx.x;
  const int l = tid & 63, w = tid >> 6;
  const int l15 = l & 15, q = l >> 4;
  const int n0 = (blockIdx.x & 15) * 32, m0 = (blockIdx.x >> 4) * 64;

  floatx4 acc[2];
#pragma unroll
  for (int nt = 0; nt < 2; ++nt) acc[nt] = (floatx4){0.f, 0.f, 0.f, 0.f};

  for (int k0 = 0; k0 < D; k0 += 32) {
    if (k0) __syncthreads();
    // WO rows (n-local 0..31), k-contiguous: 256 float4 -> one pass
    {
      const int row = tid >> 3, c4 = (tid & 7) * 4;
      const float4 wv = *(const float4*)&WO[(n0 + row) * D + k0 + c4];
      const hilo_pair w01 = cvt_hilo_pk(wv.x, wv.y);
      const hilo_pair w23 = cvt_hilo_pk(wv.z, wv.w);
      uint2_a hv = {w01.hp, w23.hp};
      uint2_a lv = {w01.lp, w23.lp};
      *(uint2_a*)&Wh[row * 40 + c4] = hv;
      *(uint2_a*)&Wl[row * 40 + c4] = lv;
    }
    // OT tile: read [k][m] coalesced, store transposed [m][k]: 512 float4
#pragma unroll
    for (int p = 0; p < 2; ++p) {
      const int idx = tid + 256 * p;
      const int kk = idx >> 4, m4 = (idx & 15) * 4;
      const float4 ov = *(const float4*)&OT[(k0 + kk) * S + m0 + m4];
      unsigned short h, g;
      cvt_hilo_fast(ov.x, h, g); Xh[(m4 + 0) * 40 + kk] = h; Xl[(m4 + 0) * 40 + kk] = g;
      cvt_hilo_fast(ov.y, h, g); Xh[(m4 + 1) * 40 + kk] = h; Xl[(m4 + 1) * 40 + kk] = g;
      cvt_hilo_fast(ov.z, h, g); Xh[(m4 + 2) * 40 + kk] = h; Xl[(m4 + 2) * 40 + kk] = g;
      cvt_hilo_fast(ov.w, h, g); Xh[(m4 + 3) * 40 + kk] = h; Xl[(m4 + 3) * 40 + kk] = g;
    }
    __syncthreads();
    const shortx8 xh = *(const shortx8_a*)&Xh[(16 * w + l15) * 40 + 8 * q];
    const shortx8 xl = *(const shortx8_a*)&Xl[(16 * w + l15) * 40 + 8 * q];
#pragma unroll
    for (int nt = 0; nt < 2; ++nt) {
      const shortx8 wh = *(const shortx8_a*)&Wh[(16 * nt + l15) * 40 + 8 * q];
      const shortx8 wl = *(const shortx8_a*)&Wl[(16 * nt + l15) * 40 + 8 * q];
      acc[nt] = __builtin_amdgcn_mfma_f32_16x16x32_bf16(wh, xh, acc[nt], 0, 0, 0);
      acc[nt] = __builtin_amdgcn_mfma_f32_16x16x32_bf16(wh, xl, acc[nt], 0, 0, 0);
      acc[nt] = __builtin_amdgcn_mfma_f32_16x16x32_bf16(wl, xh, acc[nt], 0, 0, 0);
    }
  }
  __syncthreads();
  // lane holds D[n = 16nt+4q+v][m = 16w+l15] -> Ct[m][n] (stride 36)
#pragma unroll
  for (int nt = 0; nt < 2; ++nt)
#pragma unroll
    for (int v = 0; v < 4; ++v)
      Ct[(16 * w + l15) * 36 + 16 * nt + 4 * q + v] = acc[nt][v];
  __syncthreads();
#pragma unroll
  for (int p = 0; p < 2; ++p) {
    const int idx = tid + 256 * p;
    const int row = idx >> 3;          // 0..63 (m-local)
    const int col4 = (idx & 7) * 4;    // 0..28 (n-local)
    *(float4_a*)&out[(m0 + row) * D + n0 + col4] = *(const float4_a*)&Ct[row * 36 + col4];
  }
}

extern "C" void kernel_launch(void* const* d_in, const int* in_sizes, int n_in,
                              void* d_out, int out_size, void* d_ws, size_t ws_size,
                              hipStream_t stream) {
  const float* x   = (const float*)d_in[0];
  const float* WQ  = (const float*)d_in[1];
  const float* WK  = (const float*)d_in[2];
  const float* WV  = (const float*)d_in[3];
  const float* WO  = (const float*)d_in[4];
  const float* Cs  = (const float*)d_in[5];
  const float* Ds  = (const float*)d_in[6];
  const float* Are = (const float*)d_in[7];
  const float* Aim = (const float*)d_in[8];
  const float* Cre = (const float*)d_in[9];
  const float* Cim = (const float*)d_in[10];
  const float* Dd  = (const float*)d_in[11];
  float* out = (float*)d_out;

  char* ws = (char*)d_ws;
  const size_t SD = (size_t)S * D * 4;   // 2 MB
  float* QT    = (float*)(ws + 0 * SD);
  float* KrawT = (float*)(ws + 1 * SD);
  float* VT    = (float*)(ws + 2 * SD);
  float* KnT   = (float*)(ws + 3 * SD);
  float* OT    = (float*)(ws + 4 * SD);
  unsigned short* cb2pack = (unsigned short*)(ws + 5 * SD);            // 8 MB
  unsigned short* kdpack  = (unsigned short*)(ws + 5 * SD + 8388608);  // 8 MB

  fused_qkv_cbkd<<<384 + CD / 16, 256, 0, stream>>>(
      x, WQ, WK, WV, Are, Aim, Cre, Cim, QT, KrawT, VT, cb2pack, kdpack);
  shift_ssmT<<<512, 256, 0, stream>>>(KrawT, Cs, Ds, KnT);
  s4d_fused<<<512, 256, 0, stream>>>(KnT, VT, QT, Are, Aim, cb2pack, kdpack, Dd, OT);
  gemm_outT<<<256, 256, 0, stream>>>(OT, WO, out);
}